// Round 7
// baseline (1111.649 us; speedup 1.0000x reference)
//
#include <hip/hip_runtime.h>
#include <hip/hip_bf16.h>
#include <hip/hip_fp16.h>

#define NNODE 2048
#define NGRAPH 16

using f16x8 = __attribute__((ext_vector_type(8))) _Float16;
using f32x4 = __attribute__((ext_vector_type(4))) float;

__device__ __forceinline__ int lmap(int m) { return m == 0 ? 0 : (m < 4 ? 1 : (m < 9 ? 2 : 3)); }

__device__ __forceinline__ float f4get(const float4& v, int j) {
    return j == 0 ? v.x : (j == 1 ? v.y : (j == 2 ? v.z : v.w));
}

// pack two floats as fp16 pair in a u32 (lo = a, hi = b)
__device__ __forceinline__ uint32_t f2h2(float a, float b) {
    __half2 h2 = __floats2half2_rn(a, b);
    return *reinterpret_cast<uint32_t*>(&h2);
}
__device__ __forceinline__ float2 h2f2(uint32_t u) {
    __half2 h2 = *reinterpret_cast<__half2*>(&u);
    return __half22float2(h2);
}

__device__ __forceinline__ void sph16(float x, float y, float z, float* Y) {
    Y[0] = 0.28209479177f;
    Y[1] = 0.4886025119f * y; Y[2] = 0.4886025119f * z; Y[3] = 0.4886025119f * x;
    Y[4] = 1.09254843059f * x * y;
    Y[5] = 1.09254843059f * y * z;
    Y[6] = 0.31539156525f * (3.f * z * z - 1.f);
    Y[7] = 1.09254843059f * x * z;
    Y[8] = 0.54627421529f * (x * x - y * y);
    Y[9]  = 0.59004358992f * y * (3.f * x * x - y * y);
    Y[10] = 2.89061144264f * x * y * z;
    Y[11] = 0.45704579946f * y * (5.f * z * z - 1.f);
    Y[12] = 0.37317633259f * z * (5.f * z * z - 3.f);
    Y[13] = 0.45704579946f * x * (5.f * z * z - 1.f);
    Y[14] = 1.44530572132f * z * (x * x - y * y);
    Y[15] = 0.59004358992f * x * (x * x - 3.f * y * y);
}

// process one source (REG) of the current (dh,mt) phase
#define PROC_R(REG, U0, U1, U2, U3, ACC, D, DCOL, ABASE) { \
    int a_ = (ABASE) + (REG); \
    float w_ = alphas[a_]; \
    const float* ysa = &yss[a_ * 17]; \
    float hb1 = h0col[a_ * 33 + (DCOL)] + 1.f; \
    float R0 = D[0][REG], R1 = D[1][REG], R2 = D[2][REG], R3 = D[3][REG]; \
    float Sc0 = D[4][REG] * hb1, Sc1 = D[5][REG] * hb1; \
    float Sc2 = D[6][REG] * hb1, Sc3 = D[7][REG] * hb1; \
    ACC[0]  = fmaf(w_, fmaf((U0).x, R0, Sc0 * ysa[0]),  ACC[0]); \
    ACC[1]  = fmaf(w_, fmaf((U0).y, R1, Sc1 * ysa[1]),  ACC[1]); \
    ACC[2]  = fmaf(w_, fmaf((U0).z, R1, Sc1 * ysa[2]),  ACC[2]); \
    ACC[3]  = fmaf(w_, fmaf((U0).w, R1, Sc1 * ysa[3]),  ACC[3]); \
    ACC[4]  = fmaf(w_, fmaf((U1).x, R2, Sc2 * ysa[4]),  ACC[4]); \
    ACC[5]  = fmaf(w_, fmaf((U1).y, R2, Sc2 * ysa[5]),  ACC[5]); \
    ACC[6]  = fmaf(w_, fmaf((U1).z, R2, Sc2 * ysa[6]),  ACC[6]); \
    ACC[7]  = fmaf(w_, fmaf((U1).w, R2, Sc2 * ysa[7]),  ACC[7]); \
    ACC[8]  = fmaf(w_, fmaf((U2).x, R2, Sc2 * ysa[8]),  ACC[8]); \
    ACC[9]  = fmaf(w_, fmaf((U2).y, R3, Sc3 * ysa[9]),  ACC[9]); \
    ACC[10] = fmaf(w_, fmaf((U2).z, R3, Sc3 * ysa[10]), ACC[10]); \
    ACC[11] = fmaf(w_, fmaf((U2).w, R3, Sc3 * ysa[11]), ACC[11]); \
    ACC[12] = fmaf(w_, fmaf((U3).x, R3, Sc3 * ysa[12]), ACC[12]); \
    ACC[13] = fmaf(w_, fmaf((U3).y, R3, Sc3 * ysa[13]), ACC[13]); \
    ACC[14] = fmaf(w_, fmaf((U3).z, R3, Sc3 * ysa[14]), ACC[14]); \
    ACC[15] = fmaf(w_, fmaf((U3).w, R3, Sc3 * ysa[15]), ACC[15]); \
    }

// one (dh,mt) phase: prefetch 2 vpre rows, 16 MFMAs, epilogue 4 sources (2-deep refill)
#define PHASE(DH, MT, ACC) { \
    const int dcol = (DH) * 16 + n; \
    const int abase = w * 32 + (MT) * 16 + kb * 4; \
    const float4* vr0 = reinterpret_cast<const float4*>(vpre + (gbase + abase + 0) * 512 + dcol * 16); \
    const float4* vr1 = reinterpret_cast<const float4*>(vpre + (gbase + abase + 1) * 512 + dcol * 16); \
    const float4* vr2 = reinterpret_cast<const float4*>(vpre + (gbase + abase + 2) * 512 + dcol * 16); \
    const float4* vr3 = reinterpret_cast<const float4*>(vpre + (gbase + abase + 3) * 512 + dcol * 16); \
    float4 pa0 = vr0[0], pa1 = vr0[1], pa2 = vr0[2], pa3 = vr0[3]; \
    float4 pb0 = vr1[0], pb1 = vr1[1], pb2 = vr1[2], pb3 = vr1[3]; \
    f32x4 D[8]; \
    _Pragma("unroll") \
    for (int q = 0; q < 8; q++) { \
        int nt_ = ((q >> 2) << 3) + ((q & 3) << 1) + (DH); \
        f16x8 Bf = *reinterpret_cast<const f16x8*>(wBH + nt_ * 512 + lane * 8); \
        f32x4 z = {0.f, 0.f, 0.f, 0.f}; \
        z = __builtin_amdgcn_mfma_f32_16x16x32_f16(Ahi[MT], Bf, z, 0, 0, 0); \
        z = __builtin_amdgcn_mfma_f32_16x16x32_f16(Alo[MT], Bf, z, 0, 0, 0); \
        D[q] = z; \
    } \
    { float4 u0 = pa0, u1 = pa1, u2 = pa2, u3 = pa3; \
      pa0 = vr2[0]; pa1 = vr2[1]; pa2 = vr2[2]; pa3 = vr2[3]; \
      PROC_R(0, u0, u1, u2, u3, ACC, D, dcol, abase) } \
    { float4 u0 = pb0, u1 = pb1, u2 = pb2, u3 = pb3; \
      pb0 = vr3[0]; pb1 = vr3[1]; pb2 = vr3[2]; pb3 = vr3[3]; \
      PROC_R(1, u0, u1, u2, u3, ACC, D, dcol, abase) } \
    PROC_R(2, pa0, pa1, pa2, pa3, ACC, D, dcol, abase) \
    PROC_R(3, pb0, pb1, pb2, pb3, ACC, D, dcol, abase) \
}

// One fused layer. 3 blocks/CU (LDS ~51KB).
__global__ __launch_bounds__(256, 3) void k_layer(
    const float* __restrict__ x, const float* __restrict__ h,
    const float* __restrict__ vpre, const float* __restrict__ wqk,
    const float* __restrict__ w1, const float* __restrict__ b1,
    const float* __restrict__ rW, const float* __restrict__ sW,
    const float* __restrict__ Wskip, const float* __restrict__ Wo,
    const float* __restrict__ gw, const float* __restrict__ gb,
    const float* __restrict__ Wv_n, const float* __restrict__ Wq_n, const float* __restrict__ Wk_n,
    const float* __restrict__ WvO, const float* __restrict__ WqO, const float* __restrict__ WkO,
    float* __restrict__ hnew, float* __restrict__ vpre_n, float* __restrict__ wqk_n,
    float* __restrict__ wq2, float* __restrict__ U,
    int layer, int last)
{
    // bufA: rh fp16-hi [2560 u32] + fp16-lo [2560 u32]; then h0col[128*33] f32;
    //       then P[4][512] f32; then Wskip / WvO-lo f32
    __shared__ __align__(16) uint32_t bufA[5120];
    // wB: B fragments fp16 [nt=16][lane=64][8] (16KB); later Wo / Wv_n / WvO-hi (f32 bits)
    __shared__ __align__(16) uint32_t wB[4096];
    __shared__ __align__(16) float yss[128 * 17]; // Ys; later hs[512]
    __shared__ __align__(16) float ub[1056];      // phase A: xs[384]|w1s[512]; post: hnS[528]|aggL[528]
    __shared__ float b1s[32];
    __shared__ float wqks[32];
    __shared__ float alphas[128];
    __shared__ float red[256];
    __shared__ float scale[128];
    __shared__ float sh_inv;

    int nblk = blockIdx.x, t = threadIdx.x;
    nblk = ((nblk & 7) << 8) | (nblk >> 3);   // XCD swizzle: 2 graphs per XCD
    int g = nblk >> 7, b = nblk & 127;
    int gbase = g << 7;

    float* xs = ub;           // [384]
    float* w1s = ub + 384;    // [512]

    for (int o = t; o < 384; o += 256) xs[o] = x[gbase * 3 + o];
    for (int o = t; o < 512; o += 256) w1s[o] = w1[layer * 512 + o];
    if (t < 32) { b1s[t] = b1[layer * 32 + t]; wqks[t] = wqk[nblk * 32 + t]; }
    // stage rW|sW as fp16 B-fragments: nt = rs*8 + l*2 + dh, lane = kb*16 + (d&15), pair along j
    for (int idx = t; idx < 4096; idx += 256) {
        int d2 = idx & 31, j2 = (idx >> 5) & 15, l = (idx >> 9) & 3, rs = idx >> 11;
        const float* W = rs ? sW : rW;
        int srcb = layer * 4096 + l * 1024 + (2 * j2) * 32 + d2;
        float v0 = W[srcb], v1 = W[srcb + 32];
        int nt = rs * 8 + l * 2 + (d2 >> 4);
        int lid = ((j2 >> 2) << 4) + (d2 & 15);
        wB[nt * 256 + lid * 4 + (j2 & 3)] = f2h2(v0, v1);
    }
    __syncthreads();

    // ---- phase A: geometry, rh (stored as fp16 hi+lo), partial logit ----
    {
        int a = t & 127, dh = t >> 7;
        float rx = xs[b * 3 + 0] - xs[a * 3 + 0];
        float ry = xs[b * 3 + 1] - xs[a * 3 + 1];
        float rz = xs[b * 3 + 2] - xs[a * 3 + 2];
        float dd = sqrtf(rx * rx + ry * ry + rz * rz + 1e-12f);
        float inv = 1.f / dd;
        float ys[16];
        sph16(rx * inv, ry * inv, rz * inv, ys);
        if (dh == 0) {
#pragma unroll
            for (int m = 0; m < 16; m++) yss[a * 17 + m] = ys[m];
        }
        float rbf[16];
#pragma unroll
        for (int j = 0; j < 16; j++) {
            float dc = dd - (4.f / 15.f) * j;
            rbf[j] = __expf(-2.f * dc * dc);
        }
        float lpart = 0.f;
        int d0 = dh * 16;
        float sprev = 0.f;
        for (int d2 = 0; d2 < 16; d2++) {
            int d = d0 + d2;
            float s = b1s[d];
#pragma unroll
            for (int j = 0; j < 16; j++) s = fmaf(rbf[j], w1s[j * 32 + d], s);
            s = fmaxf(s, 0.f);
            lpart = fmaf(s, wqks[d], lpart);
            if (d2 & 1) {
                __half h0 = __float2half_rn(sprev), h1 = __float2half_rn(s);
                float l0f = sprev - __half2float(h0), l1f = s - __half2float(h1);
                uint32_t hp = (uint32_t)__half_as_ushort(h0) |
                              ((uint32_t)__half_as_ushort(h1) << 16);
                uint32_t lp = (uint32_t)__half_as_ushort(__float2half_rn(l0f)) |
                              ((uint32_t)__half_as_ushort(__float2half_rn(l1f)) << 16);
                int wi = a * 20 + dh * 8 + (d2 >> 1);
                bufA[wi] = hp;
                bufA[2560 + wi] = lp;
            }
            sprev = s;
        }
        red[t] = lpart;
    }
    __syncthreads();
    if (t < 128) alphas[t] = (red[t] + red[t + 128]) * 0.17677669529663687f; // 1/sqrt(32)
    __syncthreads();

    // ---- segment softmax over 127 valid edges (wave shuffle reductions) ----
    if (t < 128) {
        float m = (t != b) ? alphas[t] : -1e30f;
#pragma unroll
        for (int off = 32; off > 0; off >>= 1) m = fmaxf(m, __shfl_xor(m, off));
        if ((t & 63) == 0) red[t >> 6] = m;
    }
    __syncthreads();
    {
        float mx = fmaxf(red[0], red[1]);
        if (t < 128) {
            float e = (t != b) ? __expf(alphas[t] - mx) : 0.f;
            alphas[t] = e;
            float s = e;
#pragma unroll
            for (int off = 32; off > 0; off >>= 1) s += __shfl_xor(s, off);
            if ((t & 63) == 0) red[2 + (t >> 6)] = s;
        }
    }
    __syncthreads();
    if (t == 0) sh_inv = 1.f / (red[2] + red[3]);

    // ---- pass 2: MFMA R/S GEMM + pipelined weighted aggregate ----
    int lane = t & 63, w = t >> 6;
    int n = lane & 15, kb = lane >> 4;

    const _Float16* rhHiH = reinterpret_cast<const _Float16*>(bufA);
    const _Float16* rhLoH = reinterpret_cast<const _Float16*>(bufA + 2560);
    const _Float16* wBH   = reinterpret_cast<const _Float16*>(wB);

    f16x8 Ahi[2], Alo[2];
#pragma unroll
    for (int mt = 0; mt < 2; mt++) {
        int row = (w * 2 + mt) * 16 + n;
        Ahi[mt] = *reinterpret_cast<const f16x8*>(rhHiH + row * 40 + kb * 8);
        Alo[mt] = *reinterpret_cast<const f16x8*>(rhLoH + row * 40 + kb * 8);
    }
    __syncthreads();   // all bufA (rh) reads done

    // stage h0 column h0col[a*33+d] = h[(gbase+a)*512 + d*16] (overlay bufA)
    float* h0col = reinterpret_cast<float*>(bufA);
    for (int idx = t; idx < 4096; idx += 256) {
        int aa = idx >> 5, dd = idx & 31;
        h0col[aa * 33 + dd] = h[(gbase + aa) * 512 + dd * 16];
    }
    __syncthreads();   // h0col ready

    float acc0[16], acc1[16];
#pragma unroll
    for (int m = 0; m < 16; m++) { acc0[m] = 0.f; acc1[m] = 0.f; }

    PHASE(0, 0, acc0)
    PHASE(0, 1, acc0)
    PHASE(1, 0, acc1)
    PHASE(1, 1, acc1)

    // cross-kb butterfly reduce (sources within wave)
#pragma unroll
    for (int m = 0; m < 16; m++) {
        float v0 = acc0[m];
        v0 += __shfl_xor(v0, 16); v0 += __shfl_xor(v0, 32);
        acc0[m] = v0;
        float v1 = acc1[m];
        v1 += __shfl_xor(v1, 16); v1 += __shfl_xor(v1, 32);
        acc1[m] = v1;
    }
    __syncthreads();   // all pass-2 LDS reads (h0col/wB/yss) done

    // S1: partials into P (overlay bufA); stage h[n] (overlay yss); stage Wo into wB
    float* P = reinterpret_cast<float*>(bufA);
    if (lane < 16) {
#pragma unroll
        for (int m = 0; m < 16; m++) {
            P[w * 512 + m * 16 + n] = acc0[m];
            P[w * 512 + 256 + m * 16 + n] = acc1[m];
        }
    }
    float* hs = yss;
    for (int o = t; o < 512; o += 256) hs[o] = h[nblk * 512 + o];
    for (int o = t; o < 4096; o += 256) wB[o] = __float_as_uint(Wo[layer * 4096 + o]);
    __syncthreads();

    // S2: reduce partials -> aggL[m*33+c]  (c = dh*16 + n)
    float* hnS = ub;          // [528]
    float* aggL = ub + 528;   // [528]
    float invs = sh_inv;
    for (int o = t; o < 512; o += 256) {
        int m = o >> 5, c = o & 31;
        int dh = c >> 4, nn = c & 15;
        float s = 0.f;
#pragma unroll
        for (int ww = 0; ww < 4; ww++) s += P[ww * 512 + dh * 256 + m * 16 + nn];
        aggL[m * 33 + c] = s * invs;
    }
    __syncthreads();

    // S3: stage Wskip into bufA (fp32), P dead
    float* bufF = reinterpret_cast<float*>(bufA);
    for (int o = t; o < 4096; o += 256) bufF[o] = Wskip[layer * 4096 + o];
    __syncthreads();

    // S4: post GEMM: hn = h@Wskip + agg@Wo
    for (int o = t; o < 512; o += 256) {
        int m = o >> 5, dd = o & 31, l = lmap(m);
        float s = 0.f;
        const float* wa = &bufF[l * 1024 + dd];
        const uint32_t* wb = &wB[l * 1024 + dd];
        const float* hrow = &hs[m];
        const float* arow = &aggL[m * 33];
#pragma unroll
        for (int c = 0; c < 32; c++) {
            s = fmaf(hrow[c * 16], wa[c * 32], s);
            s = fmaf(arow[c], __uint_as_float(wb[c * 32]), s);
        }
        hnS[m * 33 + dd] = s;
    }
    __syncthreads();

    // S5: norm gate compute + stage next-stage value weights
    if (t < 128) {
        int dd = t >> 2, l = t & 3;
        int m0 = l * l, cnt = 2 * l + 1;
        float s = 1e-12f;
        for (int m = m0; m < m0 + cnt; m++) { float v = hnS[m * 33 + dd]; s = fmaf(v, v, s); }
        float nr = sqrtf(s);
        float phi = fmaxf(nr * gw[(layer * 4 + l) * 32 + dd] + gb[(layer * 4 + l) * 32 + dd], 0.f);
        scale[dd * 4 + l] = phi / (nr + 1e-6f);
    }
    if (!last) {
        for (int o = t; o < 4096; o += 256) wB[o] = __float_as_uint(Wv_n[o]);
    } else {
        for (int o = t; o < 4096; o += 256) {
            bufF[o] = WvO[o];                               // l = 0,1
            wB[o] = __float_as_uint(WvO[4096 + o]);         // l = 2,3
        }
    }
    __syncthreads();

    // S6: apply gate, write hnew
    for (int o = t; o < 512; o += 256) {
        int dd = o >> 4, m = o & 15;
        float v = hnS[m * 33 + dd] * scale[dd * 4 + lmap(m)];
        hnew[nblk * 512 + o] = v;
        hnS[m * 33 + dd] = v;
    }
    __syncthreads();

    if (!last) {
        for (int o = t; o < 512; o += 256) {
            int dd = o >> 4, m = o & 15, l = lmap(m);
            float s = 0.f;
            const uint32_t* wv = &wB[l * 1024 + dd];
            const float* hrow = &hnS[m * 33];
#pragma unroll
            for (int c = 0; c < 32; c++) s = fmaf(hrow[c], __uint_as_float(wv[c * 32]), s);
            vpre_n[nblk * 512 + o] = s;
        }
        if (t < 32) {
            float s = 0.f;
#pragma unroll
            for (int c = 0; c < 32; c++) s = fmaf(hnS[c * 33], Wq_n[c * 32 + t], s);
            red[t] = s;
        }
        __syncthreads();
        if (t < 32) {
            float s = 0.f;
#pragma unroll
            for (int j = 0; j < 32; j++) s = fmaf(Wk_n[t * 32 + j], red[j], s);
            wqk_n[nblk * 32 + t] = s;
        }
    } else {
        for (int o = t; o < 1024; o += 256) {
            int j = o >> 4, m = o & 15, l = lmap(m);
            float s = 0.f;
            const float* hrow = &hnS[m * 33];
            if (l < 2) {
                const float* wv = &bufF[l * 2048 + j];
#pragma unroll
                for (int c = 0; c < 32; c++) s = fmaf(hrow[c], wv[c * 64], s);
            } else {
                const uint32_t* wv = &wB[(l - 2) * 2048 + j];
#pragma unroll
                for (int c = 0; c < 32; c++) s = fmaf(hrow[c], __uint_as_float(wv[c * 64]), s);
            }
            U[nblk * 1024 + o] = s;
        }
        if (t < 64) {
            float s = 0.f;
#pragma unroll
            for (int c = 0; c < 32; c++) s = fmaf(hnS[c * 33], WqO[c * 64 + t], s);
            red[t] = s;
        }
        __syncthreads();
        if (t < 32) {
            float s = 0.f;
#pragma unroll
            for (int j = 0; j < 64; j++) s = fmaf(WkO[t * 64 + j], red[j], s);
            wq2[nblk * 32 + t] = s;
        }
    }
}

// Output-stage edge kernel + fused out_post (hout). 3 blocks/CU.
__global__ __launch_bounds__(256, 3) void k_out_edge(
    const float* __restrict__ x, const float* __restrict__ h,
    const float* __restrict__ w1o, const float* __restrict__ b1o,
    const float* __restrict__ wq2, const float* __restrict__ roW,
    const float* __restrict__ U, const float* __restrict__ WoO,
    const float* __restrict__ WskipO, float* __restrict__ hout)
{
    __shared__ uint32_t rosP[4096];               // fp16 pairs of roW c-neighbors
    __shared__ __align__(16) float rhs[128 * 36];
    __shared__ __align__(16) float yss[128 * 17];
    __shared__ float xs[384];
    __shared__ float w1s[512];
    __shared__ float b1s[32];
    __shared__ float wq2s[32];
    __shared__ float alphas[128];
    __shared__ float red[256];
    __shared__ float agg64s[64];
    __shared__ float sh_inv;

    int n = blockIdx.x, t = threadIdx.x;
    n = ((n & 7) << 8) | (n >> 3);   // XCD swizzle
    int g = n >> 7, b = n & 127;
    int gbase = g << 7;

    for (int o = t; o < 384; o += 256) xs[o] = x[gbase * 3 + o];
    for (int o = t; o < 512; o += 256) w1s[o] = w1o[o];
    if (t < 32) { b1s[t] = b1o[t]; wq2s[t] = wq2[n * 32 + t]; }
    for (int o = t; o < 4096; o += 256) {
        int j = o & 63, lc = o >> 6, cp = lc & 15, l = lc >> 4;
        rosP[o] = f2h2(roW[(l * 32 + 2 * cp) * 64 + j], roW[(l * 32 + 2 * cp + 1) * 64 + j]);
    }
    __syncthreads();

    // phase A split across 256 threads
    {
        int a = t & 127, dh = t >> 7;
        float rx = xs[b * 3 + 0] - xs[a * 3 + 0];
        float ry = xs[b * 3 + 1] - xs[a * 3 + 1];
        float rz = xs[b * 3 + 2] - xs[a * 3 + 2];
        float dd = sqrtf(rx * rx + ry * ry + rz * rz + 1e-12f);
        float inv = 1.f / dd;
        float ys[16];
        sph16(rx * inv, ry * inv, rz * inv, ys);
        if (dh == 0) {
#pragma unroll
            for (int m = 0; m < 16; m++) yss[a * 17 + m] = ys[m];
        }
        float rbf[16];
#pragma unroll
        for (int j = 0; j < 16; j++) {
            float dc = dd - (4.f / 15.f) * j;
            rbf[j] = __expf(-2.f * dc * dc);
        }
        float lpart = 0.f;
        int d0 = dh * 16;
        for (int d2 = 0; d2 < 16; d2++) {
            int d = d0 + d2;
            float s = b1s[d];
#pragma unroll
            for (int j = 0; j < 16; j++) s = fmaf(rbf[j], w1s[j * 32 + d], s);
            s = fmaxf(s, 0.f);
            rhs[a * 36 + d] = s;
            lpart = fmaf(s, wq2s[d], lpart);
        }
        red[t] = lpart;
    }
    __syncthreads();
    if (t < 128) alphas[t] = (red[t] + red[t + 128]) * 0.125f; // 1/sqrt(64)
    __syncthreads();

    if (t < 128) {
        float m = (t != b) ? alphas[t] : -1e30f;
#pragma unroll
        for (int off = 32; off > 0; off >>= 1) m = fmaxf(m, __shfl_xor(m, off));
        if ((t & 63) == 0) red[t >> 6] = m;
    }
    __syncthreads();
    {
        float mx = fmaxf(red[0], red[1]);
        if (t < 128) {
            float e = (t != b) ? __expf(alphas[t] - mx) : 0.f;
            alphas[t] = e;
            float s = e;
#pragma unroll
            for (int off = 32; off > 0; off >>= 1) s += __shfl_xor(s, off);
            if ((t & 63) == 0) red[2 + (t >> 6)] = s;
        }
    }
    __syncthreads();
    if (t == 0) sh_inv = 1.f / (red[2] + red[3]);
    __syncthreads();

    int grp = t >> 6, j = t & 63;
    float accO = 0.f;
    for (int chunk = 0; chunk < 4; chunk++) {
        int a0 = grp * 32 + chunk * 8;
        float RO[8][4];
#pragma unroll
        for (int aa = 0; aa < 8; aa++)
#pragma unroll
            for (int l = 0; l < 4; l++) RO[aa][l] = 0.f;

#pragma unroll 2
        for (int cq = 0; cq < 8; cq++) {
            float4 rh4[8];
#pragma unroll
            for (int aa = 0; aa < 8; aa++)
                rh4[aa] = *reinterpret_cast<const float4*>(&rhs[(a0 + aa) * 36 + cq * 4]);
#pragma unroll
            for (int l = 0; l < 4; l++) {
#pragma unroll
                for (int ch = 0; ch < 2; ch++) {
                    float2 w2 = h2f2(rosP[(l * 16 + cq * 2 + ch) * 64 + j]);
#pragma unroll
                    for (int aa = 0; aa < 8; aa++) {
                        RO[aa][l] = fmaf(f4get(rh4[aa], 2 * ch), w2.x, RO[aa][l]);
                        RO[aa][l] = fmaf(f4get(rh4[aa], 2 * ch + 1), w2.y, RO[aa][l]);
                    }
                }
            }
        }

        float4 A0, A1, A2, A3, B0, B1, B2, B3;
        {
            const float4* p4 = reinterpret_cast<const float4*>(U + (gbase + a0) * 1024 + j * 16);
            A0 = p4[0]; A1 = p4[1]; A2 = p4[2]; A3 = p4[3];
            const float4* q4 = reinterpret_cast<const float4*>(U + (gbase + a0 + 1) * 1024 + j * 16);
            B0 = q4[0]; B1 = q4[1]; B2 = q4[2]; B3 = q4[3];
        }
#define PROC_O(aa, u0, u1, u2, u3) { \
        int a_ = a0 + (aa); \
        float w_ = alphas[a_]; \
        if (w_ != 0.f) { \
            const float* ysa = &yss[a_ * 17]; \
            float cv0 = ysa[0] * (u0).x; \
            float cv1 = fmaf(ysa[1], (u0).y, fmaf(ysa[2], (u0).z, ysa[3] * (u0).w)); \
            float cv2 = fmaf(ysa[4], (u1).x, fmaf(ysa[5], (u1).y, fmaf(ysa[6], (u1).z, fmaf(ysa[7], (u1).w, ysa[8] * (u2).x)))); \
            float cv3 = fmaf(ysa[9], (u2).y, fmaf(ysa[10], (u2).z, fmaf(ysa[11], (u2).w, \
                        fmaf(ysa[12], (u3).x, fmaf(ysa[13], (u3).y, fmaf(ysa[14], (u3).z, ysa[15] * (u3).w)))))); \
            float s_ = fmaf(cv0, RO[aa][0], fmaf(cv1, RO[aa][1], fmaf(cv2, RO[aa][2], cv3 * RO[aa][3]))); \
            accO = fmaf(w_, s_, accO); \
        } }
#pragma unroll
        for (int ap = 0; ap < 4; ap++) {
            int aa = ap * 2;
            {
                float4 u0 = A0, u1 = A1, u2 = A2, u3 = A3;
                if (ap < 3) {
                    const float4* p4 = reinterpret_cast<const float4*>(U + (gbase + a0 + aa + 2) * 1024 + j * 16);
                    A0 = p4[0]; A1 = p4[1]; A2 = p4[2]; A3 = p4[3];
                }
                PROC_O(aa, u0, u1, u2, u3)
            }
            {
                float4 u0 = B0, u1 = B1, u2 = B2, u3 = B3;
                if (ap < 3) {
                    const float4* p4 = reinterpret_cast<const float4*>(U + (gbase + a0 + aa + 3) * 1024 + j * 16);
                    B0 = p4[0]; B1 = p4[1]; B2 = p4[2]; B3 = p4[3];
                }
                PROC_O(aa + 1, u0, u1, u2, u3)
            }
        }
#undef PROC_O
    }
    red[t] = accO;
    __syncthreads();
    if (t < 64) agg64s[t] = (red[t] + red[64 + t] + red[128 + t] + red[192 + t]) * sh_inv;
    __syncthreads();

    if (t < 64) {
        float s = 0.f;
#pragma unroll
        for (int c = 0; c < 64; c++) s = fmaf(agg64s[c], WoO[c * 64 + t], s);
        const float* hr = &h[n * 512];
#pragma unroll
        for (int c = 0; c < 32; c++) s = fmaf(hr[c * 16], WskipO[c * 64 + t], s);
        hout[n * 64 + t] = s;
    }
}

__global__ __launch_bounds__(64) void k_final(
    const float* __restrict__ hout, const float* __restrict__ Whid,
    const float* __restrict__ bhid, const float* __restrict__ Wout,
    const float* __restrict__ bout, float* __restrict__ out)
{
    __shared__ float pooled[64], hid[64];
    int g = blockIdx.x, t = threadIdx.x;
    float s = 0.f;
    for (int p = 0; p < 128; p++) s += hout[(g * 128 + p) * 64 + t];
    pooled[t] = s * (1.f / 128.f);
    __syncthreads();
    float hv = bhid[t];
#pragma unroll
    for (int c = 0; c < 64; c++) hv = fmaf(pooled[c], Whid[c * 64 + t], hv);
    hid[t] = fmaxf(hv, 0.f);
    __syncthreads();
    if (t < 15) {
        float o = bout[t];
#pragma unroll
        for (int c = 0; c < 64; c++) o = fmaf(hid[c], Wout[c * 15 + t], o);
        out[g * 15 + t] = o;
    }
}

extern "C" void kernel_launch(void* const* d_in, const int* in_sizes, int n_in,
                              void* d_out, int out_size, void* d_ws, size_t ws_size,
                              hipStream_t stream) {
    const float* x      = (const float*)d_in[0];
    const float* w1     = (const float*)d_in[1];
    const float* b1     = (const float*)d_in[2];
    const float* rW     = (const float*)d_in[3];
    const float* sW     = (const float*)d_in[4];
    const float* Wv     = (const float*)d_in[5];
    const float* Wq     = (const float*)d_in[6];
    const float* Wk     = (const float*)d_in[7];
    const float* Wo     = (const float*)d_in[8];
    const float* Wskip  = (const float*)d_in[9];
    const float* gw     = (const float*)d_in[10];
    const float* gb     = (const float*)d_in[11];
    const float* w1o    = (const float*)d_in[12];
    const float* b1o    = (const float*)d_in[13];
    const float* roW    = (const float*)d_in[14];
    const float* WvO    = (const float*)d_in[15];
    const float* WqO    = (const float*)d_in[16];
    const float* WkO    = (const float*)d_in[17];
    const float* WoO    = (const float*)d_in[18];
    const float* WskipO = (const float*)d_in[19];
    const float* Whid   = (const float*)d_in[20];
    const float* bhid   = (const float*)d_in[21];
    const float* Wout   = (const float*)d_in[22];
    const float* bout   = (const float*)d_in[23];
    float* out = (float*)d_out;

    float* ws = (float*)d_ws;
    float* h0    = ws;
    float* h1    = h0 + NNODE * 512;
    float* vA    = h1 + NNODE * 512;
    float* wqkA  = vA + NNODE * 512;
    float* vB    = wqkA + NNODE * 32;
    float* wqkB  = vB + NNODE * 512;
    float* wq2   = wqkB + NNODE * 32;
    float* U     = wq2 + NNODE * 32;
    float* hout  = U + NNODE * 1024;

    hipMemsetAsync(h0, 0, NNODE * 512 * sizeof(float), stream);
    hipMemsetAsync(vA, 0, (NNODE * 512 + NNODE * 32) * sizeof(float), stream);

    for (int i = 0; i < 4; i++) {
        const float* hc  = (i & 1) ? h1 : h0;
        float*       hn  = (i & 1) ? h0 : h1;
        const float* vin  = (i & 1) ? vB : vA;
        const float* qin  = (i & 1) ? wqkB : wqkA;
        float*       vout = (i & 1) ? vA : vB;
        float*       qout = (i & 1) ? wqkA : wqkB;
        int last = (i == 3);
        k_layer<<<NNODE, 256, 0, stream>>>(
            x, hc, vin, qin, w1, b1, rW, sW, Wskip, Wo, gw, gb,
            Wv + (last ? 0 : (i + 1) * 4096),
            Wq + (last ? 0 : (i + 1) * 1024),
            Wk + (last ? 0 : (i + 1) * 1024),
            WvO, WqO, WkO,
            hn, vout, qout, wq2, U, i, last);
    }
    k_out_edge<<<NNODE, 256, 0, stream>>>(x, h0, w1o, b1o, wq2, roW, U, WoO, WskipO, hout);
    k_final<<<NGRAPH, 64, 0, stream>>>(hout, Whid, bhid, Wout, bout, out);
}

// Round 8
// 986.879 us; speedup vs baseline: 1.1264x; 1.1264x over previous
//
#include <hip/hip_runtime.h>
#include <hip/hip_bf16.h>
#include <hip/hip_fp16.h>

#define NNODE 2048
#define NGRAPH 16

using f16x8 = __attribute__((ext_vector_type(8))) _Float16;
using f32x4 = __attribute__((ext_vector_type(4))) float;

__device__ __forceinline__ int lmap(int m) { return m == 0 ? 0 : (m < 4 ? 1 : (m < 9 ? 2 : 3)); }

__device__ __forceinline__ float f4get(const float4& v, int j) {
    return j == 0 ? v.x : (j == 1 ? v.y : (j == 2 ? v.z : v.w));
}

__device__ __forceinline__ uint32_t f2h2(float a, float b) {
    __half2 h2 = __floats2half2_rn(a, b);
    return *reinterpret_cast<uint32_t*>(&h2);
}
__device__ __forceinline__ float2 h2f2(uint32_t u) {
    __half2 h2 = *reinterpret_cast<__half2*>(&u);
    return __half22float2(h2);
}

__device__ __forceinline__ void sph16(float x, float y, float z, float* Y) {
    Y[0] = 0.28209479177f;
    Y[1] = 0.4886025119f * y; Y[2] = 0.4886025119f * z; Y[3] = 0.4886025119f * x;
    Y[4] = 1.09254843059f * x * y;
    Y[5] = 1.09254843059f * y * z;
    Y[6] = 0.31539156525f * (3.f * z * z - 1.f);
    Y[7] = 1.09254843059f * x * z;
    Y[8] = 0.54627421529f * (x * x - y * y);
    Y[9]  = 0.59004358992f * y * (3.f * x * x - y * y);
    Y[10] = 2.89061144264f * x * y * z;
    Y[11] = 0.45704579946f * y * (5.f * z * z - 1.f);
    Y[12] = 0.37317633259f * z * (5.f * z * z - 3.f);
    Y[13] = 0.45704579946f * x * (5.f * z * z - 1.f);
    Y[14] = 1.44530572132f * z * (x * x - y * y);
    Y[15] = 0.59004358992f * x * (x * x - 3.f * y * y);
}

// process one source (REG) of the current (dh,mt) phase
#define PROC_R(REG, U0, U1, U2, U3, ACC, D, DCOL, ABASE) { \
    int a_ = (ABASE) + (REG); \
    float w_ = alphas[a_]; \
    const float* ysa = &yss[a_ * 17]; \
    float hb1 = h0col[a_ * 33 + (DCOL)] + 1.f; \
    float R0 = D[0][REG], R1 = D[1][REG], R2 = D[2][REG], R3 = D[3][REG]; \
    float Sc0 = D[4][REG] * hb1, Sc1 = D[5][REG] * hb1; \
    float Sc2 = D[6][REG] * hb1, Sc3 = D[7][REG] * hb1; \
    ACC[0]  = fmaf(w_, fmaf((U0).x, R0, Sc0 * ysa[0]),  ACC[0]); \
    ACC[1]  = fmaf(w_, fmaf((U0).y, R1, Sc1 * ysa[1]),  ACC[1]); \
    ACC[2]  = fmaf(w_, fmaf((U0).z, R1, Sc1 * ysa[2]),  ACC[2]); \
    ACC[3]  = fmaf(w_, fmaf((U0).w, R1, Sc1 * ysa[3]),  ACC[3]); \
    ACC[4]  = fmaf(w_, fmaf((U1).x, R2, Sc2 * ysa[4]),  ACC[4]); \
    ACC[5]  = fmaf(w_, fmaf((U1).y, R2, Sc2 * ysa[5]),  ACC[5]); \
    ACC[6]  = fmaf(w_, fmaf((U1).z, R2, Sc2 * ysa[6]),  ACC[6]); \
    ACC[7]  = fmaf(w_, fmaf((U1).w, R2, Sc2 * ysa[7]),  ACC[7]); \
    ACC[8]  = fmaf(w_, fmaf((U2).x, R2, Sc2 * ysa[8]),  ACC[8]); \
    ACC[9]  = fmaf(w_, fmaf((U2).y, R3, Sc3 * ysa[9]),  ACC[9]); \
    ACC[10] = fmaf(w_, fmaf((U2).z, R3, Sc3 * ysa[10]), ACC[10]); \
    ACC[11] = fmaf(w_, fmaf((U2).w, R3, Sc3 * ysa[11]), ACC[11]); \
    ACC[12] = fmaf(w_, fmaf((U3).x, R3, Sc3 * ysa[12]), ACC[12]); \
    ACC[13] = fmaf(w_, fmaf((U3).y, R3, Sc3 * ysa[13]), ACC[13]); \
    ACC[14] = fmaf(w_, fmaf((U3).z, R3, Sc3 * ysa[14]), ACC[14]); \
    ACC[15] = fmaf(w_, fmaf((U3).w, R3, Sc3 * ysa[15]), ACC[15]); \
    }

// one (dh,mt) phase: prefetch 2 vpre rows, 16 MFMAs, epilogue 4 sources (2-deep refill)
#define PHASE(DH, MT, ACC) { \
    const int dcol = (DH) * 16 + n; \
    const int abase = w * 32 + (MT) * 16 + kb * 4; \
    const float4* vr0 = reinterpret_cast<const float4*>(vpre + (gbase + abase + 0) * 512 + dcol * 16); \
    const float4* vr1 = reinterpret_cast<const float4*>(vpre + (gbase + abase + 1) * 512 + dcol * 16); \
    const float4* vr2 = reinterpret_cast<const float4*>(vpre + (gbase + abase + 2) * 512 + dcol * 16); \
    const float4* vr3 = reinterpret_cast<const float4*>(vpre + (gbase + abase + 3) * 512 + dcol * 16); \
    float4 pa0 = vr0[0], pa1 = vr0[1], pa2 = vr0[2], pa3 = vr0[3]; \
    float4 pb0 = vr1[0], pb1 = vr1[1], pb2 = vr1[2], pb3 = vr1[3]; \
    f32x4 D[8]; \
    _Pragma("unroll") \
    for (int q = 0; q < 8; q++) { \
        int nt_ = ((q >> 2) << 3) + ((q & 3) << 1) + (DH); \
        f16x8 Bf = *reinterpret_cast<const f16x8*>(wBH + nt_ * 512 + lane * 8); \
        f32x4 z = {0.f, 0.f, 0.f, 0.f}; \
        z = __builtin_amdgcn_mfma_f32_16x16x32_f16(Ahi[MT], Bf, z, 0, 0, 0); \
        z = __builtin_amdgcn_mfma_f32_16x16x32_f16(Alo[MT], Bf, z, 0, 0, 0); \
        D[q] = z; \
    } \
    { float4 u0 = pa0, u1 = pa1, u2 = pa2, u3 = pa3; \
      pa0 = vr2[0]; pa1 = vr2[1]; pa2 = vr2[2]; pa3 = vr2[3]; \
      PROC_R(0, u0, u1, u2, u3, ACC, D, dcol, abase) } \
    { float4 u0 = pb0, u1 = pb1, u2 = pb2, u3 = pb3; \
      pb0 = vr3[0]; pb1 = vr3[1]; pb2 = vr3[2]; pb3 = vr3[3]; \
      PROC_R(1, u0, u1, u2, u3, ACC, D, dcol, abase) } \
    PROC_R(2, pa0, pa1, pa2, pa3, ACC, D, dcol, abase) \
    PROC_R(3, pb0, pb1, pb2, pb3, ACC, D, dcol, abase) \
}

// One fused layer. 3 blocks/CU (LDS ~51KB).
__global__ __launch_bounds__(256, 3) void k_layer(
    const float* __restrict__ x, const float* __restrict__ h,
    const float* __restrict__ h0in, const float* __restrict__ vpre,
    const float* __restrict__ wqk,
    const float* __restrict__ w1, const float* __restrict__ b1,
    const float* __restrict__ rW, const float* __restrict__ sW,
    const float* __restrict__ Wskip, const float* __restrict__ Wo,
    const float* __restrict__ gw, const float* __restrict__ gb,
    const float* __restrict__ Wv_n, const float* __restrict__ Wq_n, const float* __restrict__ Wk_n,
    const float* __restrict__ WvO, const float* __restrict__ WqO, const float* __restrict__ WkO,
    float* __restrict__ hnew, float* __restrict__ h0out,
    float* __restrict__ vpre_n, float* __restrict__ wqk_n,
    float* __restrict__ wq2, float* __restrict__ U,
    int layer, int last)
{
    // bufA: rh fp16-hi [2560 u32] + fp16-lo [2560 u32]; then h0col[128*33] f32;
    //       then P[4][512] f32; then Wskip / WvO-lo f32
    __shared__ __align__(16) uint32_t bufA[5120];
    // wB: B fragments fp16 [nt=16][lane=64][8] (16KB); later Wo / Wv_n / WvO-hi (f32 bits)
    __shared__ __align__(16) uint32_t wB[4096];
    __shared__ __align__(16) float yss[128 * 17]; // Ys; later hs[512]
    __shared__ __align__(16) float ub[1056];      // phase A: xs[384]|w1s[512]; post: hnS[528]|aggL[528]
    __shared__ float b1s[32];
    __shared__ float wqks[32];
    __shared__ float alphas[128];
    __shared__ float red[256];
    __shared__ float scale[128];
    __shared__ float sh_inv;

    int nblk = blockIdx.x, t = threadIdx.x;
    int g = nblk >> 7, b = nblk & 127;
    int gbase = g << 7;

    float* xs = ub;           // [384]
    float* w1s = ub + 384;    // [512]

    for (int o = t; o < 384; o += 256) xs[o] = x[gbase * 3 + o];
    for (int o = t; o < 512; o += 256) w1s[o] = w1[layer * 512 + o];
    if (t < 32) { b1s[t] = b1[layer * 32 + t]; wqks[t] = wqk[nblk * 32 + t]; }
    // stage rW|sW as fp16 B-fragments: nt = rs*8 + l*2 + dh, lane = kb*16 + (d&15), pair along j
    for (int idx = t; idx < 4096; idx += 256) {
        int d2 = idx & 31, j2 = (idx >> 5) & 15, l = (idx >> 9) & 3, rs = idx >> 11;
        const float* W = rs ? sW : rW;
        int srcb = layer * 4096 + l * 1024 + (2 * j2) * 32 + d2;
        float v0 = W[srcb], v1 = W[srcb + 32];
        int nt = rs * 8 + l * 2 + (d2 >> 4);
        int lid = ((j2 >> 2) << 4) + (d2 & 15);
        wB[nt * 256 + lid * 4 + (j2 & 3)] = f2h2(v0, v1);
    }
    __syncthreads();

    // ---- phase A: geometry, rh (stored as fp16 hi+lo), partial logit ----
    {
        int a = t & 127, dh = t >> 7;
        float rx = xs[b * 3 + 0] - xs[a * 3 + 0];
        float ry = xs[b * 3 + 1] - xs[a * 3 + 1];
        float rz = xs[b * 3 + 2] - xs[a * 3 + 2];
        float dd = sqrtf(rx * rx + ry * ry + rz * rz + 1e-12f);
        float inv = 1.f / dd;
        float ys[16];
        sph16(rx * inv, ry * inv, rz * inv, ys);
        if (dh == 0) {
#pragma unroll
            for (int m = 0; m < 16; m++) yss[a * 17 + m] = ys[m];
        }
        float rbf[16];
#pragma unroll
        for (int j = 0; j < 16; j++) {
            float dc = dd - (4.f / 15.f) * j;
            rbf[j] = __expf(-2.f * dc * dc);
        }
        float lpart = 0.f;
        int d0 = dh * 16;
        float sprev = 0.f;
        for (int d2 = 0; d2 < 16; d2++) {
            int d = d0 + d2;
            float s = b1s[d];
#pragma unroll
            for (int j = 0; j < 16; j++) s = fmaf(rbf[j], w1s[j * 32 + d], s);
            s = fmaxf(s, 0.f);
            lpart = fmaf(s, wqks[d], lpart);
            if (d2 & 1) {
                __half h0 = __float2half_rn(sprev), h1 = __float2half_rn(s);
                float l0f = sprev - __half2float(h0), l1f = s - __half2float(h1);
                uint32_t hp = (uint32_t)__half_as_ushort(h0) |
                              ((uint32_t)__half_as_ushort(h1) << 16);
                uint32_t lp = (uint32_t)__half_as_ushort(__float2half_rn(l0f)) |
                              ((uint32_t)__half_as_ushort(__float2half_rn(l1f)) << 16);
                int wi = a * 20 + dh * 8 + (d2 >> 1);
                bufA[wi] = hp;
                bufA[2560 + wi] = lp;
            }
            sprev = s;
        }
        red[t] = lpart;
    }
    __syncthreads();
    if (t < 128) alphas[t] = (red[t] + red[t + 128]) * 0.17677669529663687f; // 1/sqrt(32)
    __syncthreads();

    // ---- segment softmax over 127 valid edges (wave shuffle reductions) ----
    if (t < 128) {
        float m = (t != b) ? alphas[t] : -1e30f;
#pragma unroll
        for (int off = 32; off > 0; off >>= 1) m = fmaxf(m, __shfl_xor(m, off));
        if ((t & 63) == 0) red[t >> 6] = m;
    }
    __syncthreads();
    {
        float mx = fmaxf(red[0], red[1]);
        if (t < 128) {
            float e = (t != b) ? __expf(alphas[t] - mx) : 0.f;
            alphas[t] = e;
            float s = e;
#pragma unroll
            for (int off = 32; off > 0; off >>= 1) s += __shfl_xor(s, off);
            if ((t & 63) == 0) red[2 + (t >> 6)] = s;
        }
    }
    __syncthreads();
    if (t == 0) sh_inv = 1.f / (red[2] + red[3]);

    // ---- pass 2: MFMA R/S GEMM + pipelined weighted aggregate ----
    int lane = t & 63, w = t >> 6;
    int n = lane & 15, kb = lane >> 4;

    const _Float16* rhHiH = reinterpret_cast<const _Float16*>(bufA);
    const _Float16* rhLoH = reinterpret_cast<const _Float16*>(bufA + 2560);
    const _Float16* wBH   = reinterpret_cast<const _Float16*>(wB);

    f16x8 Ahi[2], Alo[2];
#pragma unroll
    for (int mt = 0; mt < 2; mt++) {
        int row = (w * 2 + mt) * 16 + n;
        Ahi[mt] = *reinterpret_cast<const f16x8*>(rhHiH + row * 40 + kb * 8);
        Alo[mt] = *reinterpret_cast<const f16x8*>(rhLoH + row * 40 + kb * 8);
    }
    __syncthreads();   // all bufA (rh) reads done

    // stage h0 column from dense sidecar: h0col[a*33+d] = h0in[gbase*32 + a*32 + d]
    float* h0col = reinterpret_cast<float*>(bufA);
    for (int idx = t; idx < 4096; idx += 256)
        h0col[(idx >> 5) * 33 + (idx & 31)] = h0in[gbase * 32 + idx];
    __syncthreads();   // h0col ready

    float acc0[16], acc1[16];
#pragma unroll
    for (int m = 0; m < 16; m++) { acc0[m] = 0.f; acc1[m] = 0.f; }

    PHASE(0, 0, acc0)
    PHASE(0, 1, acc0)
    PHASE(1, 0, acc1)
    PHASE(1, 1, acc1)

    // cross-kb butterfly reduce (sources within wave)
#pragma unroll
    for (int m = 0; m < 16; m++) {
        float v0 = acc0[m];
        v0 += __shfl_xor(v0, 16); v0 += __shfl_xor(v0, 32);
        acc0[m] = v0;
        float v1 = acc1[m];
        v1 += __shfl_xor(v1, 16); v1 += __shfl_xor(v1, 32);
        acc1[m] = v1;
    }
    __syncthreads();   // all pass-2 LDS reads (h0col/wB/yss) done

    // S1: partials into P (overlay bufA); stage h[n] (overlay yss); stage Wo into wB
    float* P = reinterpret_cast<float*>(bufA);
    if (lane < 16) {
#pragma unroll
        for (int m = 0; m < 16; m++) {
            P[w * 512 + m * 16 + n] = acc0[m];
            P[w * 512 + 256 + m * 16 + n] = acc1[m];
        }
    }
    float* hs = yss;
    for (int o = t; o < 512; o += 256) hs[o] = h[nblk * 512 + o];
    for (int o = t; o < 4096; o += 256) wB[o] = __float_as_uint(Wo[layer * 4096 + o]);
    __syncthreads();

    // S2: reduce partials -> aggL[m*33+c]  (c = dh*16 + n)
    float* hnS = ub;          // [528]
    float* aggL = ub + 528;   // [528]
    float invs = sh_inv;
    for (int o = t; o < 512; o += 256) {
        int m = o >> 5, c = o & 31;
        int dh = c >> 4, nn = c & 15;
        float s = 0.f;
#pragma unroll
        for (int ww = 0; ww < 4; ww++) s += P[ww * 512 + dh * 256 + m * 16 + nn];
        aggL[m * 33 + c] = s * invs;
    }
    __syncthreads();

    // S3: stage Wskip into bufA (fp32), P dead
    float* bufF = reinterpret_cast<float*>(bufA);
    for (int o = t; o < 4096; o += 256) bufF[o] = Wskip[layer * 4096 + o];
    __syncthreads();

    // S4: post GEMM: hn = h@Wskip + agg@Wo
    for (int o = t; o < 512; o += 256) {
        int m = o >> 5, dd = o & 31, l = lmap(m);
        float s = 0.f;
        const float* wa = &bufF[l * 1024 + dd];
        const uint32_t* wb = &wB[l * 1024 + dd];
        const float* hrow = &hs[m];
        const float* arow = &aggL[m * 33];
#pragma unroll
        for (int c = 0; c < 32; c++) {
            s = fmaf(hrow[c * 16], wa[c * 32], s);
            s = fmaf(arow[c], __uint_as_float(wb[c * 32]), s);
        }
        hnS[m * 33 + dd] = s;
    }
    __syncthreads();

    // S5: norm gate compute + stage next-stage value weights
    if (t < 128) {
        int dd = t >> 2, l = t & 3;
        int m0 = l * l, cnt = 2 * l + 1;
        float s = 1e-12f;
        for (int m = m0; m < m0 + cnt; m++) { float v = hnS[m * 33 + dd]; s = fmaf(v, v, s); }
        float nr = sqrtf(s);
        float phi = fmaxf(nr * gw[(layer * 4 + l) * 32 + dd] + gb[(layer * 4 + l) * 32 + dd], 0.f);
        scale[dd * 4 + l] = phi / (nr + 1e-6f);
    }
    if (!last) {
        for (int o = t; o < 4096; o += 256) wB[o] = __float_as_uint(Wv_n[o]);
    } else {
        for (int o = t; o < 4096; o += 256) {
            bufF[o] = WvO[o];                               // l = 0,1
            wB[o] = __float_as_uint(WvO[4096 + o]);         // l = 2,3
        }
    }
    __syncthreads();

    // S6: apply gate, write hnew + dense h0 sidecar
    for (int o = t; o < 512; o += 256) {
        int dd = o >> 4, m = o & 15;
        float v = hnS[m * 33 + dd] * scale[dd * 4 + lmap(m)];
        hnew[nblk * 512 + o] = v;
        hnS[m * 33 + dd] = v;
        if (m == 0) h0out[nblk * 32 + dd] = v;
    }
    __syncthreads();

    if (!last) {
        for (int o = t; o < 512; o += 256) {
            int dd = o >> 4, m = o & 15, l = lmap(m);
            float s = 0.f;
            const uint32_t* wv = &wB[l * 1024 + dd];
            const float* hrow = &hnS[m * 33];
#pragma unroll
            for (int c = 0; c < 32; c++) s = fmaf(hrow[c], __uint_as_float(wv[c * 32]), s);
            vpre_n[nblk * 512 + o] = s;
        }
        if (t < 32) {
            float s = 0.f;
#pragma unroll
            for (int c = 0; c < 32; c++) s = fmaf(hnS[c * 33], Wq_n[c * 32 + t], s);
            red[t] = s;
        }
        __syncthreads();
        if (t < 32) {
            float s = 0.f;
#pragma unroll
            for (int j = 0; j < 32; j++) s = fmaf(Wk_n[t * 32 + j], red[j], s);
            wqk_n[nblk * 32 + t] = s;
        }
    } else {
        for (int o = t; o < 1024; o += 256) {
            int j = o >> 4, m = o & 15, l = lmap(m);
            float s = 0.f;
            const float* hrow = &hnS[m * 33];
            if (l < 2) {
                const float* wv = &bufF[l * 2048 + j];
#pragma unroll
                for (int c = 0; c < 32; c++) s = fmaf(hrow[c], wv[c * 64], s);
            } else {
                const uint32_t* wv = &wB[(l - 2) * 2048 + j];
#pragma unroll
                for (int c = 0; c < 32; c++) s = fmaf(hrow[c], __uint_as_float(wv[c * 64]), s);
            }
            U[nblk * 1024 + o] = s;
        }
        if (t < 64) {
            float s = 0.f;
#pragma unroll
            for (int c = 0; c < 32; c++) s = fmaf(hnS[c * 33], WqO[c * 64 + t], s);
            red[t] = s;
        }
        __syncthreads();
        if (t < 32) {
            float s = 0.f;
#pragma unroll
            for (int j = 0; j < 64; j++) s = fmaf(WkO[t * 64 + j], red[j], s);
            wq2[nblk * 32 + t] = s;
        }
    }
}

// Output-stage edge kernel + fused out_post (hout). 3 blocks/CU.
__global__ __launch_bounds__(256, 3) void k_out_edge(
    const float* __restrict__ x, const float* __restrict__ h0f,
    const float* __restrict__ w1o, const float* __restrict__ b1o,
    const float* __restrict__ wq2, const float* __restrict__ roW,
    const float* __restrict__ U, const float* __restrict__ WoO,
    const float* __restrict__ WskipO, float* __restrict__ hout)
{
    __shared__ uint32_t rosP[4096];               // fp16 pairs of roW c-neighbors
    __shared__ __align__(16) float rhs[128 * 36];
    __shared__ __align__(16) float yss[128 * 17];
    __shared__ float xs[384];
    __shared__ float w1s[512];
    __shared__ float b1s[32];
    __shared__ float wq2s[32];
    __shared__ float alphas[128];
    __shared__ float red[256];
    __shared__ float agg64s[64];
    __shared__ float sh_inv;

    int n = blockIdx.x, t = threadIdx.x;
    int g = n >> 7, b = n & 127;
    int gbase = g << 7;

    for (int o = t; o < 384; o += 256) xs[o] = x[gbase * 3 + o];
    for (int o = t; o < 512; o += 256) w1s[o] = w1o[o];
    if (t < 32) { b1s[t] = b1o[t]; wq2s[t] = wq2[n * 32 + t]; }
    for (int o = t; o < 4096; o += 256) {
        int j = o & 63, lc = o >> 6, cp = lc & 15, l = lc >> 4;
        rosP[o] = f2h2(roW[(l * 32 + 2 * cp) * 64 + j], roW[(l * 32 + 2 * cp + 1) * 64 + j]);
    }
    __syncthreads();

    // phase A split across 256 threads
    {
        int a = t & 127, dh = t >> 7;
        float rx = xs[b * 3 + 0] - xs[a * 3 + 0];
        float ry = xs[b * 3 + 1] - xs[a * 3 + 1];
        float rz = xs[b * 3 + 2] - xs[a * 3 + 2];
        float dd = sqrtf(rx * rx + ry * ry + rz * rz + 1e-12f);
        float inv = 1.f / dd;
        float ys[16];
        sph16(rx * inv, ry * inv, rz * inv, ys);
        if (dh == 0) {
#pragma unroll
            for (int m = 0; m < 16; m++) yss[a * 17 + m] = ys[m];
        }
        float rbf[16];
#pragma unroll
        for (int j = 0; j < 16; j++) {
            float dc = dd - (4.f / 15.f) * j;
            rbf[j] = __expf(-2.f * dc * dc);
        }
        float lpart = 0.f;
        int d0 = dh * 16;
        for (int d2 = 0; d2 < 16; d2++) {
            int d = d0 + d2;
            float s = b1s[d];
#pragma unroll
            for (int j = 0; j < 16; j++) s = fmaf(rbf[j], w1s[j * 32 + d], s);
            s = fmaxf(s, 0.f);
            rhs[a * 36 + d] = s;
            lpart = fmaf(s, wq2s[d], lpart);
        }
        red[t] = lpart;
    }
    __syncthreads();
    if (t < 128) alphas[t] = (red[t] + red[t + 128]) * 0.125f; // 1/sqrt(64)
    __syncthreads();

    if (t < 128) {
        float m = (t != b) ? alphas[t] : -1e30f;
#pragma unroll
        for (int off = 32; off > 0; off >>= 1) m = fmaxf(m, __shfl_xor(m, off));
        if ((t & 63) == 0) red[t >> 6] = m;
    }
    __syncthreads();
    {
        float mx = fmaxf(red[0], red[1]);
        if (t < 128) {
            float e = (t != b) ? __expf(alphas[t] - mx) : 0.f;
            alphas[t] = e;
            float s = e;
#pragma unroll
            for (int off = 32; off > 0; off >>= 1) s += __shfl_xor(s, off);
            if ((t & 63) == 0) red[2 + (t >> 6)] = s;
        }
    }
    __syncthreads();
    if (t == 0) sh_inv = 1.f / (red[2] + red[3]);
    __syncthreads();

    int grp = t >> 6, j = t & 63;
    float accO = 0.f;
    for (int chunk = 0; chunk < 4; chunk++) {
        int a0 = grp * 32 + chunk * 8;
        float RO[8][4];
#pragma unroll
        for (int aa = 0; aa < 8; aa++)
#pragma unroll
            for (int l = 0; l < 4; l++) RO[aa][l] = 0.f;

#pragma unroll 2
        for (int cq = 0; cq < 8; cq++) {
            float4 rh4[8];
#pragma unroll
            for (int aa = 0; aa < 8; aa++)
                rh4[aa] = *reinterpret_cast<const float4*>(&rhs[(a0 + aa) * 36 + cq * 4]);
#pragma unroll
            for (int l = 0; l < 4; l++) {
#pragma unroll
                for (int ch = 0; ch < 2; ch++) {
                    float2 w2 = h2f2(rosP[(l * 16 + cq * 2 + ch) * 64 + j]);
#pragma unroll
                    for (int aa = 0; aa < 8; aa++) {
                        RO[aa][l] = fmaf(f4get(rh4[aa], 2 * ch), w2.x, RO[aa][l]);
                        RO[aa][l] = fmaf(f4get(rh4[aa], 2 * ch + 1), w2.y, RO[aa][l]);
                    }
                }
            }
        }

        float4 A0, A1, A2, A3, B0, B1, B2, B3;
        {
            const float4* p4 = reinterpret_cast<const float4*>(U + (gbase + a0) * 1024 + j * 16);
            A0 = p4[0]; A1 = p4[1]; A2 = p4[2]; A3 = p4[3];
            const float4* q4 = reinterpret_cast<const float4*>(U + (gbase + a0 + 1) * 1024 + j * 16);
            B0 = q4[0]; B1 = q4[1]; B2 = q4[2]; B3 = q4[3];
        }
#define PROC_O(aa, u0, u1, u2, u3) { \
        int a_ = a0 + (aa); \
        float w_ = alphas[a_]; \
        if (w_ != 0.f) { \
            const float* ysa = &yss[a_ * 17]; \
            float cv0 = ysa[0] * (u0).x; \
            float cv1 = fmaf(ysa[1], (u0).y, fmaf(ysa[2], (u0).z, ysa[3] * (u0).w)); \
            float cv2 = fmaf(ysa[4], (u1).x, fmaf(ysa[5], (u1).y, fmaf(ysa[6], (u1).z, fmaf(ysa[7], (u1).w, ysa[8] * (u2).x)))); \
            float cv3 = fmaf(ysa[9], (u2).y, fmaf(ysa[10], (u2).z, fmaf(ysa[11], (u2).w, \
                        fmaf(ysa[12], (u3).x, fmaf(ysa[13], (u3).y, fmaf(ysa[14], (u3).z, ysa[15] * (u3).w)))))); \
            float s_ = fmaf(cv0, RO[aa][0], fmaf(cv1, RO[aa][1], fmaf(cv2, RO[aa][2], cv3 * RO[aa][3]))); \
            accO = fmaf(w_, s_, accO); \
        } }
#pragma unroll
        for (int ap = 0; ap < 4; ap++) {
            int aa = ap * 2;
            {
                float4 u0 = A0, u1 = A1, u2 = A2, u3 = A3;
                if (ap < 3) {
                    const float4* p4 = reinterpret_cast<const float4*>(U + (gbase + a0 + aa + 2) * 1024 + j * 16);
                    A0 = p4[0]; A1 = p4[1]; A2 = p4[2]; A3 = p4[3];
                }
                PROC_O(aa, u0, u1, u2, u3)
            }
            {
                float4 u0 = B0, u1 = B1, u2 = B2, u3 = B3;
                if (ap < 3) {
                    const float4* p4 = reinterpret_cast<const float4*>(U + (gbase + a0 + aa + 3) * 1024 + j * 16);
                    B0 = p4[0]; B1 = p4[1]; B2 = p4[2]; B3 = p4[3];
                }
                PROC_O(aa + 1, u0, u1, u2, u3)
            }
        }
#undef PROC_O
    }
    red[t] = accO;
    __syncthreads();
    if (t < 64) agg64s[t] = (red[t] + red[64 + t] + red[128 + t] + red[192 + t]) * sh_inv;
    __syncthreads();

    if (t < 64) {
        float s = 0.f;
#pragma unroll
        for (int c = 0; c < 64; c++) s = fmaf(agg64s[c], WoO[c * 64 + t], s);
        const float* hr = &h0f[n * 32];
#pragma unroll
        for (int c = 0; c < 32; c++) s = fmaf(hr[c], WskipO[c * 64 + t], s);
        hout[n * 64 + t] = s;
    }
}

__global__ __launch_bounds__(64) void k_final(
    const float* __restrict__ hout, const float* __restrict__ Whid,
    const float* __restrict__ bhid, const float* __restrict__ Wout,
    const float* __restrict__ bout, float* __restrict__ out)
{
    __shared__ float pooled[64], hid[64];
    int g = blockIdx.x, t = threadIdx.x;
    float s = 0.f;
    for (int p = 0; p < 128; p++) s += hout[(g * 128 + p) * 64 + t];
    pooled[t] = s * (1.f / 128.f);
    __syncthreads();
    float hv = bhid[t];
#pragma unroll
    for (int c = 0; c < 64; c++) hv = fmaf(pooled[c], Whid[c * 64 + t], hv);
    hid[t] = fmaxf(hv, 0.f);
    __syncthreads();
    if (t < 15) {
        float o = bout[t];
#pragma unroll
        for (int c = 0; c < 64; c++) o = fmaf(hid[c], Wout[c * 15 + t], o);
        out[g * 15 + t] = o;
    }
}

extern "C" void kernel_launch(void* const* d_in, const int* in_sizes, int n_in,
                              void* d_out, int out_size, void* d_ws, size_t ws_size,
                              hipStream_t stream) {
    const float* x      = (const float*)d_in[0];
    const float* w1     = (const float*)d_in[1];
    const float* b1     = (const float*)d_in[2];
    const float* rW     = (const float*)d_in[3];
    const float* sW     = (const float*)d_in[4];
    const float* Wv     = (const float*)d_in[5];
    const float* Wq     = (const float*)d_in[6];
    const float* Wk     = (const float*)d_in[7];
    const float* Wo     = (const float*)d_in[8];
    const float* Wskip  = (const float*)d_in[9];
    const float* gw     = (const float*)d_in[10];
    const float* gb     = (const float*)d_in[11];
    const float* w1o    = (const float*)d_in[12];
    const float* b1o    = (const float*)d_in[13];
    const float* roW    = (const float*)d_in[14];
    const float* WvO    = (const float*)d_in[15];
    const float* WqO    = (const float*)d_in[16];
    const float* WkO    = (const float*)d_in[17];
    const float* WoO    = (const float*)d_in[18];
    const float* WskipO = (const float*)d_in[19];
    const float* Whid   = (const float*)d_in[20];
    const float* bhid   = (const float*)d_in[21];
    const float* Wout   = (const float*)d_in[22];
    const float* bout   = (const float*)d_in[23];
    float* out = (float*)d_out;

    float* ws = (float*)d_ws;
    float* h0    = ws;
    float* h1    = h0 + NNODE * 512;
    float* vA    = h1 + NNODE * 512;
    float* wqkA  = vA + NNODE * 512;
    float* vB    = wqkA + NNODE * 32;
    float* wqkB  = vB + NNODE * 512;
    float* wq2   = wqkB + NNODE * 32;
    float* U     = wq2 + NNODE * 32;
    float* hout  = U + NNODE * 1024;
    float* s0A   = hout + NNODE * 64;
    float* s0B   = s0A + NNODE * 32;

    hipMemsetAsync(h0, 0, NNODE * 512 * sizeof(float), stream);
    hipMemsetAsync(vA, 0, (NNODE * 512 + NNODE * 32) * sizeof(float), stream);
    hipMemsetAsync(s0A, 0, NNODE * 32 * sizeof(float), stream);

    for (int i = 0; i < 4; i++) {
        const float* hc  = (i & 1) ? h1 : h0;
        float*       hn  = (i & 1) ? h0 : h1;
        const float* vin  = (i & 1) ? vB : vA;
        const float* qin  = (i & 1) ? wqkB : wqkA;
        float*       vout = (i & 1) ? vA : vB;
        float*       qout = (i & 1) ? wqkA : wqkB;
        const float* s0in = (i & 1) ? s0B : s0A;
        float*       s0out= (i & 1) ? s0A : s0B;
        int last = (i == 3);
        k_layer<<<NNODE, 256, 0, stream>>>(
            x, hc, s0in, vin, qin, w1, b1, rW, sW, Wskip, Wo, gw, gb,
            Wv + (last ? 0 : (i + 1) * 4096),
            Wq + (last ? 0 : (i + 1) * 1024),
            Wk + (last ? 0 : (i + 1) * 1024),
            WvO, WqO, WkO,
            hn, s0out, vout, qout, wq2, U, i, last);
    }
    // final h0 sidecar: i=3 wrote s0A
    k_out_edge<<<NNODE, 256, 0, stream>>>(x, s0A, w1o, b1o, wq2, roW, U, WoO, WskipO, hout);
    k_final<<<NGRAPH, 64, 0, stream>>>(hout, Whid, bhid, Wout, bout, out);
}

// Round 9
// 701.748 us; speedup vs baseline: 1.5841x; 1.4063x over previous
//
#include <hip/hip_runtime.h>
#include <hip/hip_bf16.h>
#include <hip/hip_fp16.h>

#define NNODE 2048
#define NGRAPH 16

__device__ __forceinline__ int lmap(int m) { return m == 0 ? 0 : (m < 4 ? 1 : (m < 9 ? 2 : 3)); }

__device__ __forceinline__ float f4get(const float4& v, int j) {
    return j == 0 ? v.x : (j == 1 ? v.y : (j == 2 ? v.z : v.w));
}

// pack two floats as fp16 pair in a u32 (lo = a, hi = b)
__device__ __forceinline__ uint32_t f2h2(float a, float b) {
    __half2 h2 = __floats2half2_rn(a, b);
    return *reinterpret_cast<uint32_t*>(&h2);
}
__device__ __forceinline__ float2 h2f2(uint32_t u) {
    __half2 h2 = *reinterpret_cast<__half2*>(&u);
    return __half22float2(h2);
}

__device__ __forceinline__ void sph16(float x, float y, float z, float* Y) {
    Y[0] = 0.28209479177f;
    Y[1] = 0.4886025119f * y; Y[2] = 0.4886025119f * z; Y[3] = 0.4886025119f * x;
    Y[4] = 1.09254843059f * x * y;
    Y[5] = 1.09254843059f * y * z;
    Y[6] = 0.31539156525f * (3.f * z * z - 1.f);
    Y[7] = 1.09254843059f * x * z;
    Y[8] = 0.54627421529f * (x * x - y * y);
    Y[9]  = 0.59004358992f * y * (3.f * x * x - y * y);
    Y[10] = 2.89061144264f * x * y * z;
    Y[11] = 0.45704579946f * y * (5.f * z * z - 1.f);
    Y[12] = 0.37317633259f * z * (5.f * z * z - 3.f);
    Y[13] = 0.45704579946f * x * (5.f * z * z - 1.f);
    Y[14] = 1.44530572132f * z * (x * x - y * y);
    Y[15] = 0.59004358992f * x * (x * x - 3.f * y * y);
}

#define PROC_SRC(aa, u0, u1, u2, u3, h0v) { \
    int a_ = a0 + (aa); \
    float w_ = alphas[a_]; \
    const float* ysa = &yss[a_ * 17]; \
    float hb1 = (h0v) + 1.f; \
    float sc0 = S[aa][0] * hb1, sc1 = S[aa][1] * hb1; \
    float sc2 = S[aa][2] * hb1, sc3 = S[aa][3] * hb1; \
    acc[0]  = fmaf(w_, fmaf((u0).x, R[aa][0], sc0 * ysa[0]),  acc[0]); \
    acc[1]  = fmaf(w_, fmaf((u0).y, R[aa][1], sc1 * ysa[1]),  acc[1]); \
    acc[2]  = fmaf(w_, fmaf((u0).z, R[aa][1], sc1 * ysa[2]),  acc[2]); \
    acc[3]  = fmaf(w_, fmaf((u0).w, R[aa][1], sc1 * ysa[3]),  acc[3]); \
    acc[4]  = fmaf(w_, fmaf((u1).x, R[aa][2], sc2 * ysa[4]),  acc[4]); \
    acc[5]  = fmaf(w_, fmaf((u1).y, R[aa][2], sc2 * ysa[5]),  acc[5]); \
    acc[6]  = fmaf(w_, fmaf((u1).z, R[aa][2], sc2 * ysa[6]),  acc[6]); \
    acc[7]  = fmaf(w_, fmaf((u1).w, R[aa][2], sc2 * ysa[7]),  acc[7]); \
    acc[8]  = fmaf(w_, fmaf((u2).x, R[aa][2], sc2 * ysa[8]),  acc[8]); \
    acc[9]  = fmaf(w_, fmaf((u2).y, R[aa][3], sc3 * ysa[9]),  acc[9]); \
    acc[10] = fmaf(w_, fmaf((u2).z, R[aa][3], sc3 * ysa[10]), acc[10]); \
    acc[11] = fmaf(w_, fmaf((u2).w, R[aa][3], sc3 * ysa[11]), acc[11]); \
    acc[12] = fmaf(w_, fmaf((u3).x, R[aa][3], sc3 * ysa[12]), acc[12]); \
    acc[13] = fmaf(w_, fmaf((u3).y, R[aa][3], sc3 * ysa[13]), acc[13]); \
    acc[14] = fmaf(w_, fmaf((u3).z, R[aa][3], sc3 * ysa[14]), acc[14]); \
    acc[15] = fmaf(w_, fmaf((u3).w, R[aa][3], sc3 * ysa[15]), acc[15]); \
    }

// One fused layer. 3 blocks/CU (LDS ~49KB).
__global__ __launch_bounds__(256, 3) void k_layer(
    const float* __restrict__ x, const float* __restrict__ h,
    const float* __restrict__ h0in, const float* __restrict__ vpre,
    const float* __restrict__ wqk,
    const float* __restrict__ w1, const float* __restrict__ b1,
    const float* __restrict__ rW, const float* __restrict__ sW,
    const float* __restrict__ Wskip, const float* __restrict__ Wo,
    const float* __restrict__ gw, const float* __restrict__ gb,
    const float* __restrict__ Wv_n, const float* __restrict__ Wq_n, const float* __restrict__ Wk_n,
    const float* __restrict__ WvO, const float* __restrict__ WqO, const float* __restrict__ WkO,
    float* __restrict__ hnew, float* __restrict__ h0out,
    float* __restrict__ vpre_n, float* __restrict__ wqk_n,
    float* __restrict__ wq2, float* __restrict__ U,
    int layer, int last)
{
    __shared__ uint32_t rwswP[4096];             // fp16 pair (rW,sW); later float-bits Wo / Wv_n / WvO-hi
    __shared__ __align__(16) float rhs[128 * 36]; // rh; later P[8][528]; later wsk / WvO-lo
    __shared__ __align__(16) float yss[128 * 17]; // Ys; later hs[512]
    __shared__ __align__(16) float ub[1056];      // phase A: xs[384]|w1s[512]; post: hnS[528]|aggL[528]
    __shared__ float b1s[32];
    __shared__ float wqks[32];
    __shared__ float alphas[128];
    __shared__ float red[256];
    __shared__ float scale[128];
    __shared__ float sh_inv;

    int nblk = blockIdx.x, t = threadIdx.x;
    int g = nblk >> 7, b = nblk & 127;
    int gbase = g << 7;

    float* xs = ub;           // [384]
    float* w1s = ub + 384;    // [512]

    for (int o = t; o < 384; o += 256) xs[o] = x[gbase * 3 + o];
    for (int o = t; o < 512; o += 256) w1s[o] = w1[layer * 512 + o];
    if (t < 32) { b1s[t] = b1[layer * 32 + t]; wqks[t] = wqk[nblk * 32 + t]; }
    for (int o = t; o < 4096; o += 256)
        rwswP[o] = f2h2(rW[layer * 4096 + o], sW[layer * 4096 + o]);
    __syncthreads();

    // ---- phase A: geometry, rh, partial logit (all 256 threads; 2 d-halves) ----
    {
        int a = t & 127, dh = t >> 7;
        float rx = xs[b * 3 + 0] - xs[a * 3 + 0];
        float ry = xs[b * 3 + 1] - xs[a * 3 + 1];
        float rz = xs[b * 3 + 2] - xs[a * 3 + 2];
        float dd = sqrtf(rx * rx + ry * ry + rz * rz + 1e-12f);
        float inv = 1.f / dd;
        float ys[16];
        sph16(rx * inv, ry * inv, rz * inv, ys);
        if (dh == 0) {
#pragma unroll
            for (int m = 0; m < 16; m++) yss[a * 17 + m] = ys[m];
        }
        float rbf[16];
#pragma unroll
        for (int j = 0; j < 16; j++) {
            float dc = dd - (4.f / 15.f) * j;
            rbf[j] = __expf(-2.f * dc * dc);
        }
        float lpart = 0.f;
        int d0 = dh * 16;
        for (int d2 = 0; d2 < 16; d2++) {
            int d = d0 + d2;
            float s = b1s[d];
#pragma unroll
            for (int j = 0; j < 16; j++) s = fmaf(rbf[j], w1s[j * 32 + d], s);
            s = fmaxf(s, 0.f);
            rhs[a * 36 + d] = s;
            lpart = fmaf(s, wqks[d], lpart);
        }
        red[t] = lpart;
    }
    __syncthreads();
    if (t < 128) alphas[t] = (red[t] + red[t + 128]) * 0.17677669529663687f; // 1/sqrt(32)
    __syncthreads();

    // ---- segment softmax over 127 valid edges (wave shuffle reductions) ----
    if (t < 128) {
        float m = (t != b) ? alphas[t] : -1e30f;
#pragma unroll
        for (int off = 32; off > 0; off >>= 1) m = fmaxf(m, __shfl_xor(m, off));
        if ((t & 63) == 0) red[t >> 6] = m;
    }
    __syncthreads();
    {
        float mx = fmaxf(red[0], red[1]);
        if (t < 128) {
            float e = (t != b) ? __expf(alphas[t] - mx) : 0.f;
            alphas[t] = e;
            float s = e;
#pragma unroll
            for (int off = 32; off > 0; off >>= 1) s += __shfl_xor(s, off);
            if ((t & 63) == 0) red[2 + (t >> 6)] = s;
        }
    }
    __syncthreads();
    if (t == 0) sh_inv = 1.f / (red[2] + red[3]);

    // ---- pass 2: register-blocked R/S GEMM + weighted aggregate ----
    int grp = t >> 5, d = t & 31;
    float acc[16];
#pragma unroll
    for (int m = 0; m < 16; m++) acc[m] = 0.f;

    for (int chunk = 0; chunk < 2; chunk++) {
        int a0 = grp * 16 + chunk * 8;
        float R[8][4], S[8][4];
#pragma unroll
        for (int aa = 0; aa < 8; aa++)
#pragma unroll
            for (int l = 0; l < 4; l++) { R[aa][l] = 0.f; S[aa][l] = 0.f; }

#pragma unroll 2
        for (int jq = 0; jq < 8; jq++) {
            float4 rh4[8];
#pragma unroll
            for (int aa = 0; aa < 8; aa++)
                rh4[aa] = *reinterpret_cast<const float4*>(&rhs[(a0 + aa) * 36 + jq * 4]);
#pragma unroll
            for (int l = 0; l < 4; l++) {
#pragma unroll
                for (int jj = 0; jj < 4; jj++) {
                    float2 w2 = h2f2(rwswP[(l * 32 + jq * 4 + jj) * 32 + d]);
#pragma unroll
                    for (int aa = 0; aa < 8; aa++) {
                        float rv = f4get(rh4[aa], jj);
                        R[aa][l] = fmaf(rv, w2.x, R[aa][l]);
                        S[aa][l] = fmaf(rv, w2.y, S[aa][l]);
                    }
                }
            }
        }

        // epilogue: 2-deep double-buffered global loads (vpre rows + dense h0 sidecar)
        float4 A0, A1, A2, A3, B0, B1, B2, B3; float Ah, Bh;
        {
            const float4* p4 = reinterpret_cast<const float4*>(vpre + (gbase + a0) * 512 + d * 16);
            A0 = p4[0]; A1 = p4[1]; A2 = p4[2]; A3 = p4[3];
            Ah = h0in[(gbase + a0) * 32 + d];
            const float4* q4 = reinterpret_cast<const float4*>(vpre + (gbase + a0 + 1) * 512 + d * 16);
            B0 = q4[0]; B1 = q4[1]; B2 = q4[2]; B3 = q4[3];
            Bh = h0in[(gbase + a0 + 1) * 32 + d];
        }
#pragma unroll
        for (int ap = 0; ap < 4; ap++) {
            int aa = ap * 2;
            {
                float4 u0 = A0, u1 = A1, u2 = A2, u3 = A3; float h0v = Ah;
                if (ap < 3) {
                    const float4* p4 = reinterpret_cast<const float4*>(vpre + (gbase + a0 + aa + 2) * 512 + d * 16);
                    A0 = p4[0]; A1 = p4[1]; A2 = p4[2]; A3 = p4[3];
                    Ah = h0in[(gbase + a0 + aa + 2) * 32 + d];
                }
                PROC_SRC(aa, u0, u1, u2, u3, h0v)
            }
            {
                float4 u0 = B0, u1 = B1, u2 = B2, u3 = B3; float h0v = Bh;
                if (ap < 3) {
                    const float4* p4 = reinterpret_cast<const float4*>(vpre + (gbase + a0 + aa + 3) * 512 + d * 16);
                    B0 = p4[0]; B1 = p4[1]; B2 = p4[2]; B3 = p4[3];
                    Bh = h0in[(gbase + a0 + aa + 3) * 32 + d];
                }
                PROC_SRC(aa + 1, u0, u1, u2, u3, h0v)
            }
        }
    }
    __syncthreads();   // all pass-2 LDS reads (rhs/rwswP/yss) done

    // S1: partials into P (overlay rhs); stage h[n] (overlay yss); stage Wo (float bits in rwswP)
    float* P = rhs;
#pragma unroll
    for (int m = 0; m < 16; m++) P[grp * 528 + m * 33 + d] = acc[m];
    float* hs = yss;
    for (int o = t; o < 512; o += 256) hs[o] = h[nblk * 512 + o];
    for (int o = t; o < 4096; o += 256) rwswP[o] = __float_as_uint(Wo[layer * 4096 + o]);
    __syncthreads();

    // S2: reduce partials -> aggL[m*33+c]
    float* hnS = ub;          // [528]
    float* aggL = ub + 528;   // [528]
    float invs = sh_inv;
    for (int o = t; o < 512; o += 256) {
        int m = o >> 5, c = o & 31;
        float s = 0.f;
#pragma unroll
        for (int gg = 0; gg < 8; gg++) s += P[gg * 528 + m * 33 + c];
        aggL[m * 33 + c] = s * invs;
    }
    __syncthreads();

    // S3: stage Wskip into rhs (fp32), P dead
    for (int o = t; o < 4096; o += 256) rhs[o] = Wskip[layer * 4096 + o];
    __syncthreads();

    // S4: post GEMM: hn = h@Wskip + agg@Wo
    for (int o = t; o < 512; o += 256) {
        int m = o >> 5, dd = o & 31, l = lmap(m);
        float s = 0.f;
        const float* wa = &rhs[l * 1024 + dd];
        const uint32_t* wb = &rwswP[l * 1024 + dd];
        const float* hrow = &hs[m];
        const float* arow = &aggL[m * 33];
#pragma unroll
        for (int c = 0; c < 32; c++) {
            s = fmaf(hrow[c * 16], wa[c * 32], s);
            s = fmaf(arow[c], __uint_as_float(wb[c * 32]), s);
        }
        hnS[m * 33 + dd] = s;
    }
    __syncthreads();

    // S5: norm gate compute + stage next-stage value weights
    if (t < 128) {
        int dd = t >> 2, l = t & 3;
        int m0 = l * l, cnt = 2 * l + 1;
        float s = 1e-12f;
        for (int m = m0; m < m0 + cnt; m++) { float v = hnS[m * 33 + dd]; s = fmaf(v, v, s); }
        float nr = sqrtf(s);
        float phi = fmaxf(nr * gw[(layer * 4 + l) * 32 + dd] + gb[(layer * 4 + l) * 32 + dd], 0.f);
        scale[dd * 4 + l] = phi / (nr + 1e-6f);
    }
    if (!last) {
        for (int o = t; o < 4096; o += 256) rwswP[o] = __float_as_uint(Wv_n[o]);
    } else {
        for (int o = t; o < 4096; o += 256) {
            rhs[o] = WvO[o];                                   // l = 0,1
            rwswP[o] = __float_as_uint(WvO[4096 + o]);         // l = 2,3
        }
    }
    __syncthreads();

    // S6: apply gate, write hnew + dense h0 sidecar
    for (int o = t; o < 512; o += 256) {
        int dd = o >> 4, m = o & 15;
        float v = hnS[m * 33 + dd] * scale[dd * 4 + lmap(m)];
        hnew[nblk * 512 + o] = v;
        hnS[m * 33 + dd] = v;
        if (m == 0) h0out[nblk * 32 + dd] = v;
    }
    __syncthreads();

    if (!last) {
        for (int o = t; o < 512; o += 256) {
            int dd = o >> 4, m = o & 15, l = lmap(m);
            float s = 0.f;
            const uint32_t* wv = &rwswP[l * 1024 + dd];
            const float* hrow = &hnS[m * 33];
#pragma unroll
            for (int c = 0; c < 32; c++) s = fmaf(hrow[c], __uint_as_float(wv[c * 32]), s);
            vpre_n[nblk * 512 + o] = s;
        }
        if (t < 32) {
            float s = 0.f;
#pragma unroll
            for (int c = 0; c < 32; c++) s = fmaf(hnS[c * 33], Wq_n[c * 32 + t], s);
            red[t] = s;
        }
        __syncthreads();
        if (t < 32) {
            float s = 0.f;
#pragma unroll
            for (int j = 0; j < 32; j++) s = fmaf(Wk_n[t * 32 + j], red[j], s);
            wqk_n[nblk * 32 + t] = s;
        }
    } else {
        for (int o = t; o < 1024; o += 256) {
            int j = o >> 4, m = o & 15, l = lmap(m);
            float s = 0.f;
            const float* hrow = &hnS[m * 33];
            if (l < 2) {
                const float* wv = &rhs[l * 2048 + j];
#pragma unroll
                for (int c = 0; c < 32; c++) s = fmaf(hrow[c], wv[c * 64], s);
            } else {
                const uint32_t* wv = &rwswP[(l - 2) * 2048 + j];
#pragma unroll
                for (int c = 0; c < 32; c++) s = fmaf(hrow[c], __uint_as_float(wv[c * 64]), s);
            }
            U[nblk * 1024 + o] = s;
        }
        if (t < 64) {
            float s = 0.f;
#pragma unroll
            for (int c = 0; c < 32; c++) s = fmaf(hnS[c * 33], WqO[c * 64 + t], s);
            red[t] = s;
        }
        __syncthreads();
        if (t < 32) {
            float s = 0.f;
#pragma unroll
            for (int j = 0; j < 64; j++) s = fmaf(WkO[t * 64 + j], red[j], s);
            wq2[nblk * 32 + t] = s;
        }
    }
}

// Output-stage edge kernel + fused out_post (hout). 3 blocks/CU.
__global__ __launch_bounds__(256, 3) void k_out_edge(
    const float* __restrict__ x, const float* __restrict__ h0f,
    const float* __restrict__ w1o, const float* __restrict__ b1o,
    const float* __restrict__ wq2, const float* __restrict__ roW,
    const float* __restrict__ U, const float* __restrict__ WoO,
    const float* __restrict__ WskipO, float* __restrict__ hout)
{
    __shared__ uint32_t rosP[4096];               // fp16 pairs of roW c-neighbors
    __shared__ __align__(16) float rhs[128 * 36];
    __shared__ __align__(16) float yss[128 * 17];
    __shared__ float xs[384];
    __shared__ float w1s[512];
    __shared__ float b1s[32];
    __shared__ float wq2s[32];
    __shared__ float alphas[128];
    __shared__ float red[256];
    __shared__ float agg64s[64];
    __shared__ float sh_inv;

    int n = blockIdx.x, t = threadIdx.x;
    int g = n >> 7, b = n & 127;
    int gbase = g << 7;

    for (int o = t; o < 384; o += 256) xs[o] = x[gbase * 3 + o];
    for (int o = t; o < 512; o += 256) w1s[o] = w1o[o];
    if (t < 32) { b1s[t] = b1o[t]; wq2s[t] = wq2[n * 32 + t]; }
    for (int o = t; o < 4096; o += 256) {
        int j = o & 63, lc = o >> 6, cp = lc & 15, l = lc >> 4;
        rosP[o] = f2h2(roW[(l * 32 + 2 * cp) * 64 + j], roW[(l * 32 + 2 * cp + 1) * 64 + j]);
    }
    __syncthreads();

    // phase A split across 256 threads
    {
        int a = t & 127, dh = t >> 7;
        float rx = xs[b * 3 + 0] - xs[a * 3 + 0];
        float ry = xs[b * 3 + 1] - xs[a * 3 + 1];
        float rz = xs[b * 3 + 2] - xs[a * 3 + 2];
        float dd = sqrtf(rx * rx + ry * ry + rz * rz + 1e-12f);
        float inv = 1.f / dd;
        float ys[16];
        sph16(rx * inv, ry * inv, rz * inv, ys);
        if (dh == 0) {
#pragma unroll
            for (int m = 0; m < 16; m++) yss[a * 17 + m] = ys[m];
        }
        float rbf[16];
#pragma unroll
        for (int j = 0; j < 16; j++) {
            float dc = dd - (4.f / 15.f) * j;
            rbf[j] = __expf(-2.f * dc * dc);
        }
        float lpart = 0.f;
        int d0 = dh * 16;
        for (int d2 = 0; d2 < 16; d2++) {
            int d = d0 + d2;
            float s = b1s[d];
#pragma unroll
            for (int j = 0; j < 16; j++) s = fmaf(rbf[j], w1s[j * 32 + d], s);
            s = fmaxf(s, 0.f);
            rhs[a * 36 + d] = s;
            lpart = fmaf(s, wq2s[d], lpart);
        }
        red[t] = lpart;
    }
    __syncthreads();
    if (t < 128) alphas[t] = (red[t] + red[t + 128]) * 0.125f; // 1/sqrt(64)
    __syncthreads();

    if (t < 128) {
        float m = (t != b) ? alphas[t] : -1e30f;
#pragma unroll
        for (int off = 32; off > 0; off >>= 1) m = fmaxf(m, __shfl_xor(m, off));
        if ((t & 63) == 0) red[t >> 6] = m;
    }
    __syncthreads();
    {
        float mx = fmaxf(red[0], red[1]);
        if (t < 128) {
            float e = (t != b) ? __expf(alphas[t] - mx) : 0.f;
            alphas[t] = e;
            float s = e;
#pragma unroll
            for (int off = 32; off > 0; off >>= 1) s += __shfl_xor(s, off);
            if ((t & 63) == 0) red[2 + (t >> 6)] = s;
        }
    }
    __syncthreads();
    if (t == 0) sh_inv = 1.f / (red[2] + red[3]);
    __syncthreads();

    int grp = t >> 6, j = t & 63;
    float accO = 0.f;
    for (int chunk = 0; chunk < 4; chunk++) {
        int a0 = grp * 32 + chunk * 8;
        float RO[8][4];
#pragma unroll
        for (int aa = 0; aa < 8; aa++)
#pragma unroll
            for (int l = 0; l < 4; l++) RO[aa][l] = 0.f;

#pragma unroll 2
        for (int cq = 0; cq < 8; cq++) {
            float4 rh4[8];
#pragma unroll
            for (int aa = 0; aa < 8; aa++)
                rh4[aa] = *reinterpret_cast<const float4*>(&rhs[(a0 + aa) * 36 + cq * 4]);
#pragma unroll
            for (int l = 0; l < 4; l++) {
#pragma unroll
                for (int ch = 0; ch < 2; ch++) {
                    float2 w2 = h2f2(rosP[(l * 16 + cq * 2 + ch) * 64 + j]);
#pragma unroll
                    for (int aa = 0; aa < 8; aa++) {
                        RO[aa][l] = fmaf(f4get(rh4[aa], 2 * ch), w2.x, RO[aa][l]);
                        RO[aa][l] = fmaf(f4get(rh4[aa], 2 * ch + 1), w2.y, RO[aa][l]);
                    }
                }
            }
        }

        float4 A0, A1, A2, A3, B0, B1, B2, B3;
        {
            const float4* p4 = reinterpret_cast<const float4*>(U + (gbase + a0) * 1024 + j * 16);
            A0 = p4[0]; A1 = p4[1]; A2 = p4[2]; A3 = p4[3];
            const float4* q4 = reinterpret_cast<const float4*>(U + (gbase + a0 + 1) * 1024 + j * 16);
            B0 = q4[0]; B1 = q4[1]; B2 = q4[2]; B3 = q4[3];
        }
#define PROC_O(aa, u0, u1, u2, u3) { \
        int a_ = a0 + (aa); \
        float w_ = alphas[a_]; \
        if (w_ != 0.f) { \
            const float* ysa = &yss[a_ * 17]; \
            float cv0 = ysa[0] * (u0).x; \
            float cv1 = fmaf(ysa[1], (u0).y, fmaf(ysa[2], (u0).z, ysa[3] * (u0).w)); \
            float cv2 = fmaf(ysa[4], (u1).x, fmaf(ysa[5], (u1).y, fmaf(ysa[6], (u1).z, fmaf(ysa[7], (u1).w, ysa[8] * (u2).x)))); \
            float cv3 = fmaf(ysa[9], (u2).y, fmaf(ysa[10], (u2).z, fmaf(ysa[11], (u2).w, \
                        fmaf(ysa[12], (u3).x, fmaf(ysa[13], (u3).y, fmaf(ysa[14], (u3).z, ysa[15] * (u3).w)))))); \
            float s_ = fmaf(cv0, RO[aa][0], fmaf(cv1, RO[aa][1], fmaf(cv2, RO[aa][2], cv3 * RO[aa][3]))); \
            accO = fmaf(w_, s_, accO); \
        } }
#pragma unroll
        for (int ap = 0; ap < 4; ap++) {
            int aa = ap * 2;
            {
                float4 u0 = A0, u1 = A1, u2 = A2, u3 = A3;
                if (ap < 3) {
                    const float4* p4 = reinterpret_cast<const float4*>(U + (gbase + a0 + aa + 2) * 1024 + j * 16);
                    A0 = p4[0]; A1 = p4[1]; A2 = p4[2]; A3 = p4[3];
                }
                PROC_O(aa, u0, u1, u2, u3)
            }
            {
                float4 u0 = B0, u1 = B1, u2 = B2, u3 = B3;
                if (ap < 3) {
                    const float4* p4 = reinterpret_cast<const float4*>(U + (gbase + a0 + aa + 3) * 1024 + j * 16);
                    B0 = p4[0]; B1 = p4[1]; B2 = p4[2]; B3 = p4[3];
                }
                PROC_O(aa + 1, u0, u1, u2, u3)
            }
        }
#undef PROC_O
    }
    red[t] = accO;
    __syncthreads();
    if (t < 64) agg64s[t] = (red[t] + red[64 + t] + red[128 + t] + red[192 + t]) * sh_inv;
    __syncthreads();

    if (t < 64) {
        float s = 0.f;
#pragma unroll
        for (int c = 0; c < 64; c++) s = fmaf(agg64s[c], WoO[c * 64 + t], s);
        const float* hr = &h0f[n * 32];
#pragma unroll
        for (int c = 0; c < 32; c++) s = fmaf(hr[c], WskipO[c * 64 + t], s);
        hout[n * 64 + t] = s;
    }
}

__global__ __launch_bounds__(64) void k_final(
    const float* __restrict__ hout, const float* __restrict__ Whid,
    const float* __restrict__ bhid, const float* __restrict__ Wout,
    const float* __restrict__ bout, float* __restrict__ out)
{
    __shared__ float pooled[64], hid[64];
    int g = blockIdx.x, t = threadIdx.x;
    float s = 0.f;
    for (int p = 0; p < 128; p++) s += hout[(g * 128 + p) * 64 + t];
    pooled[t] = s * (1.f / 128.f);
    __syncthreads();
    float hv = bhid[t];
#pragma unroll
    for (int c = 0; c < 64; c++) hv = fmaf(pooled[c], Whid[c * 64 + t], hv);
    hid[t] = fmaxf(hv, 0.f);
    __syncthreads();
    if (t < 15) {
        float o = bout[t];
#pragma unroll
        for (int c = 0; c < 64; c++) o = fmaf(hid[c], Wout[c * 15 + t], o);
        out[g * 15 + t] = o;
    }
}

extern "C" void kernel_launch(void* const* d_in, const int* in_sizes, int n_in,
                              void* d_out, int out_size, void* d_ws, size_t ws_size,
                              hipStream_t stream) {
    const float* x      = (const float*)d_in[0];
    const float* w1     = (const float*)d_in[1];
    const float* b1     = (const float*)d_in[2];
    const float* rW     = (const float*)d_in[3];
    const float* sW     = (const float*)d_in[4];
    const float* Wv     = (const float*)d_in[5];
    const float* Wq     = (const float*)d_in[6];
    const float* Wk     = (const float*)d_in[7];
    const float* Wo     = (const float*)d_in[8];
    const float* Wskip  = (const float*)d_in[9];
    const float* gw     = (const float*)d_in[10];
    const float* gb     = (const float*)d_in[11];
    const float* w1o    = (const float*)d_in[12];
    const float* b1o    = (const float*)d_in[13];
    const float* roW    = (const float*)d_in[14];
    const float* WvO    = (const float*)d_in[15];
    const float* WqO    = (const float*)d_in[16];
    const float* WkO    = (const float*)d_in[17];
    const float* WoO    = (const float*)d_in[18];
    const float* WskipO = (const float*)d_in[19];
    const float* Whid   = (const float*)d_in[20];
    const float* bhid   = (const float*)d_in[21];
    const float* Wout   = (const float*)d_in[22];
    const float* bout   = (const float*)d_in[23];
    float* out = (float*)d_out;

    float* ws = (float*)d_ws;
    float* h0    = ws;
    float* h1    = h0 + NNODE * 512;
    float* vA    = h1 + NNODE * 512;
    float* wqkA  = vA + NNODE * 512;
    float* vB    = wqkA + NNODE * 32;
    float* wqkB  = vB + NNODE * 512;
    float* wq2   = wqkB + NNODE * 32;
    float* U     = wq2 + NNODE * 32;
    float* hout  = U + NNODE * 1024;
    float* s0A   = hout + NNODE * 64;
    float* s0B   = s0A + NNODE * 32;

    hipMemsetAsync(h0, 0, NNODE * 512 * sizeof(float), stream);
    hipMemsetAsync(vA, 0, (NNODE * 512 + NNODE * 32) * sizeof(float), stream);
    hipMemsetAsync(s0A, 0, NNODE * 32 * sizeof(float), stream);

    for (int i = 0; i < 4; i++) {
        const float* hc  = (i & 1) ? h1 : h0;
        float*       hn  = (i & 1) ? h0 : h1;
        const float* vin  = (i & 1) ? vB : vA;
        const float* qin  = (i & 1) ? wqkB : wqkA;
        float*       vout = (i & 1) ? vA : vB;
        float*       qout = (i & 1) ? wqkA : wqkB;
        const float* s0in = (i & 1) ? s0B : s0A;
        float*       s0out= (i & 1) ? s0A : s0B;
        int last = (i == 3);
        k_layer<<<NNODE, 256, 0, stream>>>(
            x, hc, s0in, vin, qin, w1, b1, rW, sW, Wskip, Wo, gw, gb,
            Wv + (last ? 0 : (i + 1) * 4096),
            Wq + (last ? 0 : (i + 1) * 1024),
            Wk + (last ? 0 : (i + 1) * 1024),
            WvO, WqO, WkO,
            hn, s0out, vout, qout, wq2, U, i, last);
    }
    // final h0 sidecar: i=3 wrote s0A
    k_out_edge<<<NNODE, 256, 0, stream>>>(x, s0A, w1o, b1o, wq2, roW, U, WoO, WskipO, hout);
    k_final<<<NGRAPH, 64, 0, stream>>>(hout, Whid, bhid, Wout, bout, out);
}

// Round 10
// 556.759 us; speedup vs baseline: 1.9966x; 1.2604x over previous
//
#include <hip/hip_runtime.h>
#include <hip/hip_bf16.h>
#include <hip/hip_fp16.h>

#define NNODE 2048
#define NGRAPH 16

__device__ __forceinline__ int lmap(int m) { return m == 0 ? 0 : (m < 4 ? 1 : (m < 9 ? 2 : 3)); }

__device__ __forceinline__ float f4get(const float4& v, int j) {
    return j == 0 ? v.x : (j == 1 ? v.y : (j == 2 ? v.z : v.w));
}

// pack two floats as fp16 pair in a u32 (lo = a, hi = b)
__device__ __forceinline__ uint32_t f2h2(float a, float b) {
    __half2 h2 = __floats2half2_rn(a, b);
    return *reinterpret_cast<uint32_t*>(&h2);
}
__device__ __forceinline__ float2 h2f2(uint32_t u) {
    __half2 h2 = *reinterpret_cast<__half2*>(&u);
    return __half22float2(h2);
}

__device__ __forceinline__ void sph16(float x, float y, float z, float* Y) {
    Y[0] = 0.28209479177f;
    Y[1] = 0.4886025119f * y; Y[2] = 0.4886025119f * z; Y[3] = 0.4886025119f * x;
    Y[4] = 1.09254843059f * x * y;
    Y[5] = 1.09254843059f * y * z;
    Y[6] = 0.31539156525f * (3.f * z * z - 1.f);
    Y[7] = 1.09254843059f * x * z;
    Y[8] = 0.54627421529f * (x * x - y * y);
    Y[9]  = 0.59004358992f * y * (3.f * x * x - y * y);
    Y[10] = 2.89061144264f * x * y * z;
    Y[11] = 0.45704579946f * y * (5.f * z * z - 1.f);
    Y[12] = 0.37317633259f * z * (5.f * z * z - 3.f);
    Y[13] = 0.45704579946f * x * (5.f * z * z - 1.f);
    Y[14] = 1.44530572132f * z * (x * x - y * y);
    Y[15] = 0.59004358992f * x * (x * x - 3.f * y * y);
}

#define PROC_SRC(aa, u0, u1, u2, u3, h0v) { \
    int a_ = a0 + (aa); \
    float w_ = alphas[a_]; \
    if (w_ != 0.f) { \
        const float4* yp = reinterpret_cast<const float4*>(&yss[a_ * 20]); \
        float4 y0 = yp[0], y1 = yp[1], y2 = yp[2], y3 = yp[3]; \
        float hb1 = (h0v) + 1.f; \
        float sc0 = S[aa][0] * hb1, sc1 = S[aa][1] * hb1; \
        float sc2 = S[aa][2] * hb1, sc3 = S[aa][3] * hb1; \
        acc[0]  = fmaf(w_, fmaf((u0).x, R[aa][0], sc0 * y0.x), acc[0]); \
        acc[1]  = fmaf(w_, fmaf((u0).y, R[aa][1], sc1 * y0.y), acc[1]); \
        acc[2]  = fmaf(w_, fmaf((u0).z, R[aa][1], sc1 * y0.z), acc[2]); \
        acc[3]  = fmaf(w_, fmaf((u0).w, R[aa][1], sc1 * y0.w), acc[3]); \
        acc[4]  = fmaf(w_, fmaf((u1).x, R[aa][2], sc2 * y1.x), acc[4]); \
        acc[5]  = fmaf(w_, fmaf((u1).y, R[aa][2], sc2 * y1.y), acc[5]); \
        acc[6]  = fmaf(w_, fmaf((u1).z, R[aa][2], sc2 * y1.z), acc[6]); \
        acc[7]  = fmaf(w_, fmaf((u1).w, R[aa][2], sc2 * y1.w), acc[7]); \
        acc[8]  = fmaf(w_, fmaf((u2).x, R[aa][2], sc2 * y2.x), acc[8]); \
        acc[9]  = fmaf(w_, fmaf((u2).y, R[aa][3], sc3 * y2.y), acc[9]); \
        acc[10] = fmaf(w_, fmaf((u2).z, R[aa][3], sc3 * y2.z), acc[10]); \
        acc[11] = fmaf(w_, fmaf((u2).w, R[aa][3], sc3 * y2.w), acc[11]); \
        acc[12] = fmaf(w_, fmaf((u3).x, R[aa][3], sc3 * y3.x), acc[12]); \
        acc[13] = fmaf(w_, fmaf((u3).y, R[aa][3], sc3 * y3.y), acc[13]); \
        acc[14] = fmaf(w_, fmaf((u3).z, R[aa][3], sc3 * y3.z), acc[14]); \
        acc[15] = fmaf(w_, fmaf((u3).w, R[aa][3], sc3 * y3.w), acc[15]); \
    } }

// One fused layer. 3 blocks/CU (LDS ~51KB).
__global__ __launch_bounds__(256, 3) void k_layer(
    const float* __restrict__ x, const float* __restrict__ h,
    const float* __restrict__ h0in, const float* __restrict__ vpre,
    const float* __restrict__ wqk,
    const float* __restrict__ w1, const float* __restrict__ b1,
    const float* __restrict__ rW, const float* __restrict__ sW,
    const float* __restrict__ Wskip, const float* __restrict__ Wo,
    const float* __restrict__ gw, const float* __restrict__ gb,
    const float* __restrict__ Wv_n, const float* __restrict__ Wq_n, const float* __restrict__ Wk_n,
    const float* __restrict__ WvO, const float* __restrict__ WqO, const float* __restrict__ WkO,
    float* __restrict__ hnew, float* __restrict__ h0out,
    float* __restrict__ vpre_n, float* __restrict__ wqk_n,
    float* __restrict__ wq2, float* __restrict__ U,
    int layer, int last)
{
    __shared__ uint32_t rwswP[4096];             // fp16 pair (rW,sW); later float-bits Wo / Wv_n / WvO-hi
    __shared__ __align__(16) float rhs[128 * 36]; // rh; later P[8][528]; later wsk / WvO-lo
    __shared__ __align__(16) float yss[128 * 20]; // Ys (stride 20, 16B-aligned); later hs[512]
    __shared__ __align__(16) float ub[1056];      // phase A: xs[384]|w1s[512]; post: hnS[528]|aggL[528]
    __shared__ float b1s[32];
    __shared__ float wqks[32];
    __shared__ float alphas[128];
    __shared__ float red[256];
    __shared__ float scale[128];
    __shared__ float sh_inv;

    int nblk = blockIdx.x, t = threadIdx.x;
    int g = nblk >> 7, b = nblk & 127;
    int gbase = g << 7;

    float* xs = ub;           // [384]
    float* w1s = ub + 384;    // [512]

    for (int o = t; o < 384; o += 256) xs[o] = x[gbase * 3 + o];
    for (int o = t; o < 512; o += 256) w1s[o] = w1[layer * 512 + o];
    if (t < 32) { b1s[t] = b1[layer * 32 + t]; wqks[t] = wqk[nblk * 32 + t]; }
    for (int o = t; o < 4096; o += 256)
        rwswP[o] = f2h2(rW[layer * 4096 + o], sW[layer * 4096 + o]);
    __syncthreads();

    // ---- phase A: geometry, rh, partial logit (all 256 threads; 2 d-halves) ----
    {
        int a = t & 127, dh = t >> 7;
        float rx = xs[b * 3 + 0] - xs[a * 3 + 0];
        float ry = xs[b * 3 + 1] - xs[a * 3 + 1];
        float rz = xs[b * 3 + 2] - xs[a * 3 + 2];
        float dd = sqrtf(rx * rx + ry * ry + rz * rz + 1e-12f);
        float inv = 1.f / dd;
        float ys[16];
        sph16(rx * inv, ry * inv, rz * inv, ys);
        if (dh == 0) {
#pragma unroll
            for (int m = 0; m < 16; m++) yss[a * 20 + m] = ys[m];
        }
        float rbf[16];
#pragma unroll
        for (int j = 0; j < 16; j++) {
            float dc = dd - (4.f / 15.f) * j;
            rbf[j] = __expf(-2.f * dc * dc);
        }
        float lpart = 0.f;
        int d0 = dh * 16;
        for (int d2 = 0; d2 < 16; d2++) {
            int d = d0 + d2;
            float s = b1s[d];
#pragma unroll
            for (int j = 0; j < 16; j++) s = fmaf(rbf[j], w1s[j * 32 + d], s);
            s = fmaxf(s, 0.f);
            rhs[a * 36 + d] = s;
            lpart = fmaf(s, wqks[d], lpart);
        }
        red[t] = lpart;
    }
    __syncthreads();
    if (t < 128) alphas[t] = (red[t] + red[t + 128]) * 0.17677669529663687f; // 1/sqrt(32)
    __syncthreads();

    // ---- segment softmax over 127 valid edges (wave shuffle reductions) ----
    if (t < 128) {
        float m = (t != b) ? alphas[t] : -1e30f;
#pragma unroll
        for (int off = 32; off > 0; off >>= 1) m = fmaxf(m, __shfl_xor(m, off));
        if ((t & 63) == 0) red[t >> 6] = m;
    }
    __syncthreads();
    {
        float mx = fmaxf(red[0], red[1]);
        if (t < 128) {
            float e = (t != b) ? __expf(alphas[t] - mx) : 0.f;
            alphas[t] = e;
            float s = e;
#pragma unroll
            for (int off = 32; off > 0; off >>= 1) s += __shfl_xor(s, off);
            if ((t & 63) == 0) red[2 + (t >> 6)] = s;
        }
    }
    __syncthreads();
    if (t == 0) sh_inv = 1.f / (red[2] + red[3]);

    // ---- pass 2: register-blocked R/S GEMM + weighted aggregate ----
    int grp = t >> 5, d = t & 31;
    float acc[16];
#pragma unroll
    for (int m = 0; m < 16; m++) acc[m] = 0.f;

    for (int chunk = 0; chunk < 2; chunk++) {
        int a0 = grp * 16 + chunk * 8;
        float R[8][4], S[8][4];
#pragma unroll
        for (int aa = 0; aa < 8; aa++)
#pragma unroll
            for (int l = 0; l < 4; l++) { R[aa][l] = 0.f; S[aa][l] = 0.f; }

#pragma unroll 2
        for (int jq = 0; jq < 8; jq++) {
            float4 rh4[8];
#pragma unroll
            for (int aa = 0; aa < 8; aa++)
                rh4[aa] = *reinterpret_cast<const float4*>(&rhs[(a0 + aa) * 36 + jq * 4]);
#pragma unroll
            for (int l = 0; l < 4; l++) {
#pragma unroll
                for (int jj = 0; jj < 4; jj++) {
                    float2 w2 = h2f2(rwswP[(l * 32 + jq * 4 + jj) * 32 + d]);
#pragma unroll
                    for (int aa = 0; aa < 8; aa++) {
                        float rv = f4get(rh4[aa], jj);
                        R[aa][l] = fmaf(rv, w2.x, R[aa][l]);
                        S[aa][l] = fmaf(rv, w2.y, S[aa][l]);
                    }
                }
            }
        }

        // epilogue: 2-deep double-buffered global loads (vpre rows + dense h0 sidecar)
        float4 A0, A1, A2, A3, B0, B1, B2, B3; float Ah, Bh;
        {
            const float4* p4 = reinterpret_cast<const float4*>(vpre + (gbase + a0) * 512 + d * 16);
            A0 = p4[0]; A1 = p4[1]; A2 = p4[2]; A3 = p4[3];
            Ah = h0in[(gbase + a0) * 32 + d];
            const float4* q4 = reinterpret_cast<const float4*>(vpre + (gbase + a0 + 1) * 512 + d * 16);
            B0 = q4[0]; B1 = q4[1]; B2 = q4[2]; B3 = q4[3];
            Bh = h0in[(gbase + a0 + 1) * 32 + d];
        }
#pragma unroll
        for (int ap = 0; ap < 4; ap++) {
            int aa = ap * 2;
            {
                float4 u0 = A0, u1 = A1, u2 = A2, u3 = A3; float h0v = Ah;
                if (ap < 3) {
                    const float4* p4 = reinterpret_cast<const float4*>(vpre + (gbase + a0 + aa + 2) * 512 + d * 16);
                    A0 = p4[0]; A1 = p4[1]; A2 = p4[2]; A3 = p4[3];
                    Ah = h0in[(gbase + a0 + aa + 2) * 32 + d];
                }
                PROC_SRC(aa, u0, u1, u2, u3, h0v)
            }
            {
                float4 u0 = B0, u1 = B1, u2 = B2, u3 = B3; float h0v = Bh;
                if (ap < 3) {
                    const float4* p4 = reinterpret_cast<const float4*>(vpre + (gbase + a0 + aa + 3) * 512 + d * 16);
                    B0 = p4[0]; B1 = p4[1]; B2 = p4[2]; B3 = p4[3];
                    Bh = h0in[(gbase + a0 + aa + 3) * 32 + d];
                }
                PROC_SRC(aa + 1, u0, u1, u2, u3, h0v)
            }
        }
    }
    __syncthreads();   // all pass-2 LDS reads (rhs/rwswP/yss) done

    // S1: partials into P (overlay rhs); stage h[n] (overlay yss); stage Wo (float bits in rwswP)
    float* P = rhs;
#pragma unroll
    for (int m = 0; m < 16; m++) P[grp * 528 + m * 33 + d] = acc[m];
    float* hs = yss;
    for (int o = t; o < 512; o += 256) hs[o] = h[nblk * 512 + o];
    for (int o = t; o < 4096; o += 256) rwswP[o] = __float_as_uint(Wo[layer * 4096 + o]);
    __syncthreads();

    // S2: reduce partials -> aggL[m*33+c]
    float* hnS = ub;          // [528]
    float* aggL = ub + 528;   // [528]
    float invs = sh_inv;
    for (int o = t; o < 512; o += 256) {
        int m = o >> 5, c = o & 31;
        float s = 0.f;
#pragma unroll
        for (int gg = 0; gg < 8; gg++) s += P[gg * 528 + m * 33 + c];
        aggL[m * 33 + c] = s * invs;
    }
    __syncthreads();

    // S3: stage Wskip into rhs (fp32), P dead
    for (int o = t; o < 4096; o += 256) rhs[o] = Wskip[layer * 4096 + o];
    __syncthreads();

    // S4: post GEMM: hn = h@Wskip + agg@Wo
    for (int o = t; o < 512; o += 256) {
        int m = o >> 5, dd = o & 31, l = lmap(m);
        float s = 0.f;
        const float* wa = &rhs[l * 1024 + dd];
        const uint32_t* wb = &rwswP[l * 1024 + dd];
        const float* hrow = &hs[m];
        const float* arow = &aggL[m * 33];
#pragma unroll
        for (int c = 0; c < 32; c++) {
            s = fmaf(hrow[c * 16], wa[c * 32], s);
            s = fmaf(arow[c], __uint_as_float(wb[c * 32]), s);
        }
        hnS[m * 33 + dd] = s;
    }
    __syncthreads();

    // S5: norm gate compute + stage next-stage value weights
    if (t < 128) {
        int dd = t >> 2, l = t & 3;
        int m0 = l * l, cnt = 2 * l + 1;
        float s = 1e-12f;
        for (int m = m0; m < m0 + cnt; m++) { float v = hnS[m * 33 + dd]; s = fmaf(v, v, s); }
        float nr = sqrtf(s);
        float phi = fmaxf(nr * gw[(layer * 4 + l) * 32 + dd] + gb[(layer * 4 + l) * 32 + dd], 0.f);
        scale[dd * 4 + l] = phi / (nr + 1e-6f);
    }
    if (!last) {
        for (int o = t; o < 4096; o += 256) rwswP[o] = __float_as_uint(Wv_n[o]);
    } else {
        for (int o = t; o < 4096; o += 256) {
            rhs[o] = WvO[o];                                   // l = 0,1
            rwswP[o] = __float_as_uint(WvO[4096 + o]);         // l = 2,3
        }
    }
    __syncthreads();

    // S6: apply gate, write hnew
    for (int o = t; o < 512; o += 256) {
        int dd = o >> 4, m = o & 15;
        float v = hnS[m * 33 + dd] * scale[dd * 4 + lmap(m)];
        hnew[nblk * 512 + o] = v;
        hnS[m * 33 + dd] = v;
    }
    __syncthreads();

    // dense h0 sidecar: one coalesced wave-store of the gated m=0 column
    if (t < 32) h0out[nblk * 32 + t] = hnS[t];

    if (!last) {
        for (int o = t; o < 512; o += 256) {
            int dd = o >> 4, m = o & 15, l = lmap(m);
            float s = 0.f;
            const uint32_t* wv = &rwswP[l * 1024 + dd];
            const float* hrow = &hnS[m * 33];
#pragma unroll
            for (int c = 0; c < 32; c++) s = fmaf(hrow[c], __uint_as_float(wv[c * 32]), s);
            vpre_n[nblk * 512 + o] = s;
        }
        if (t < 32) {
            float s = 0.f;
#pragma unroll
            for (int c = 0; c < 32; c++) s = fmaf(hnS[c * 33], Wq_n[c * 32 + t], s);
            red[t] = s;
        }
        __syncthreads();
        if (t < 32) {
            float s = 0.f;
#pragma unroll
            for (int j = 0; j < 32; j++) s = fmaf(Wk_n[t * 32 + j], red[j], s);
            wqk_n[nblk * 32 + t] = s;
        }
    } else {
        for (int o = t; o < 1024; o += 256) {
            int j = o >> 4, m = o & 15, l = lmap(m);
            float s = 0.f;
            const float* hrow = &hnS[m * 33];
            if (l < 2) {
                const float* wv = &rhs[l * 2048 + j];
#pragma unroll
                for (int c = 0; c < 32; c++) s = fmaf(hrow[c], wv[c * 64], s);
            } else {
                const uint32_t* wv = &rwswP[(l - 2) * 2048 + j];
#pragma unroll
                for (int c = 0; c < 32; c++) s = fmaf(hrow[c], __uint_as_float(wv[c * 64]), s);
            }
            U[nblk * 1024 + o] = s;
        }
        if (t < 64) {
            float s = 0.f;
#pragma unroll
            for (int c = 0; c < 32; c++) s = fmaf(hnS[c * 33], WqO[c * 64 + t], s);
            red[t] = s;
        }
        __syncthreads();
        if (t < 32) {
            float s = 0.f;
#pragma unroll
            for (int j = 0; j < 64; j++) s = fmaf(WkO[t * 64 + j], red[j], s);
            wq2[nblk * 32 + t] = s;
        }
    }
}

// Output-stage edge kernel + fused out_post (hout). 3 blocks/CU.
__global__ __launch_bounds__(256, 3) void k_out_edge(
    const float* __restrict__ x, const float* __restrict__ h0f,
    const float* __restrict__ w1o, const float* __restrict__ b1o,
    const float* __restrict__ wq2, const float* __restrict__ roW,
    const float* __restrict__ U, const float* __restrict__ WoO,
    const float* __restrict__ WskipO, float* __restrict__ hout)
{
    __shared__ uint32_t rosP[4096];               // fp16 pairs of roW c-neighbors
    __shared__ __align__(16) float rhs[128 * 36];
    __shared__ __align__(16) float yss[128 * 20];
    __shared__ float xs[384];
    __shared__ float w1s[512];
    __shared__ float b1s[32];
    __shared__ float wq2s[32];
    __shared__ float alphas[128];
    __shared__ float red[256];
    __shared__ float agg64s[64];
    __shared__ float sh_inv;

    int n = blockIdx.x, t = threadIdx.x;
    int g = n >> 7, b = n & 127;
    int gbase = g << 7;

    for (int o = t; o < 384; o += 256) xs[o] = x[gbase * 3 + o];
    for (int o = t; o < 512; o += 256) w1s[o] = w1o[o];
    if (t < 32) { b1s[t] = b1o[t]; wq2s[t] = wq2[n * 32 + t]; }
    for (int o = t; o < 4096; o += 256) {
        int j = o & 63, lc = o >> 6, cp = lc & 15, l = lc >> 4;
        rosP[o] = f2h2(roW[(l * 32 + 2 * cp) * 64 + j], roW[(l * 32 + 2 * cp + 1) * 64 + j]);
    }
    __syncthreads();

    // phase A split across 256 threads
    {
        int a = t & 127, dh = t >> 7;
        float rx = xs[b * 3 + 0] - xs[a * 3 + 0];
        float ry = xs[b * 3 + 1] - xs[a * 3 + 1];
        float rz = xs[b * 3 + 2] - xs[a * 3 + 2];
        float dd = sqrtf(rx * rx + ry * ry + rz * rz + 1e-12f);
        float inv = 1.f / dd;
        float ys[16];
        sph16(rx * inv, ry * inv, rz * inv, ys);
        if (dh == 0) {
#pragma unroll
            for (int m = 0; m < 16; m++) yss[a * 20 + m] = ys[m];
        }
        float rbf[16];
#pragma unroll
        for (int j = 0; j < 16; j++) {
            float dc = dd - (4.f / 15.f) * j;
            rbf[j] = __expf(-2.f * dc * dc);
        }
        float lpart = 0.f;
        int d0 = dh * 16;
        for (int d2 = 0; d2 < 16; d2++) {
            int d = d0 + d2;
            float s = b1s[d];
#pragma unroll
            for (int j = 0; j < 16; j++) s = fmaf(rbf[j], w1s[j * 32 + d], s);
            s = fmaxf(s, 0.f);
            rhs[a * 36 + d] = s;
            lpart = fmaf(s, wq2s[d], lpart);
        }
        red[t] = lpart;
    }
    __syncthreads();
    if (t < 128) alphas[t] = (red[t] + red[t + 128]) * 0.125f; // 1/sqrt(64)
    __syncthreads();

    if (t < 128) {
        float m = (t != b) ? alphas[t] : -1e30f;
#pragma unroll
        for (int off = 32; off > 0; off >>= 1) m = fmaxf(m, __shfl_xor(m, off));
        if ((t & 63) == 0) red[t >> 6] = m;
    }
    __syncthreads();
    {
        float mx = fmaxf(red[0], red[1]);
        if (t < 128) {
            float e = (t != b) ? __expf(alphas[t] - mx) : 0.f;
            alphas[t] = e;
            float s = e;
#pragma unroll
            for (int off = 32; off > 0; off >>= 1) s += __shfl_xor(s, off);
            if ((t & 63) == 0) red[2 + (t >> 6)] = s;
        }
    }
    __syncthreads();
    if (t == 0) sh_inv = 1.f / (red[2] + red[3]);
    __syncthreads();

    int grp = t >> 6, j = t & 63;
    float accO = 0.f;
    for (int chunk = 0; chunk < 4; chunk++) {
        int a0 = grp * 32 + chunk * 8;
        float RO[8][4];
#pragma unroll
        for (int aa = 0; aa < 8; aa++)
#pragma unroll
            for (int l = 0; l < 4; l++) RO[aa][l] = 0.f;

#pragma unroll 2
        for (int cq = 0; cq < 8; cq++) {
            float4 rh4[8];
#pragma unroll
            for (int aa = 0; aa < 8; aa++)
                rh4[aa] = *reinterpret_cast<const float4*>(&rhs[(a0 + aa) * 36 + cq * 4]);
#pragma unroll
            for (int l = 0; l < 4; l++) {
#pragma unroll
                for (int ch = 0; ch < 2; ch++) {
                    float2 w2 = h2f2(rosP[(l * 16 + cq * 2 + ch) * 64 + j]);
#pragma unroll
                    for (int aa = 0; aa < 8; aa++) {
                        RO[aa][l] = fmaf(f4get(rh4[aa], 2 * ch), w2.x, RO[aa][l]);
                        RO[aa][l] = fmaf(f4get(rh4[aa], 2 * ch + 1), w2.y, RO[aa][l]);
                    }
                }
            }
        }

        float4 A0, A1, A2, A3, B0, B1, B2, B3;
        {
            const float4* p4 = reinterpret_cast<const float4*>(U + (gbase + a0) * 1024 + j * 16);
            A0 = p4[0]; A1 = p4[1]; A2 = p4[2]; A3 = p4[3];
            const float4* q4 = reinterpret_cast<const float4*>(U + (gbase + a0 + 1) * 1024 + j * 16);
            B0 = q4[0]; B1 = q4[1]; B2 = q4[2]; B3 = q4[3];
        }
#define PROC_O(aa, u0, u1, u2, u3) { \
        int a_ = a0 + (aa); \
        float w_ = alphas[a_]; \
        if (w_ != 0.f) { \
            const float4* yp = reinterpret_cast<const float4*>(&yss[a_ * 20]); \
            float4 y0 = yp[0], y1 = yp[1], y2 = yp[2], y3 = yp[3]; \
            float cv0 = y0.x * (u0).x; \
            float cv1 = fmaf(y0.y, (u0).y, fmaf(y0.z, (u0).z, y0.w * (u0).w)); \
            float cv2 = fmaf(y1.x, (u1).x, fmaf(y1.y, (u1).y, fmaf(y1.z, (u1).z, fmaf(y1.w, (u1).w, y2.x * (u2).x)))); \
            float cv3 = fmaf(y2.y, (u2).y, fmaf(y2.z, (u2).z, fmaf(y2.w, (u2).w, \
                        fmaf(y3.x, (u3).x, fmaf(y3.y, (u3).y, fmaf(y3.z, (u3).z, y3.w * (u3).w)))))); \
            float s_ = fmaf(cv0, RO[aa][0], fmaf(cv1, RO[aa][1], fmaf(cv2, RO[aa][2], cv3 * RO[aa][3]))); \
            accO = fmaf(w_, s_, accO); \
        } }
#pragma unroll
        for (int ap = 0; ap < 4; ap++) {
            int aa = ap * 2;
            {
                float4 u0 = A0, u1 = A1, u2 = A2, u3 = A3;
                if (ap < 3) {
                    const float4* p4 = reinterpret_cast<const float4*>(U + (gbase + a0 + aa + 2) * 1024 + j * 16);
                    A0 = p4[0]; A1 = p4[1]; A2 = p4[2]; A3 = p4[3];
                }
                PROC_O(aa, u0, u1, u2, u3)
            }
            {
                float4 u0 = B0, u1 = B1, u2 = B2, u3 = B3;
                if (ap < 3) {
                    const float4* p4 = reinterpret_cast<const float4*>(U + (gbase + a0 + aa + 3) * 1024 + j * 16);
                    B0 = p4[0]; B1 = p4[1]; B2 = p4[2]; B3 = p4[3];
                }
                PROC_O(aa + 1, u0, u1, u2, u3)
            }
        }
#undef PROC_O
    }
    red[t] = accO;
    __syncthreads();
    if (t < 64) agg64s[t] = (red[t] + red[64 + t] + red[128 + t] + red[192 + t]) * sh_inv;
    __syncthreads();

    if (t < 64) {
        float s = 0.f;
#pragma unroll
        for (int c = 0; c < 64; c++) s = fmaf(agg64s[c], WoO[c * 64 + t], s);
        const float* hr = &h0f[n * 32];
#pragma unroll
        for (int c = 0; c < 32; c++) s = fmaf(hr[c], WskipO[c * 64 + t], s);
        hout[n * 64 + t] = s;
    }
}

__global__ __launch_bounds__(64) void k_final(
    const float* __restrict__ hout, const float* __restrict__ Whid,
    const float* __restrict__ bhid, const float* __restrict__ Wout,
    const float* __restrict__ bout, float* __restrict__ out)
{
    __shared__ float pooled[64], hid[64];
    int g = blockIdx.x, t = threadIdx.x;
    float s = 0.f;
    for (int p = 0; p < 128; p++) s += hout[(g * 128 + p) * 64 + t];
    pooled[t] = s * (1.f / 128.f);
    __syncthreads();
    float hv = bhid[t];
#pragma unroll
    for (int c = 0; c < 64; c++) hv = fmaf(pooled[c], Whid[c * 64 + t], hv);
    hid[t] = fmaxf(hv, 0.f);
    __syncthreads();
    if (t < 15) {
        float o = bout[t];
#pragma unroll
        for (int c = 0; c < 64; c++) o = fmaf(hid[c], Wout[c * 15 + t], o);
        out[g * 15 + t] = o;
    }
}

extern "C" void kernel_launch(void* const* d_in, const int* in_sizes, int n_in,
                              void* d_out, int out_size, void* d_ws, size_t ws_size,
                              hipStream_t stream) {
    const float* x      = (const float*)d_in[0];
    const float* w1     = (const float*)d_in[1];
    const float* b1     = (const float*)d_in[2];
    const float* rW     = (const float*)d_in[3];
    const float* sW     = (const float*)d_in[4];
    const float* Wv     = (const float*)d_in[5];
    const float* Wq     = (const float*)d_in[6];
    const float* Wk     = (const float*)d_in[7];
    const float* Wo     = (const float*)d_in[8];
    const float* Wskip  = (const float*)d_in[9];
    const float* gw     = (const float*)d_in[10];
    const float* gb     = (const float*)d_in[11];
    const float* w1o    = (const float*)d_in[12];
    const float* b1o    = (const float*)d_in[13];
    const float* roW    = (const float*)d_in[14];
    const float* WvO    = (const float*)d_in[15];
    const float* WqO    = (const float*)d_in[16];
    const float* WkO    = (const float*)d_in[17];
    const float* WoO    = (const float*)d_in[18];
    const float* WskipO = (const float*)d_in[19];
    const float* Whid   = (const float*)d_in[20];
    const float* bhid   = (const float*)d_in[21];
    const float* Wout   = (const float*)d_in[22];
    const float* bout   = (const float*)d_in[23];
    float* out = (float*)d_out;

    float* ws = (float*)d_ws;
    float* h0    = ws;
    float* h1    = h0 + NNODE * 512;
    float* vA    = h1 + NNODE * 512;
    float* wqkA  = vA + NNODE * 512;
    float* vB    = wqkA + NNODE * 32;
    float* wqkB  = vB + NNODE * 512;
    float* wq2   = wqkB + NNODE * 32;
    float* U     = wq2 + NNODE * 32;
    float* hout  = U + NNODE * 1024;
    float* s0A   = hout + NNODE * 64;
    float* s0B   = s0A + NNODE * 32;

    hipMemsetAsync(h0, 0, NNODE * 512 * sizeof(float), stream);
    hipMemsetAsync(vA, 0, (NNODE * 512 + NNODE * 32) * sizeof(float), stream);
    hipMemsetAsync(s0A, 0, NNODE * 32 * sizeof(float), stream);

    for (int i = 0; i < 4; i++) {
        const float* hc  = (i & 1) ? h1 : h0;
        float*       hn  = (i & 1) ? h0 : h1;
        const float* vin  = (i & 1) ? vB : vA;
        const float* qin  = (i & 1) ? wqkB : wqkA;
        float*       vout = (i & 1) ? vA : vB;
        float*       qout = (i & 1) ? wqkA : wqkB;
        const float* s0in = (i & 1) ? s0B : s0A;
        float*       s0out= (i & 1) ? s0A : s0B;
        int last = (i == 3);
        k_layer<<<NNODE, 256, 0, stream>>>(
            x, hc, s0in, vin, qin, w1, b1, rW, sW, Wskip, Wo, gw, gb,
            Wv + (last ? 0 : (i + 1) * 4096),
            Wq + (last ? 0 : (i + 1) * 1024),
            Wk + (last ? 0 : (i + 1) * 1024),
            WvO, WqO, WkO,
            hn, s0out, vout, qout, wq2, U, i, last);
    }
    // final h0 sidecar: i=3 wrote s0A
    k_out_edge<<<NNODE, 256, 0, stream>>>(x, s0A, w1o, b1o, wq2, roW, U, WoO, WskipO, hout);
    k_final<<<NGRAPH, 64, 0, stream>>>(hout, Whid, bhid, Wout, bout, out);
}

// Round 11
// 528.837 us; speedup vs baseline: 2.1021x; 1.0528x over previous
//
#include <hip/hip_runtime.h>
#include <hip/hip_bf16.h>
#include <hip/hip_fp16.h>

#define NNODE 2048
#define NGRAPH 16

typedef _Float16 h2v __attribute__((ext_vector_type(2)));

__device__ __forceinline__ int lmap(int m) { return m == 0 ? 0 : (m < 4 ? 1 : (m < 9 ? 2 : 3)); }

__device__ __forceinline__ float f4get(const float4& v, int j) {
    return j == 0 ? v.x : (j == 1 ? v.y : (j == 2 ? v.z : v.w));
}
__device__ __forceinline__ uint32_t u4get(const uint4& v, int j) {
    return j == 0 ? v.x : (j == 1 ? v.y : (j == 2 ? v.z : v.w));
}

// pack two floats as fp16 pair in a u32 (lo = a, hi = b)
__device__ __forceinline__ uint32_t f2h2(float a, float b) {
    __half2 h2 = __floats2half2_rn(a, b);
    return *reinterpret_cast<uint32_t*>(&h2);
}
__device__ __forceinline__ float2 h2f2(uint32_t u) {
    __half2 h2 = *reinterpret_cast<__half2*>(&u);
    return __half22float2(h2);
}

// 2-way f16 dot with fp32 accumulate (V_DOT2_F32_F16); safe fallback
__device__ __forceinline__ float fdot2u(uint32_t a, uint32_t b, float c) {
#if defined(__has_builtin)
#if __has_builtin(__builtin_amdgcn_fdot2)
    return __builtin_amdgcn_fdot2(__builtin_bit_cast(h2v, a), __builtin_bit_cast(h2v, b), c, false);
#else
    float2 af = h2f2(a), bf = h2f2(b);
    return fmaf(af.x, bf.x, fmaf(af.y, bf.y, c));
#endif
#else
    float2 af = h2f2(a), bf = h2f2(b);
    return fmaf(af.x, bf.x, fmaf(af.y, bf.y, c));
#endif
}

__device__ __forceinline__ void sph16(float x, float y, float z, float* Y) {
    Y[0] = 0.28209479177f;
    Y[1] = 0.4886025119f * y; Y[2] = 0.4886025119f * z; Y[3] = 0.4886025119f * x;
    Y[4] = 1.09254843059f * x * y;
    Y[5] = 1.09254843059f * y * z;
    Y[6] = 0.31539156525f * (3.f * z * z - 1.f);
    Y[7] = 1.09254843059f * x * z;
    Y[8] = 0.54627421529f * (x * x - y * y);
    Y[9]  = 0.59004358992f * y * (3.f * x * x - y * y);
    Y[10] = 2.89061144264f * x * y * z;
    Y[11] = 0.45704579946f * y * (5.f * z * z - 1.f);
    Y[12] = 0.37317633259f * z * (5.f * z * z - 3.f);
    Y[13] = 0.45704579946f * x * (5.f * z * z - 1.f);
    Y[14] = 1.44530572132f * z * (x * x - y * y);
    Y[15] = 0.59004358992f * x * (x * x - 3.f * y * y);
}

#define PROC_SRC(aa, u0, u1, u2, u3, h0v) { \
    int a_ = a0 + (aa); \
    float w_ = alphas[a_]; \
    if (w_ != 0.f) { \
        const float4* yp = reinterpret_cast<const float4*>(&yss[a_ * 20]); \
        float4 y0 = yp[0], y1 = yp[1], y2 = yp[2], y3 = yp[3]; \
        float hb1 = (h0v) + 1.f; \
        float sc0 = S[aa][0] * hb1, sc1 = S[aa][1] * hb1; \
        float sc2 = S[aa][2] * hb1, sc3 = S[aa][3] * hb1; \
        acc[0]  = fmaf(w_, fmaf((u0).x, R[aa][0], sc0 * y0.x), acc[0]); \
        acc[1]  = fmaf(w_, fmaf((u0).y, R[aa][1], sc1 * y0.y), acc[1]); \
        acc[2]  = fmaf(w_, fmaf((u0).z, R[aa][1], sc1 * y0.z), acc[2]); \
        acc[3]  = fmaf(w_, fmaf((u0).w, R[aa][1], sc1 * y0.w), acc[3]); \
        acc[4]  = fmaf(w_, fmaf((u1).x, R[aa][2], sc2 * y1.x), acc[4]); \
        acc[5]  = fmaf(w_, fmaf((u1).y, R[aa][2], sc2 * y1.y), acc[5]); \
        acc[6]  = fmaf(w_, fmaf((u1).z, R[aa][2], sc2 * y1.z), acc[6]); \
        acc[7]  = fmaf(w_, fmaf((u1).w, R[aa][2], sc2 * y1.w), acc[7]); \
        acc[8]  = fmaf(w_, fmaf((u2).x, R[aa][2], sc2 * y2.x), acc[8]); \
        acc[9]  = fmaf(w_, fmaf((u2).y, R[aa][3], sc3 * y2.y), acc[9]); \
        acc[10] = fmaf(w_, fmaf((u2).z, R[aa][3], sc3 * y2.z), acc[10]); \
        acc[11] = fmaf(w_, fmaf((u2).w, R[aa][3], sc3 * y2.w), acc[11]); \
        acc[12] = fmaf(w_, fmaf((u3).x, R[aa][3], sc3 * y3.x), acc[12]); \
        acc[13] = fmaf(w_, fmaf((u3).y, R[aa][3], sc3 * y3.y), acc[13]); \
        acc[14] = fmaf(w_, fmaf((u3).z, R[aa][3], sc3 * y3.z), acc[14]); \
        acc[15] = fmaf(w_, fmaf((u3).w, R[aa][3], sc3 * y3.w), acc[15]); \
    } }

// One fused layer. 3 blocks/CU (LDS ~51KB).
__global__ __launch_bounds__(256, 3) void k_layer(
    const float* __restrict__ x, const float* __restrict__ h,
    const float* __restrict__ h0in, const float* __restrict__ vpre,
    const float* __restrict__ wqk,
    const float* __restrict__ w1, const float* __restrict__ b1,
    const float* __restrict__ rW, const float* __restrict__ sW,
    const float* __restrict__ Wskip, const float* __restrict__ Wo,
    const float* __restrict__ gw, const float* __restrict__ gb,
    const float* __restrict__ Wv_n, const float* __restrict__ Wq_n, const float* __restrict__ Wk_n,
    const float* __restrict__ WvO, const float* __restrict__ WqO, const float* __restrict__ WkO,
    float* __restrict__ hnew, float* __restrict__ h0out,
    float* __restrict__ vpre_n, float* __restrict__ wqk_n,
    float* __restrict__ wq2, float* __restrict__ U,
    int layer, int last)
{
    // rwswP: [wR2 2048 u32][wS2 2048 u32] fp16 j-pairs; later float-bits Wo / Wv_n / WvO-hi
    __shared__ uint32_t rwswP[4096];
    // rhs: first 2048 u32 = rh fp16 j-pairs (stride 16 u32/row); later P[8][528] f32; later Wskip / WvO-lo
    __shared__ __align__(16) float rhs[128 * 36];
    __shared__ __align__(16) float yss[128 * 20]; // Ys (stride 20, 16B-aligned); later hs[512]
    __shared__ __align__(16) float ub[1056];      // phase A: xs[384]|w1s[512]; post: hnS[528]|aggL[528]
    __shared__ float b1s[32];
    __shared__ float wqks[32];
    __shared__ float alphas[128];
    __shared__ float red[256];
    __shared__ float scale[128];
    __shared__ float sh_inv;

    int nblk = blockIdx.x, t = threadIdx.x;
    int g = nblk >> 7, b = nblk & 127;
    int gbase = g << 7;

    float* xs = ub;           // [384]
    float* w1s = ub + 384;    // [512]
    uint32_t* rh16 = reinterpret_cast<uint32_t*>(rhs);  // [128][16] fp16 j-pairs

    for (int o = t; o < 384; o += 256) xs[o] = x[gbase * 3 + o];
    for (int o = t; o < 512; o += 256) w1s[o] = w1[layer * 512 + o];
    if (t < 32) { b1s[t] = b1[layer * 32 + t]; wqks[t] = wqk[nblk * 32 + t]; }
    // stage rW/sW as fp16 j-pairs: wR2[(l*16+j2)*32+d] = (rW[l][2j2][d], rW[l][2j2+1][d])
    for (int idx = t; idx < 2048; idx += 256) {
        int d2 = idx & 31, j2 = (idx >> 5) & 15, l = idx >> 9;
        int src = layer * 4096 + l * 1024 + (2 * j2) * 32 + d2;
        rwswP[idx]        = f2h2(rW[src], rW[src + 32]);
        rwswP[2048 + idx] = f2h2(sW[src], sW[src + 32]);
    }
    __syncthreads();

    // ---- phase A: geometry, rh (fp32 for logit, fp16 j-pairs for GEMM), partial logit ----
    {
        int a = t & 127, dh = t >> 7;
        float rx = xs[b * 3 + 0] - xs[a * 3 + 0];
        float ry = xs[b * 3 + 1] - xs[a * 3 + 1];
        float rz = xs[b * 3 + 2] - xs[a * 3 + 2];
        float dd = sqrtf(rx * rx + ry * ry + rz * rz + 1e-12f);
        float inv = 1.f / dd;
        float ys[16];
        sph16(rx * inv, ry * inv, rz * inv, ys);
        if (dh == 0) {
#pragma unroll
            for (int m = 0; m < 16; m++) yss[a * 20 + m] = ys[m];
        }
        float rbf[16];
#pragma unroll
        for (int j = 0; j < 16; j++) {
            float dc = dd - (4.f / 15.f) * j;
            rbf[j] = __expf(-2.f * dc * dc);
        }
        float lpart = 0.f;
        int d0 = dh * 16;
        float sprev = 0.f;
        for (int d2 = 0; d2 < 16; d2++) {
            int d = d0 + d2;
            float s = b1s[d];
#pragma unroll
            for (int j = 0; j < 16; j++) s = fmaf(rbf[j], w1s[j * 32 + d], s);
            s = fmaxf(s, 0.f);
            lpart = fmaf(s, wqks[d], lpart);
            if (d2 & 1) rh16[a * 16 + dh * 8 + (d2 >> 1)] = f2h2(sprev, s);
            sprev = s;
        }
        red[t] = lpart;
    }
    __syncthreads();
    if (t < 128) alphas[t] = (red[t] + red[t + 128]) * 0.17677669529663687f; // 1/sqrt(32)
    __syncthreads();

    // ---- segment softmax over 127 valid edges (wave shuffle reductions) ----
    if (t < 128) {
        float m = (t != b) ? alphas[t] : -1e30f;
#pragma unroll
        for (int off = 32; off > 0; off >>= 1) m = fmaxf(m, __shfl_xor(m, off));
        if ((t & 63) == 0) red[t >> 6] = m;
    }
    __syncthreads();
    {
        float mx = fmaxf(red[0], red[1]);
        if (t < 128) {
            float e = (t != b) ? __expf(alphas[t] - mx) : 0.f;
            alphas[t] = e;
            float s = e;
#pragma unroll
            for (int off = 32; off > 0; off >>= 1) s += __shfl_xor(s, off);
            if ((t & 63) == 0) red[2 + (t >> 6)] = s;
        }
    }
    __syncthreads();
    if (t == 0) sh_inv = 1.f / (red[2] + red[3]);

    // ---- pass 2: dot2-based R/S GEMM + weighted aggregate ----
    int grp = t >> 5, d = t & 31;
    float acc[16];
#pragma unroll
    for (int m = 0; m < 16; m++) acc[m] = 0.f;

    for (int chunk = 0; chunk < 2; chunk++) {
        int a0 = grp * 16 + chunk * 8;
        float R[8][4], S[8][4];
#pragma unroll
        for (int aa = 0; aa < 8; aa++)
#pragma unroll
            for (int l = 0; l < 4; l++) { R[aa][l] = 0.f; S[aa][l] = 0.f; }

#pragma unroll 2
        for (int j8 = 0; j8 < 4; j8++) {           // 4 j-pair quads (8 j's each)
            uint4 rq[8];
#pragma unroll
            for (int aa = 0; aa < 8; aa++)
                rq[aa] = *reinterpret_cast<const uint4*>(&rh16[(a0 + aa) * 16 + j8 * 4]);
#pragma unroll
            for (int l = 0; l < 4; l++) {
#pragma unroll
                for (int jp = 0; jp < 4; jp++) {
                    uint32_t wr = rwswP[(l * 16 + j8 * 4 + jp) * 32 + d];
                    uint32_t ws = rwswP[2048 + (l * 16 + j8 * 4 + jp) * 32 + d];
#pragma unroll
                    for (int aa = 0; aa < 8; aa++) {
                        uint32_t rv = u4get(rq[aa], jp);
                        R[aa][l] = fdot2u(rv, wr, R[aa][l]);
                        S[aa][l] = fdot2u(rv, ws, S[aa][l]);
                    }
                }
            }
        }

        // epilogue: 2-deep double-buffered global loads (vpre rows + dense h0 sidecar)
        float4 A0, A1, A2, A3, B0, B1, B2, B3; float Ah, Bh;
        {
            const float4* p4 = reinterpret_cast<const float4*>(vpre + (gbase + a0) * 512 + d * 16);
            A0 = p4[0]; A1 = p4[1]; A2 = p4[2]; A3 = p4[3];
            Ah = h0in[(gbase + a0) * 32 + d];
            const float4* q4 = reinterpret_cast<const float4*>(vpre + (gbase + a0 + 1) * 512 + d * 16);
            B0 = q4[0]; B1 = q4[1]; B2 = q4[2]; B3 = q4[3];
            Bh = h0in[(gbase + a0 + 1) * 32 + d];
        }
#pragma unroll
        for (int ap = 0; ap < 4; ap++) {
            int aa = ap * 2;
            {
                float4 u0 = A0, u1 = A1, u2 = A2, u3 = A3; float h0v = Ah;
                if (ap < 3) {
                    const float4* p4 = reinterpret_cast<const float4*>(vpre + (gbase + a0 + aa + 2) * 512 + d * 16);
                    A0 = p4[0]; A1 = p4[1]; A2 = p4[2]; A3 = p4[3];
                    Ah = h0in[(gbase + a0 + aa + 2) * 32 + d];
                }
                PROC_SRC(aa, u0, u1, u2, u3, h0v)
            }
            {
                float4 u0 = B0, u1 = B1, u2 = B2, u3 = B3; float h0v = Bh;
                if (ap < 3) {
                    const float4* p4 = reinterpret_cast<const float4*>(vpre + (gbase + a0 + aa + 3) * 512 + d * 16);
                    B0 = p4[0]; B1 = p4[1]; B2 = p4[2]; B3 = p4[3];
                    Bh = h0in[(gbase + a0 + aa + 3) * 32 + d];
                }
                PROC_SRC(aa + 1, u0, u1, u2, u3, h0v)
            }
        }
    }
    __syncthreads();   // all pass-2 LDS reads (rh16/rwswP/yss) done

    // S1: partials into P (overlay rhs); stage h[n] (overlay yss); stage Wo (float bits in rwswP)
    float* P = rhs;
#pragma unroll
    for (int m = 0; m < 16; m++) P[grp * 528 + m * 33 + d] = acc[m];
    float* hs = yss;
    for (int o = t; o < 512; o += 256) hs[o] = h[nblk * 512 + o];
    for (int o = t; o < 4096; o += 256) rwswP[o] = __float_as_uint(Wo[layer * 4096 + o]);
    __syncthreads();

    // S2: reduce partials -> aggL[m*33+c]
    float* hnS = ub;          // [528]
    float* aggL = ub + 528;   // [528]
    float invs = sh_inv;
    for (int o = t; o < 512; o += 256) {
        int m = o >> 5, c = o & 31;
        float s = 0.f;
#pragma unroll
        for (int gg = 0; gg < 8; gg++) s += P[gg * 528 + m * 33 + c];
        aggL[m * 33 + c] = s * invs;
    }
    __syncthreads();

    // S3: stage Wskip into rhs (fp32), P dead
    for (int o = t; o < 4096; o += 256) rhs[o] = Wskip[layer * 4096 + o];
    __syncthreads();

    // S4: post GEMM: hn = h@Wskip + agg@Wo
    for (int o = t; o < 512; o += 256) {
        int m = o >> 5, dd = o & 31, l = lmap(m);
        float s = 0.f;
        const float* wa = &rhs[l * 1024 + dd];
        const uint32_t* wb = &rwswP[l * 1024 + dd];
        const float* hrow = &hs[m];
        const float* arow = &aggL[m * 33];
#pragma unroll
        for (int c = 0; c < 32; c++) {
            s = fmaf(hrow[c * 16], wa[c * 32], s);
            s = fmaf(arow[c], __uint_as_float(wb[c * 32]), s);
        }
        hnS[m * 33 + dd] = s;
    }
    __syncthreads();

    // S5: norm gate compute + stage next-stage value weights
    if (t < 128) {
        int dd = t >> 2, l = t & 3;
        int m0 = l * l, cnt = 2 * l + 1;
        float s = 1e-12f;
        for (int m = m0; m < m0 + cnt; m++) { float v = hnS[m * 33 + dd]; s = fmaf(v, v, s); }
        float nr = sqrtf(s);
        float phi = fmaxf(nr * gw[(layer * 4 + l) * 32 + dd] + gb[(layer * 4 + l) * 32 + dd], 0.f);
        scale[dd * 4 + l] = phi / (nr + 1e-6f);
    }
    if (!last) {
        for (int o = t; o < 4096; o += 256) rwswP[o] = __float_as_uint(Wv_n[o]);
    } else {
        for (int o = t; o < 4096; o += 256) {
            rhs[o] = WvO[o];                                   // l = 0,1
            rwswP[o] = __float_as_uint(WvO[4096 + o]);         // l = 2,3
        }
    }
    __syncthreads();

    // S6: apply gate, write hnew
    for (int o = t; o < 512; o += 256) {
        int dd = o >> 4, m = o & 15;
        float v = hnS[m * 33 + dd] * scale[dd * 4 + lmap(m)];
        hnew[nblk * 512 + o] = v;
        hnS[m * 33 + dd] = v;
    }
    __syncthreads();

    // dense h0 sidecar: one coalesced wave-store of the gated m=0 column
    if (t < 32) h0out[nblk * 32 + t] = hnS[t];

    if (!last) {
        for (int o = t; o < 512; o += 256) {
            int dd = o >> 4, m = o & 15, l = lmap(m);
            float s = 0.f;
            const uint32_t* wv = &rwswP[l * 1024 + dd];
            const float* hrow = &hnS[m * 33];
#pragma unroll
            for (int c = 0; c < 32; c++) s = fmaf(hrow[c], __uint_as_float(wv[c * 32]), s);
            vpre_n[nblk * 512 + o] = s;
        }
        if (t < 32) {
            float s = 0.f;
#pragma unroll
            for (int c = 0; c < 32; c++) s = fmaf(hnS[c * 33], Wq_n[c * 32 + t], s);
            red[t] = s;
        }
        __syncthreads();
        if (t < 32) {
            float s = 0.f;
#pragma unroll
            for (int j = 0; j < 32; j++) s = fmaf(Wk_n[t * 32 + j], red[j], s);
            wqk_n[nblk * 32 + t] = s;
        }
    } else {
        for (int o = t; o < 1024; o += 256) {
            int j = o >> 4, m = o & 15, l = lmap(m);
            float s = 0.f;
            const float* hrow = &hnS[m * 33];
            if (l < 2) {
                const float* wv = &rhs[l * 2048 + j];
#pragma unroll
                for (int c = 0; c < 32; c++) s = fmaf(hrow[c], wv[c * 64], s);
            } else {
                const uint32_t* wv = &rwswP[(l - 2) * 2048 + j];
#pragma unroll
                for (int c = 0; c < 32; c++) s = fmaf(hrow[c], __uint_as_float(wv[c * 64]), s);
            }
            U[nblk * 1024 + o] = s;
        }
        if (t < 64) {
            float s = 0.f;
#pragma unroll
            for (int c = 0; c < 32; c++) s = fmaf(hnS[c * 33], WqO[c * 64 + t], s);
            red[t] = s;
        }
        __syncthreads();
        if (t < 32) {
            float s = 0.f;
#pragma unroll
            for (int j = 0; j < 64; j++) s = fmaf(WkO[t * 64 + j], red[j], s);
            wq2[nblk * 32 + t] = s;
        }
    }
}

// Output-stage edge kernel + fused out_post (hout). 3 blocks/CU.
__global__ __launch_bounds__(256, 3) void k_out_edge(
    const float* __restrict__ x, const float* __restrict__ h0f,
    const float* __restrict__ w1o, const float* __restrict__ b1o,
    const float* __restrict__ wq2, const float* __restrict__ roW,
    const float* __restrict__ U, const float* __restrict__ WoO,
    const float* __restrict__ WskipO, float* __restrict__ hout)
{
    __shared__ uint32_t rosP[4096];               // fp16 pairs of roW c-neighbors
    __shared__ __align__(16) float rhs[128 * 36];
    __shared__ __align__(16) float yss[128 * 20];
    __shared__ float xs[384];
    __shared__ float w1s[512];
    __shared__ float b1s[32];
    __shared__ float wq2s[32];
    __shared__ float alphas[128];
    __shared__ float red[256];
    __shared__ float agg64s[64];
    __shared__ float sh_inv;

    int n = blockIdx.x, t = threadIdx.x;
    int g = n >> 7, b = n & 127;
    int gbase = g << 7;

    for (int o = t; o < 384; o += 256) xs[o] = x[gbase * 3 + o];
    for (int o = t; o < 512; o += 256) w1s[o] = w1o[o];
    if (t < 32) { b1s[t] = b1o[t]; wq2s[t] = wq2[n * 32 + t]; }
    for (int o = t; o < 4096; o += 256) {
        int j = o & 63, lc = o >> 6, cp = lc & 15, l = lc >> 4;
        rosP[o] = f2h2(roW[(l * 32 + 2 * cp) * 64 + j], roW[(l * 32 + 2 * cp + 1) * 64 + j]);
    }
    __syncthreads();

    // phase A split across 256 threads
    {
        int a = t & 127, dh = t >> 7;
        float rx = xs[b * 3 + 0] - xs[a * 3 + 0];
        float ry = xs[b * 3 + 1] - xs[a * 3 + 1];
        float rz = xs[b * 3 + 2] - xs[a * 3 + 2];
        float dd = sqrtf(rx * rx + ry * ry + rz * rz + 1e-12f);
        float inv = 1.f / dd;
        float ys[16];
        sph16(rx * inv, ry * inv, rz * inv, ys);
        if (dh == 0) {
#pragma unroll
            for (int m = 0; m < 16; m++) yss[a * 20 + m] = ys[m];
        }
        float rbf[16];
#pragma unroll
        for (int j = 0; j < 16; j++) {
            float dc = dd - (4.f / 15.f) * j;
            rbf[j] = __expf(-2.f * dc * dc);
        }
        float lpart = 0.f;
        int d0 = dh * 16;
        for (int d2 = 0; d2 < 16; d2++) {
            int d = d0 + d2;
            float s = b1s[d];
#pragma unroll
            for (int j = 0; j < 16; j++) s = fmaf(rbf[j], w1s[j * 32 + d], s);
            s = fmaxf(s, 0.f);
            rhs[a * 36 + d] = s;
            lpart = fmaf(s, wq2s[d], lpart);
        }
        red[t] = lpart;
    }
    __syncthreads();
    if (t < 128) alphas[t] = (red[t] + red[t + 128]) * 0.125f; // 1/sqrt(64)
    __syncthreads();

    if (t < 128) {
        float m = (t != b) ? alphas[t] : -1e30f;
#pragma unroll
        for (int off = 32; off > 0; off >>= 1) m = fmaxf(m, __shfl_xor(m, off));
        if ((t & 63) == 0) red[t >> 6] = m;
    }
    __syncthreads();
    {
        float mx = fmaxf(red[0], red[1]);
        if (t < 128) {
            float e = (t != b) ? __expf(alphas[t] - mx) : 0.f;
            alphas[t] = e;
            float s = e;
#pragma unroll
            for (int off = 32; off > 0; off >>= 1) s += __shfl_xor(s, off);
            if ((t & 63) == 0) red[2 + (t >> 6)] = s;
        }
    }
    __syncthreads();
    if (t == 0) sh_inv = 1.f / (red[2] + red[3]);
    __syncthreads();

    int grp = t >> 6, j = t & 63;
    float accO = 0.f;
    for (int chunk = 0; chunk < 4; chunk++) {
        int a0 = grp * 32 + chunk * 8;
        float RO[8][4];
#pragma unroll
        for (int aa = 0; aa < 8; aa++)
#pragma unroll
            for (int l = 0; l < 4; l++) RO[aa][l] = 0.f;

#pragma unroll 2
        for (int cq = 0; cq < 8; cq++) {
            float4 rh4[8];
#pragma unroll
            for (int aa = 0; aa < 8; aa++)
                rh4[aa] = *reinterpret_cast<const float4*>(&rhs[(a0 + aa) * 36 + cq * 4]);
#pragma unroll
            for (int l = 0; l < 4; l++) {
#pragma unroll
                for (int ch = 0; ch < 2; ch++) {
                    float2 w2 = h2f2(rosP[(l * 16 + cq * 2 + ch) * 64 + j]);
#pragma unroll
                    for (int aa = 0; aa < 8; aa++) {
                        RO[aa][l] = fmaf(f4get(rh4[aa], 2 * ch), w2.x, RO[aa][l]);
                        RO[aa][l] = fmaf(f4get(rh4[aa], 2 * ch + 1), w2.y, RO[aa][l]);
                    }
                }
            }
        }

        float4 A0, A1, A2, A3, B0, B1, B2, B3;
        {
            const float4* p4 = reinterpret_cast<const float4*>(U + (gbase + a0) * 1024 + j * 16);
            A0 = p4[0]; A1 = p4[1]; A2 = p4[2]; A3 = p4[3];
            const float4* q4 = reinterpret_cast<const float4*>(U + (gbase + a0 + 1) * 1024 + j * 16);
            B0 = q4[0]; B1 = q4[1]; B2 = q4[2]; B3 = q4[3];
        }
#define PROC_O(aa, u0, u1, u2, u3) { \
        int a_ = a0 + (aa); \
        float w_ = alphas[a_]; \
        if (w_ != 0.f) { \
            const float4* yp = reinterpret_cast<const float4*>(&yss[a_ * 20]); \
            float4 y0 = yp[0], y1 = yp[1], y2 = yp[2], y3 = yp[3]; \
            float cv0 = y0.x * (u0).x; \
            float cv1 = fmaf(y0.y, (u0).y, fmaf(y0.z, (u0).z, y0.w * (u0).w)); \
            float cv2 = fmaf(y1.x, (u1).x, fmaf(y1.y, (u1).y, fmaf(y1.z, (u1).z, fmaf(y1.w, (u1).w, y2.x * (u2).x)))); \
            float cv3 = fmaf(y2.y, (u2).y, fmaf(y2.z, (u2).z, fmaf(y2.w, (u2).w, \
                        fmaf(y3.x, (u3).x, fmaf(y3.y, (u3).y, fmaf(y3.z, (u3).z, y3.w * (u3).w)))))); \
            float s_ = fmaf(cv0, RO[aa][0], fmaf(cv1, RO[aa][1], fmaf(cv2, RO[aa][2], cv3 * RO[aa][3]))); \
            accO = fmaf(w_, s_, accO); \
        } }
#pragma unroll
        for (int ap = 0; ap < 4; ap++) {
            int aa = ap * 2;
            {
                float4 u0 = A0, u1 = A1, u2 = A2, u3 = A3;
                if (ap < 3) {
                    const float4* p4 = reinterpret_cast<const float4*>(U + (gbase + a0 + aa + 2) * 1024 + j * 16);
                    A0 = p4[0]; A1 = p4[1]; A2 = p4[2]; A3 = p4[3];
                }
                PROC_O(aa, u0, u1, u2, u3)
            }
            {
                float4 u0 = B0, u1 = B1, u2 = B2, u3 = B3;
                if (ap < 3) {
                    const float4* p4 = reinterpret_cast<const float4*>(U + (gbase + a0 + aa + 3) * 1024 + j * 16);
                    B0 = p4[0]; B1 = p4[1]; B2 = p4[2]; B3 = p4[3];
                }
                PROC_O(aa + 1, u0, u1, u2, u3)
            }
        }
#undef PROC_O
    }
    red[t] = accO;
    __syncthreads();
    if (t < 64) agg64s[t] = (red[t] + red[64 + t] + red[128 + t] + red[192 + t]) * sh_inv;
    __syncthreads();

    if (t < 64) {
        float s = 0.f;
#pragma unroll
        for (int c = 0; c < 64; c++) s = fmaf(agg64s[c], WoO[c * 64 + t], s);
        const float* hr = &h0f[n * 32];
#pragma unroll
        for (int c = 0; c < 32; c++) s = fmaf(hr[c], WskipO[c * 64 + t], s);
        hout[n * 64 + t] = s;
    }
}

__global__ __launch_bounds__(64) void k_final(
    const float* __restrict__ hout, const float* __restrict__ Whid,
    const float* __restrict__ bhid, const float* __restrict__ Wout,
    const float* __restrict__ bout, float* __restrict__ out)
{
    __shared__ float pooled[64], hid[64];
    int g = blockIdx.x, t = threadIdx.x;
    float s = 0.f;
    for (int p = 0; p < 128; p++) s += hout[(g * 128 + p) * 64 + t];
    pooled[t] = s * (1.f / 128.f);
    __syncthreads();
    float hv = bhid[t];
#pragma unroll
    for (int c = 0; c < 64; c++) hv = fmaf(pooled[c], Whid[c * 64 + t], hv);
    hid[t] = fmaxf(hv, 0.f);
    __syncthreads();
    if (t < 15) {
        float o = bout[t];
#pragma unroll
        for (int c = 0; c < 64; c++) o = fmaf(hid[c], Wout[c * 15 + t], o);
        out[g * 15 + t] = o;
    }
}

extern "C" void kernel_launch(void* const* d_in, const int* in_sizes, int n_in,
                              void* d_out, int out_size, void* d_ws, size_t ws_size,
                              hipStream_t stream) {
    const float* x      = (const float*)d_in[0];
    const float* w1     = (const float*)d_in[1];
    const float* b1     = (const float*)d_in[2];
    const float* rW     = (const float*)d_in[3];
    const float* sW     = (const float*)d_in[4];
    const float* Wv     = (const float*)d_in[5];
    const float* Wq     = (const float*)d_in[6];
    const float* Wk     = (const float*)d_in[7];
    const float* Wo     = (const float*)d_in[8];
    const float* Wskip  = (const float*)d_in[9];
    const float* gw     = (const float*)d_in[10];
    const float* gb     = (const float*)d_in[11];
    const float* w1o    = (const float*)d_in[12];
    const float* b1o    = (const float*)d_in[13];
    const float* roW    = (const float*)d_in[14];
    const float* WvO    = (const float*)d_in[15];
    const float* WqO    = (const float*)d_in[16];
    const float* WkO    = (const float*)d_in[17];
    const float* WoO    = (const float*)d_in[18];
    const float* WskipO = (const float*)d_in[19];
    const float* Whid   = (const float*)d_in[20];
    const float* bhid   = (const float*)d_in[21];
    const float* Wout   = (const float*)d_in[22];
    const float* bout   = (const float*)d_in[23];
    float* out = (float*)d_out;

    float* ws = (float*)d_ws;
    float* h0    = ws;
    float* h1    = h0 + NNODE * 512;
    float* vA    = h1 + NNODE * 512;
    float* wqkA  = vA + NNODE * 512;
    float* vB    = wqkA + NNODE * 32;
    float* wqkB  = vB + NNODE * 512;
    float* wq2   = wqkB + NNODE * 32;
    float* U     = wq2 + NNODE * 32;
    float* hout  = U + NNODE * 1024;
    float* s0A   = hout + NNODE * 64;
    float* s0B   = s0A + NNODE * 32;

    hipMemsetAsync(h0, 0, NNODE * 512 * sizeof(float), stream);
    hipMemsetAsync(vA, 0, (NNODE * 512 + NNODE * 32) * sizeof(float), stream);
    hipMemsetAsync(s0A, 0, NNODE * 32 * sizeof(float), stream);

    for (int i = 0; i < 4; i++) {
        const float* hc  = (i & 1) ? h1 : h0;
        float*       hn  = (i & 1) ? h0 : h1;
        const float* vin  = (i & 1) ? vB : vA;
        const float* qin  = (i & 1) ? wqkB : wqkA;
        float*       vout = (i & 1) ? vA : vB;
        float*       qout = (i & 1) ? wqkA : wqkB;
        const float* s0in = (i & 1) ? s0B : s0A;
        float*       s0out= (i & 1) ? s0A : s0B;
        int last = (i == 3);
        k_layer<<<NNODE, 256, 0, stream>>>(
            x, hc, s0in, vin, qin, w1, b1, rW, sW, Wskip, Wo, gw, gb,
            Wv + (last ? 0 : (i + 1) * 4096),
            Wq + (last ? 0 : (i + 1) * 1024),
            Wk + (last ? 0 : (i + 1) * 1024),
            WvO, WqO, WkO,
            hn, s0out, vout, qout, wq2, U, i, last);
    }
    // final h0 sidecar: i=3 wrote s0A
    k_out_edge<<<NNODE, 256, 0, stream>>>(x, s0A, w1o, b1o, wq2, roW, U, WoO, WskipO, hout);
    k_final<<<NGRAPH, 64, 0, stream>>>(hout, Whid, bhid, Wout, bout, out);
}

// Round 12
// 527.719 us; speedup vs baseline: 2.1065x; 1.0021x over previous
//
#include <hip/hip_runtime.h>
#include <hip/hip_bf16.h>
#include <hip/hip_fp16.h>

#define NNODE 2048
#define NGRAPH 16

typedef _Float16 h2v __attribute__((ext_vector_type(2)));

__device__ __forceinline__ int lmap(int m) { return m == 0 ? 0 : (m < 4 ? 1 : (m < 9 ? 2 : 3)); }

__device__ __forceinline__ float f4get(const float4& v, int j) {
    return j == 0 ? v.x : (j == 1 ? v.y : (j == 2 ? v.z : v.w));
}
__device__ __forceinline__ uint32_t u4get(const uint4& v, int j) {
    return j == 0 ? v.x : (j == 1 ? v.y : (j == 2 ? v.z : v.w));
}

// pack two floats as fp16 pair in a u32 (lo = a, hi = b)
__device__ __forceinline__ uint32_t f2h2(float a, float b) {
    __half2 h2 = __floats2half2_rn(a, b);
    return *reinterpret_cast<uint32_t*>(&h2);
}
__device__ __forceinline__ float2 h2f2(uint32_t u) {
    __half2 h2 = *reinterpret_cast<__half2*>(&u);
    return __half22float2(h2);
}

// 2-way f16 dot with fp32 accumulate (V_DOT2_F32_F16); safe fallback
__device__ __forceinline__ float fdot2u(uint32_t a, uint32_t b, float c) {
#if defined(__has_builtin)
#if __has_builtin(__builtin_amdgcn_fdot2)
    return __builtin_amdgcn_fdot2(__builtin_bit_cast(h2v, a), __builtin_bit_cast(h2v, b), c, false);
#else
    float2 af = h2f2(a), bf = h2f2(b);
    return fmaf(af.x, bf.x, fmaf(af.y, bf.y, c));
#endif
#else
    float2 af = h2f2(a), bf = h2f2(b);
    return fmaf(af.x, bf.x, fmaf(af.y, bf.y, c));
#endif
}

__device__ __forceinline__ void sph16(float x, float y, float z, float* Y) {
    Y[0] = 0.28209479177f;
    Y[1] = 0.4886025119f * y; Y[2] = 0.4886025119f * z; Y[3] = 0.4886025119f * x;
    Y[4] = 1.09254843059f * x * y;
    Y[5] = 1.09254843059f * y * z;
    Y[6] = 0.31539156525f * (3.f * z * z - 1.f);
    Y[7] = 1.09254843059f * x * z;
    Y[8] = 0.54627421529f * (x * x - y * y);
    Y[9]  = 0.59004358992f * y * (3.f * x * x - y * y);
    Y[10] = 2.89061144264f * x * y * z;
    Y[11] = 0.45704579946f * y * (5.f * z * z - 1.f);
    Y[12] = 0.37317633259f * z * (5.f * z * z - 3.f);
    Y[13] = 0.45704579946f * x * (5.f * z * z - 1.f);
    Y[14] = 1.44530572132f * z * (x * x - y * y);
    Y[15] = 0.59004358992f * x * (x * x - 3.f * y * y);
}

#define PROC_SRC(aa, u0, u1, u2, u3, h0v) { \
    int a_ = a0 + (aa); \
    float w_ = alphas[a_]; \
    if (w_ != 0.f) { \
        const float4* yp = reinterpret_cast<const float4*>(&yss[a_ * 20]); \
        float4 y0 = yp[0], y1 = yp[1], y2 = yp[2], y3 = yp[3]; \
        float hb1 = (h0v) + 1.f; \
        float sc0 = S[aa][0] * hb1, sc1 = S[aa][1] * hb1; \
        float sc2 = S[aa][2] * hb1, sc3 = S[aa][3] * hb1; \
        acc[0]  = fmaf(w_, fmaf((u0).x, R[aa][0], sc0 * y0.x), acc[0]); \
        acc[1]  = fmaf(w_, fmaf((u0).y, R[aa][1], sc1 * y0.y), acc[1]); \
        acc[2]  = fmaf(w_, fmaf((u0).z, R[aa][1], sc1 * y0.z), acc[2]); \
        acc[3]  = fmaf(w_, fmaf((u0).w, R[aa][1], sc1 * y0.w), acc[3]); \
        acc[4]  = fmaf(w_, fmaf((u1).x, R[aa][2], sc2 * y1.x), acc[4]); \
        acc[5]  = fmaf(w_, fmaf((u1).y, R[aa][2], sc2 * y1.y), acc[5]); \
        acc[6]  = fmaf(w_, fmaf((u1).z, R[aa][2], sc2 * y1.z), acc[6]); \
        acc[7]  = fmaf(w_, fmaf((u1).w, R[aa][2], sc2 * y1.w), acc[7]); \
        acc[8]  = fmaf(w_, fmaf((u2).x, R[aa][2], sc2 * y2.x), acc[8]); \
        acc[9]  = fmaf(w_, fmaf((u2).y, R[aa][3], sc3 * y2.y), acc[9]); \
        acc[10] = fmaf(w_, fmaf((u2).z, R[aa][3], sc3 * y2.z), acc[10]); \
        acc[11] = fmaf(w_, fmaf((u2).w, R[aa][3], sc3 * y2.w), acc[11]); \
        acc[12] = fmaf(w_, fmaf((u3).x, R[aa][3], sc3 * y3.x), acc[12]); \
        acc[13] = fmaf(w_, fmaf((u3).y, R[aa][3], sc3 * y3.y), acc[13]); \
        acc[14] = fmaf(w_, fmaf((u3).z, R[aa][3], sc3 * y3.z), acc[14]); \
        acc[15] = fmaf(w_, fmaf((u3).w, R[aa][3], sc3 * y3.w), acc[15]); \
    } }

// One fused layer. 3 blocks/CU (LDS ~51KB).
__global__ __launch_bounds__(256, 3) void k_layer(
    const float* __restrict__ x, const float* __restrict__ h,
    const float* __restrict__ h0in, const float* __restrict__ vpre,
    const float* __restrict__ wqk,
    const float* __restrict__ w1, const float* __restrict__ b1,
    const float* __restrict__ rW, const float* __restrict__ sW,
    const float* __restrict__ Wskip, const float* __restrict__ Wo,
    const float* __restrict__ gw, const float* __restrict__ gb,
    const float* __restrict__ Wv_n, const float* __restrict__ Wq_n, const float* __restrict__ Wk_n,
    const float* __restrict__ WvO, const float* __restrict__ WqO, const float* __restrict__ WkO,
    float* __restrict__ hnew, float* __restrict__ h0out,
    float* __restrict__ vpre_n, float* __restrict__ wqk_n,
    float* __restrict__ wq2, float* __restrict__ U,
    int layer, int last)
{
    // rwswP: [wR2 2048 u32][wS2 2048 u32] fp16 j-pairs; later float-bits Wo / Wv_n / WvO-hi
    __shared__ uint32_t rwswP[4096];
    // rhs: first 2048 u32 = rh fp16 j-pairs (stride 16 u32/row); later P[8][528] f32; later Wskip / WvO-lo
    __shared__ __align__(16) float rhs[128 * 36];
    __shared__ __align__(16) float yss[128 * 20]; // Ys (stride 20, 16B-aligned); later hs[512]
    __shared__ __align__(16) float ub[1056];      // phase A: xs[384]|w1s[512]; post: hnS[528]|aggL[528]
    __shared__ float b1s[32];
    __shared__ float wqks[32];
    __shared__ float alphas[128];
    __shared__ float red[256];
    __shared__ float scale[128];
    __shared__ float sh_inv;

    int nblk = blockIdx.x, t = threadIdx.x;
    int g = nblk >> 7, b = nblk & 127;
    int gbase = g << 7;

    float* xs = ub;           // [384]
    float* w1s = ub + 384;    // [512]
    uint32_t* rh16 = reinterpret_cast<uint32_t*>(rhs);  // [128][16] fp16 j-pairs

    for (int o = t; o < 384; o += 256) xs[o] = x[gbase * 3 + o];
    for (int o = t; o < 512; o += 256) w1s[o] = w1[layer * 512 + o];
    if (t < 32) { b1s[t] = b1[layer * 32 + t]; wqks[t] = wqk[nblk * 32 + t]; }
    // stage rW/sW as fp16 j-pairs: wR2[(l*16+j2)*32+d] = (rW[l][2j2][d], rW[l][2j2+1][d])
    for (int idx = t; idx < 2048; idx += 256) {
        int d2 = idx & 31, j2 = (idx >> 5) & 15, l = idx >> 9;
        int src = layer * 4096 + l * 1024 + (2 * j2) * 32 + d2;
        rwswP[idx]        = f2h2(rW[src], rW[src + 32]);
        rwswP[2048 + idx] = f2h2(sW[src], sW[src + 32]);
    }
    __syncthreads();

    // ---- phase A: geometry, rh (fp32 for logit, fp16 j-pairs for GEMM), partial logit ----
    {
        int a = t & 127, dh = t >> 7;
        float rx = xs[b * 3 + 0] - xs[a * 3 + 0];
        float ry = xs[b * 3 + 1] - xs[a * 3 + 1];
        float rz = xs[b * 3 + 2] - xs[a * 3 + 2];
        float dd = sqrtf(rx * rx + ry * ry + rz * rz + 1e-12f);
        float inv = 1.f / dd;
        float ys[16];
        sph16(rx * inv, ry * inv, rz * inv, ys);
        if (dh == 0) {
#pragma unroll
            for (int m = 0; m < 16; m++) yss[a * 20 + m] = ys[m];
        }
        float rbf[16];
#pragma unroll
        for (int j = 0; j < 16; j++) {
            float dc = dd - (4.f / 15.f) * j;
            rbf[j] = __expf(-2.f * dc * dc);
        }
        float lpart = 0.f;
        int d0 = dh * 16;
        float sprev = 0.f;
        for (int d2 = 0; d2 < 16; d2++) {
            int d = d0 + d2;
            float s = b1s[d];
#pragma unroll
            for (int j = 0; j < 16; j++) s = fmaf(rbf[j], w1s[j * 32 + d], s);
            s = fmaxf(s, 0.f);
            lpart = fmaf(s, wqks[d], lpart);
            if (d2 & 1) rh16[a * 16 + dh * 8 + (d2 >> 1)] = f2h2(sprev, s);
            sprev = s;
        }
        red[t] = lpart;
    }
    __syncthreads();
    if (t < 128) alphas[t] = (red[t] + red[t + 128]) * 0.17677669529663687f; // 1/sqrt(32)
    __syncthreads();

    // ---- segment softmax over 127 valid edges (wave shuffle reductions) ----
    if (t < 128) {
        float m = (t != b) ? alphas[t] : -1e30f;
#pragma unroll
        for (int off = 32; off > 0; off >>= 1) m = fmaxf(m, __shfl_xor(m, off));
        if ((t & 63) == 0) red[t >> 6] = m;
    }
    __syncthreads();
    {
        float mx = fmaxf(red[0], red[1]);
        if (t < 128) {
            float e = (t != b) ? __expf(alphas[t] - mx) : 0.f;
            alphas[t] = e;
            float s = e;
#pragma unroll
            for (int off = 32; off > 0; off >>= 1) s += __shfl_xor(s, off);
            if ((t & 63) == 0) red[2 + (t >> 6)] = s;
        }
    }
    __syncthreads();
    if (t == 0) sh_inv = 1.f / (red[2] + red[3]);

    // ---- pass 2: dot2-based R/S GEMM + weighted aggregate ----
    int grp = t >> 5, d = t & 31;
    float acc[16];
#pragma unroll
    for (int m = 0; m < 16; m++) acc[m] = 0.f;

    for (int chunk = 0; chunk < 2; chunk++) {
        int a0 = grp * 16 + chunk * 8;
        float R[8][4], S[8][4];
#pragma unroll
        for (int aa = 0; aa < 8; aa++)
#pragma unroll
            for (int l = 0; l < 4; l++) { R[aa][l] = 0.f; S[aa][l] = 0.f; }

#pragma unroll 2
        for (int j8 = 0; j8 < 4; j8++) {           // 4 j-pair quads (8 j's each)
            uint4 rq[8];
#pragma unroll
            for (int aa = 0; aa < 8; aa++)
                rq[aa] = *reinterpret_cast<const uint4*>(&rh16[(a0 + aa) * 16 + j8 * 4]);
#pragma unroll
            for (int l = 0; l < 4; l++) {
#pragma unroll
                for (int jp = 0; jp < 4; jp++) {
                    uint32_t wr = rwswP[(l * 16 + j8 * 4 + jp) * 32 + d];
                    uint32_t ws = rwswP[2048 + (l * 16 + j8 * 4 + jp) * 32 + d];
#pragma unroll
                    for (int aa = 0; aa < 8; aa++) {
                        uint32_t rv = u4get(rq[aa], jp);
                        R[aa][l] = fdot2u(rv, wr, R[aa][l]);
                        S[aa][l] = fdot2u(rv, ws, S[aa][l]);
                    }
                }
            }
        }

        // epilogue: 2-deep double-buffered global loads (vpre rows + dense h0 sidecar)
        float4 A0, A1, A2, A3, B0, B1, B2, B3; float Ah, Bh;
        {
            const float4* p4 = reinterpret_cast<const float4*>(vpre + (gbase + a0) * 512 + d * 16);
            A0 = p4[0]; A1 = p4[1]; A2 = p4[2]; A3 = p4[3];
            Ah = h0in[(gbase + a0) * 32 + d];
            const float4* q4 = reinterpret_cast<const float4*>(vpre + (gbase + a0 + 1) * 512 + d * 16);
            B0 = q4[0]; B1 = q4[1]; B2 = q4[2]; B3 = q4[3];
            Bh = h0in[(gbase + a0 + 1) * 32 + d];
        }
#pragma unroll
        for (int ap = 0; ap < 4; ap++) {
            int aa = ap * 2;
            {
                float4 u0 = A0, u1 = A1, u2 = A2, u3 = A3; float h0v = Ah;
                if (ap < 3) {
                    const float4* p4 = reinterpret_cast<const float4*>(vpre + (gbase + a0 + aa + 2) * 512 + d * 16);
                    A0 = p4[0]; A1 = p4[1]; A2 = p4[2]; A3 = p4[3];
                    Ah = h0in[(gbase + a0 + aa + 2) * 32 + d];
                }
                PROC_SRC(aa, u0, u1, u2, u3, h0v)
            }
            {
                float4 u0 = B0, u1 = B1, u2 = B2, u3 = B3; float h0v = Bh;
                if (ap < 3) {
                    const float4* p4 = reinterpret_cast<const float4*>(vpre + (gbase + a0 + aa + 3) * 512 + d * 16);
                    B0 = p4[0]; B1 = p4[1]; B2 = p4[2]; B3 = p4[3];
                    Bh = h0in[(gbase + a0 + aa + 3) * 32 + d];
                }
                PROC_SRC(aa + 1, u0, u1, u2, u3, h0v)
            }
        }
    }
    __syncthreads();   // all pass-2 LDS reads (rh16/rwswP/yss) done

    // S1: partials into P (overlay rhs); stage h[n] (overlay yss); stage Wo (float bits in rwswP)
    float* P = rhs;
#pragma unroll
    for (int m = 0; m < 16; m++) P[grp * 528 + m * 33 + d] = acc[m];
    float* hs = yss;
    for (int o = t; o < 512; o += 256) hs[o] = h[nblk * 512 + o];
    for (int o = t; o < 4096; o += 256) rwswP[o] = __float_as_uint(Wo[layer * 4096 + o]);
    __syncthreads();

    // S2: reduce partials -> aggL[m*33+c]
    float* hnS = ub;          // [528]
    float* aggL = ub + 528;   // [528]
    float invs = sh_inv;
    for (int o = t; o < 512; o += 256) {
        int m = o >> 5, c = o & 31;
        float s = 0.f;
#pragma unroll
        for (int gg = 0; gg < 8; gg++) s += P[gg * 528 + m * 33 + c];
        aggL[m * 33 + c] = s * invs;
    }
    __syncthreads();

    // S3: stage Wskip into rhs (fp32), P dead
    for (int o = t; o < 4096; o += 256) rhs[o] = Wskip[layer * 4096 + o];
    __syncthreads();

    // S4: post GEMM: hn = h@Wskip + agg@Wo
    for (int o = t; o < 512; o += 256) {
        int m = o >> 5, dd = o & 31, l = lmap(m);
        float s = 0.f;
        const float* wa = &rhs[l * 1024 + dd];
        const uint32_t* wb = &rwswP[l * 1024 + dd];
        const float* hrow = &hs[m];
        const float* arow = &aggL[m * 33];
#pragma unroll
        for (int c = 0; c < 32; c++) {
            s = fmaf(hrow[c * 16], wa[c * 32], s);
            s = fmaf(arow[c], __uint_as_float(wb[c * 32]), s);
        }
        hnS[m * 33 + dd] = s;
    }
    __syncthreads();

    // S5: norm gate compute + stage next-stage value weights
    if (t < 128) {
        int dd = t >> 2, l = t & 3;
        int m0 = l * l, cnt = 2 * l + 1;
        float s = 1e-12f;
        for (int m = m0; m < m0 + cnt; m++) { float v = hnS[m * 33 + dd]; s = fmaf(v, v, s); }
        float nr = sqrtf(s);
        float phi = fmaxf(nr * gw[(layer * 4 + l) * 32 + dd] + gb[(layer * 4 + l) * 32 + dd], 0.f);
        scale[dd * 4 + l] = phi / (nr + 1e-6f);
    }
    if (!last) {
        for (int o = t; o < 4096; o += 256) rwswP[o] = __float_as_uint(Wv_n[o]);
    } else {
        for (int o = t; o < 4096; o += 256) {
            rhs[o] = WvO[o];                                   // l = 0,1
            rwswP[o] = __float_as_uint(WvO[4096 + o]);         // l = 2,3
        }
    }
    __syncthreads();

    // S6: apply gate, write hnew
    for (int o = t; o < 512; o += 256) {
        int dd = o >> 4, m = o & 15;
        float v = hnS[m * 33 + dd] * scale[dd * 4 + lmap(m)];
        hnew[nblk * 512 + o] = v;
        hnS[m * 33 + dd] = v;
    }
    __syncthreads();

    // dense h0 sidecar: one coalesced wave-store of the gated m=0 column
    if (t < 32) h0out[nblk * 32 + t] = hnS[t];

    if (!last) {
        for (int o = t; o < 512; o += 256) {
            int dd = o >> 4, m = o & 15, l = lmap(m);
            float s = 0.f;
            const uint32_t* wv = &rwswP[l * 1024 + dd];
            const float* hrow = &hnS[m * 33];
#pragma unroll
            for (int c = 0; c < 32; c++) s = fmaf(hrow[c], __uint_as_float(wv[c * 32]), s);
            vpre_n[nblk * 512 + o] = s;
        }
        if (t < 32) {
            float s = 0.f;
#pragma unroll
            for (int c = 0; c < 32; c++) s = fmaf(hnS[c * 33], Wq_n[c * 32 + t], s);
            red[t] = s;
        }
        __syncthreads();
        if (t < 32) {
            float s = 0.f;
#pragma unroll
            for (int j = 0; j < 32; j++) s = fmaf(Wk_n[t * 32 + j], red[j], s);
            wqk_n[nblk * 32 + t] = s;
        }
    } else {
        for (int o = t; o < 1024; o += 256) {
            int j = o >> 4, m = o & 15, l = lmap(m);
            float s = 0.f;
            const float* hrow = &hnS[m * 33];
            if (l < 2) {
                const float* wv = &rhs[l * 2048 + j];
#pragma unroll
                for (int c = 0; c < 32; c++) s = fmaf(hrow[c], wv[c * 64], s);
            } else {
                const uint32_t* wv = &rwswP[(l - 2) * 2048 + j];
#pragma unroll
                for (int c = 0; c < 32; c++) s = fmaf(hrow[c], __uint_as_float(wv[c * 64]), s);
            }
            U[nblk * 1024 + o] = s;
        }
        if (t < 64) {
            float s = 0.f;
#pragma unroll
            for (int c = 0; c < 32; c++) s = fmaf(hnS[c * 33], WqO[c * 64 + t], s);
            red[t] = s;
        }
        __syncthreads();
        if (t < 32) {
            float s = 0.f;
#pragma unroll
            for (int j = 0; j < 64; j++) s = fmaf(WkO[t * 64 + j], red[j], s);
            wq2[nblk * 32 + t] = s;
        }
    }
}

// Output-stage edge kernel + fused out_post (hout). 3 blocks/CU.
__global__ __launch_bounds__(256, 3) void k_out_edge(
    const float* __restrict__ x, const float* __restrict__ h0f,
    const float* __restrict__ w1o, const float* __restrict__ b1o,
    const float* __restrict__ wq2, const float* __restrict__ roW,
    const float* __restrict__ U, const float* __restrict__ WoO,
    const float* __restrict__ WskipO, float* __restrict__ hout)
{
    __shared__ uint32_t rosP[4096];               // fp16 pairs of roW c-neighbors
    __shared__ __align__(16) float rhs[128 * 36];
    __shared__ __align__(16) float yss[128 * 20];
    __shared__ float xs[384];
    __shared__ float w1s[512];
    __shared__ float b1s[32];
    __shared__ float wq2s[32];
    __shared__ float alphas[128];
    __shared__ float red[256];
    __shared__ float agg64s[64];
    __shared__ float sh_inv;

    int n = blockIdx.x, t = threadIdx.x;
    int g = n >> 7, b = n & 127;
    int gbase = g << 7;

    for (int o = t; o < 384; o += 256) xs[o] = x[gbase * 3 + o];
    for (int o = t; o < 512; o += 256) w1s[o] = w1o[o];
    if (t < 32) { b1s[t] = b1o[t]; wq2s[t] = wq2[n * 32 + t]; }
    for (int o = t; o < 4096; o += 256) {
        int j = o & 63, lc = o >> 6, cp = lc & 15, l = lc >> 4;
        rosP[o] = f2h2(roW[(l * 32 + 2 * cp) * 64 + j], roW[(l * 32 + 2 * cp + 1) * 64 + j]);
    }
    __syncthreads();

    // phase A split across 256 threads
    {
        int a = t & 127, dh = t >> 7;
        float rx = xs[b * 3 + 0] - xs[a * 3 + 0];
        float ry = xs[b * 3 + 1] - xs[a * 3 + 1];
        float rz = xs[b * 3 + 2] - xs[a * 3 + 2];
        float dd = sqrtf(rx * rx + ry * ry + rz * rz + 1e-12f);
        float inv = 1.f / dd;
        float ys[16];
        sph16(rx * inv, ry * inv, rz * inv, ys);
        if (dh == 0) {
#pragma unroll
            for (int m = 0; m < 16; m++) yss[a * 20 + m] = ys[m];
        }
        float rbf[16];
#pragma unroll
        for (int j = 0; j < 16; j++) {
            float dc = dd - (4.f / 15.f) * j;
            rbf[j] = __expf(-2.f * dc * dc);
        }
        float lpart = 0.f;
        int d0 = dh * 16;
        for (int d2 = 0; d2 < 16; d2++) {
            int d = d0 + d2;
            float s = b1s[d];
#pragma unroll
            for (int j = 0; j < 16; j++) s = fmaf(rbf[j], w1s[j * 32 + d], s);
            s = fmaxf(s, 0.f);
            rhs[a * 36 + d] = s;
            lpart = fmaf(s, wq2s[d], lpart);
        }
        red[t] = lpart;
    }
    __syncthreads();
    if (t < 128) alphas[t] = (red[t] + red[t + 128]) * 0.125f; // 1/sqrt(64)
    __syncthreads();

    if (t < 128) {
        float m = (t != b) ? alphas[t] : -1e30f;
#pragma unroll
        for (int off = 32; off > 0; off >>= 1) m = fmaxf(m, __shfl_xor(m, off));
        if ((t & 63) == 0) red[t >> 6] = m;
    }
    __syncthreads();
    {
        float mx = fmaxf(red[0], red[1]);
        if (t < 128) {
            float e = (t != b) ? __expf(alphas[t] - mx) : 0.f;
            alphas[t] = e;
            float s = e;
#pragma unroll
            for (int off = 32; off > 0; off >>= 1) s += __shfl_xor(s, off);
            if ((t & 63) == 0) red[2 + (t >> 6)] = s;
        }
    }
    __syncthreads();
    if (t == 0) sh_inv = 1.f / (red[2] + red[3]);
    __syncthreads();

    int grp = t >> 6, j = t & 63;
    float accO = 0.f;
    for (int chunk = 0; chunk < 4; chunk++) {
        int a0 = grp * 32 + chunk * 8;
        float RO[8][4];
#pragma unroll
        for (int aa = 0; aa < 8; aa++)
#pragma unroll
            for (int l = 0; l < 4; l++) RO[aa][l] = 0.f;

#pragma unroll 2
        for (int cq = 0; cq < 8; cq++) {
            float4 rh4[8];
#pragma unroll
            for (int aa = 0; aa < 8; aa++)
                rh4[aa] = *reinterpret_cast<const float4*>(&rhs[(a0 + aa) * 36 + cq * 4]);
#pragma unroll
            for (int l = 0; l < 4; l++) {
#pragma unroll
                for (int ch = 0; ch < 2; ch++) {
                    float2 w2 = h2f2(rosP[(l * 16 + cq * 2 + ch) * 64 + j]);
#pragma unroll
                    for (int aa = 0; aa < 8; aa++) {
                        RO[aa][l] = fmaf(f4get(rh4[aa], 2 * ch), w2.x, RO[aa][l]);
                        RO[aa][l] = fmaf(f4get(rh4[aa], 2 * ch + 1), w2.y, RO[aa][l]);
                    }
                }
            }
        }

        float4 A0, A1, A2, A3, B0, B1, B2, B3;
        {
            const float4* p4 = reinterpret_cast<const float4*>(U + (gbase + a0) * 1024 + j * 16);
            A0 = p4[0]; A1 = p4[1]; A2 = p4[2]; A3 = p4[3];
            const float4* q4 = reinterpret_cast<const float4*>(U + (gbase + a0 + 1) * 1024 + j * 16);
            B0 = q4[0]; B1 = q4[1]; B2 = q4[2]; B3 = q4[3];
        }
#define PROC_O(aa, u0, u1, u2, u3) { \
        int a_ = a0 + (aa); \
        float w_ = alphas[a_]; \
        if (w_ != 0.f) { \
            const float4* yp = reinterpret_cast<const float4*>(&yss[a_ * 20]); \
            float4 y0 = yp[0], y1 = yp[1], y2 = yp[2], y3 = yp[3]; \
            float cv0 = y0.x * (u0).x; \
            float cv1 = fmaf(y0.y, (u0).y, fmaf(y0.z, (u0).z, y0.w * (u0).w)); \
            float cv2 = fmaf(y1.x, (u1).x, fmaf(y1.y, (u1).y, fmaf(y1.z, (u1).z, fmaf(y1.w, (u1).w, y2.x * (u2).x)))); \
            float cv3 = fmaf(y2.y, (u2).y, fmaf(y2.z, (u2).z, fmaf(y2.w, (u2).w, \
                        fmaf(y3.x, (u3).x, fmaf(y3.y, (u3).y, fmaf(y3.z, (u3).z, y3.w * (u3).w)))))); \
            float s_ = fmaf(cv0, RO[aa][0], fmaf(cv1, RO[aa][1], fmaf(cv2, RO[aa][2], cv3 * RO[aa][3]))); \
            accO = fmaf(w_, s_, accO); \
        } }
#pragma unroll
        for (int ap = 0; ap < 4; ap++) {
            int aa = ap * 2;
            {
                float4 u0 = A0, u1 = A1, u2 = A2, u3 = A3;
                if (ap < 3) {
                    const float4* p4 = reinterpret_cast<const float4*>(U + (gbase + a0 + aa + 2) * 1024 + j * 16);
                    A0 = p4[0]; A1 = p4[1]; A2 = p4[2]; A3 = p4[3];
                }
                PROC_O(aa, u0, u1, u2, u3)
            }
            {
                float4 u0 = B0, u1 = B1, u2 = B2, u3 = B3;
                if (ap < 3) {
                    const float4* p4 = reinterpret_cast<const float4*>(U + (gbase + a0 + aa + 3) * 1024 + j * 16);
                    B0 = p4[0]; B1 = p4[1]; B2 = p4[2]; B3 = p4[3];
                }
                PROC_O(aa + 1, u0, u1, u2, u3)
            }
        }
#undef PROC_O
    }
    red[t] = accO;
    __syncthreads();
    if (t < 64) agg64s[t] = (red[t] + red[64 + t] + red[128 + t] + red[192 + t]) * sh_inv;
    __syncthreads();

    if (t < 64) {
        float s = 0.f;
#pragma unroll
        for (int c = 0; c < 64; c++) s = fmaf(agg64s[c], WoO[c * 64 + t], s);
        const float* hr = &h0f[n * 32];
#pragma unroll
        for (int c = 0; c < 32; c++) s = fmaf(hr[c], WskipO[c * 64 + t], s);
        hout[n * 64 + t] = s;
    }
}

__global__ __launch_bounds__(64) void k_final(
    const float* __restrict__ hout, const float* __restrict__ Whid,
    const float* __restrict__ bhid, const float* __restrict__ Wout,
    const float* __restrict__ bout, float* __restrict__ out)
{
    __shared__ float pooled[64], hid[64];
    int g = blockIdx.x, t = threadIdx.x;
    float s = 0.f;
    for (int p = 0; p < 128; p++) s += hout[(g * 128 + p) * 64 + t];
    pooled[t] = s * (1.f / 128.f);
    __syncthreads();
    float hv = bhid[t];
#pragma unroll
    for (int c = 0; c < 64; c++) hv = fmaf(pooled[c], Whid[c * 64 + t], hv);
    hid[t] = fmaxf(hv, 0.f);
    __syncthreads();
    if (t < 15) {
        float o = bout[t];
#pragma unroll
        for (int c = 0; c < 64; c++) o = fmaf(hid[c], Wout[c * 15 + t], o);
        out[g * 15 + t] = o;
    }
}

extern "C" void kernel_launch(void* const* d_in, const int* in_sizes, int n_in,
                              void* d_out, int out_size, void* d_ws, size_t ws_size,
                              hipStream_t stream) {
    const float* x      = (const float*)d_in[0];
    const float* w1     = (const float*)d_in[1];
    const float* b1     = (const float*)d_in[2];
    const float* rW     = (const float*)d_in[3];
    const float* sW     = (const float*)d_in[4];
    const float* Wv     = (const float*)d_in[5];
    const float* Wq     = (const float*)d_in[6];
    const float* Wk     = (const float*)d_in[7];
    const float* Wo     = (const float*)d_in[8];
    const float* Wskip  = (const float*)d_in[9];
    const float* gw     = (const float*)d_in[10];
    const float* gb     = (const float*)d_in[11];
    const float* w1o    = (const float*)d_in[12];
    const float* b1o    = (const float*)d_in[13];
    const float* roW    = (const float*)d_in[14];
    const float* WvO    = (const float*)d_in[15];
    const float* WqO    = (const float*)d_in[16];
    const float* WkO    = (const float*)d_in[17];
    const float* WoO    = (const float*)d_in[18];
    const float* WskipO = (const float*)d_in[19];
    const float* Whid   = (const float*)d_in[20];
    const float* bhid   = (const float*)d_in[21];
    const float* Wout   = (const float*)d_in[22];
    const float* bout   = (const float*)d_in[23];
    float* out = (float*)d_out;

    float* ws = (float*)d_ws;
    float* h0    = ws;
    float* h1    = h0 + NNODE * 512;
    float* vA    = h1 + NNODE * 512;
    float* wqkA  = vA + NNODE * 512;
    float* vB    = wqkA + NNODE * 32;
    float* wqkB  = vB + NNODE * 512;
    float* wq2   = wqkB + NNODE * 32;
    float* U     = wq2 + NNODE * 32;
    float* hout  = U + NNODE * 1024;
    float* s0A   = hout + NNODE * 64;
    float* s0B   = s0A + NNODE * 32;

    hipMemsetAsync(h0, 0, NNODE * 512 * sizeof(float), stream);
    hipMemsetAsync(vA, 0, (NNODE * 512 + NNODE * 32) * sizeof(float), stream);
    hipMemsetAsync(s0A, 0, NNODE * 32 * sizeof(float), stream);

    for (int i = 0; i < 4; i++) {
        const float* hc  = (i & 1) ? h1 : h0;
        float*       hn  = (i & 1) ? h0 : h1;
        const float* vin  = (i & 1) ? vB : vA;
        const float* qin  = (i & 1) ? wqkB : wqkA;
        float*       vout = (i & 1) ? vA : vB;
        float*       qout = (i & 1) ? wqkA : wqkB;
        const float* s0in = (i & 1) ? s0B : s0A;
        float*       s0out= (i & 1) ? s0A : s0B;
        int last = (i == 3);
        k_layer<<<NNODE, 256, 0, stream>>>(
            x, hc, s0in, vin, qin, w1, b1, rW, sW, Wskip, Wo, gw, gb,
            Wv + (last ? 0 : (i + 1) * 4096),
            Wq + (last ? 0 : (i + 1) * 1024),
            Wk + (last ? 0 : (i + 1) * 1024),
            WvO, WqO, WkO,
            hn, s0out, vout, qout, wq2, U, i, last);
    }
    // final h0 sidecar: i=3 wrote s0A
    k_out_edge<<<NNODE, 256, 0, stream>>>(x, s0A, w1o, b1o, wq2, roW, U, WoO, WskipO, hout);
    k_final<<<NGRAPH, 64, 0, stream>>>(hout, Whid, bhid, Wout, bout, out);
}

// Round 13
// 526.081 us; speedup vs baseline: 2.1131x; 1.0031x over previous
//
#include <hip/hip_runtime.h>
#include <hip/hip_bf16.h>
#include <hip/hip_fp16.h>

#define NNODE 2048
#define NGRAPH 16

typedef _Float16 h2v __attribute__((ext_vector_type(2)));

__device__ __forceinline__ int lmap(int m) { return m == 0 ? 0 : (m < 4 ? 1 : (m < 9 ? 2 : 3)); }

__device__ __forceinline__ float f4get(const float4& v, int j) {
    return j == 0 ? v.x : (j == 1 ? v.y : (j == 2 ? v.z : v.w));
}
__device__ __forceinline__ uint32_t u4get(const uint4& v, int j) {
    return j == 0 ? v.x : (j == 1 ? v.y : (j == 2 ? v.z : v.w));
}

// pack two floats as fp16 pair in a u32 (lo = a, hi = b)
__device__ __forceinline__ uint32_t f2h2(float a, float b) {
    __half2 h2 = __floats2half2_rn(a, b);
    return *reinterpret_cast<uint32_t*>(&h2);
}
__device__ __forceinline__ float2 h2f2(uint32_t u) {
    __half2 h2 = *reinterpret_cast<__half2*>(&u);
    return __half22float2(h2);
}

// 2-way f16 dot with fp32 accumulate (V_DOT2_F32_F16); safe fallback
__device__ __forceinline__ float fdot2u(uint32_t a, uint32_t b, float c) {
#if defined(__has_builtin)
#if __has_builtin(__builtin_amdgcn_fdot2)
    return __builtin_amdgcn_fdot2(__builtin_bit_cast(h2v, a), __builtin_bit_cast(h2v, b), c, false);
#else
    float2 af = h2f2(a), bf = h2f2(b);
    return fmaf(af.x, bf.x, fmaf(af.y, bf.y, c));
#endif
#else
    float2 af = h2f2(a), bf = h2f2(b);
    return fmaf(af.x, bf.x, fmaf(af.y, bf.y, c));
#endif
}

__device__ __forceinline__ void sph16(float x, float y, float z, float* Y) {
    Y[0] = 0.28209479177f;
    Y[1] = 0.4886025119f * y; Y[2] = 0.4886025119f * z; Y[3] = 0.4886025119f * x;
    Y[4] = 1.09254843059f * x * y;
    Y[5] = 1.09254843059f * y * z;
    Y[6] = 0.31539156525f * (3.f * z * z - 1.f);
    Y[7] = 1.09254843059f * x * z;
    Y[8] = 0.54627421529f * (x * x - y * y);
    Y[9]  = 0.59004358992f * y * (3.f * x * x - y * y);
    Y[10] = 2.89061144264f * x * y * z;
    Y[11] = 0.45704579946f * y * (5.f * z * z - 1.f);
    Y[12] = 0.37317633259f * z * (5.f * z * z - 3.f);
    Y[13] = 0.45704579946f * x * (5.f * z * z - 1.f);
    Y[14] = 1.44530572132f * z * (x * x - y * y);
    Y[15] = 0.59004358992f * x * (x * x - 3.f * y * y);
}

#define PROC_SRC(aa, u0, u1, u2, u3, h0v) { \
    int a_ = a0 + (aa); \
    float w_ = alphas[a_]; \
    if (w_ != 0.f) { \
        const float4* yp = reinterpret_cast<const float4*>(&yss[a_ * 20]); \
        float4 y0 = yp[0], y1 = yp[1], y2 = yp[2], y3 = yp[3]; \
        float hb1 = (h0v) + 1.f; \
        float sc0 = S[aa][0] * hb1, sc1 = S[aa][1] * hb1; \
        float sc2 = S[aa][2] * hb1, sc3 = S[aa][3] * hb1; \
        acc[0]  = fmaf(w_, fmaf((u0).x, R[aa][0], sc0 * y0.x), acc[0]); \
        acc[1]  = fmaf(w_, fmaf((u0).y, R[aa][1], sc1 * y0.y), acc[1]); \
        acc[2]  = fmaf(w_, fmaf((u0).z, R[aa][1], sc1 * y0.z), acc[2]); \
        acc[3]  = fmaf(w_, fmaf((u0).w, R[aa][1], sc1 * y0.w), acc[3]); \
        acc[4]  = fmaf(w_, fmaf((u1).x, R[aa][2], sc2 * y1.x), acc[4]); \
        acc[5]  = fmaf(w_, fmaf((u1).y, R[aa][2], sc2 * y1.y), acc[5]); \
        acc[6]  = fmaf(w_, fmaf((u1).z, R[aa][2], sc2 * y1.z), acc[6]); \
        acc[7]  = fmaf(w_, fmaf((u1).w, R[aa][2], sc2 * y1.w), acc[7]); \
        acc[8]  = fmaf(w_, fmaf((u2).x, R[aa][2], sc2 * y2.x), acc[8]); \
        acc[9]  = fmaf(w_, fmaf((u2).y, R[aa][3], sc3 * y2.y), acc[9]); \
        acc[10] = fmaf(w_, fmaf((u2).z, R[aa][3], sc3 * y2.z), acc[10]); \
        acc[11] = fmaf(w_, fmaf((u2).w, R[aa][3], sc3 * y2.w), acc[11]); \
        acc[12] = fmaf(w_, fmaf((u3).x, R[aa][3], sc3 * y3.x), acc[12]); \
        acc[13] = fmaf(w_, fmaf((u3).y, R[aa][3], sc3 * y3.y), acc[13]); \
        acc[14] = fmaf(w_, fmaf((u3).z, R[aa][3], sc3 * y3.z), acc[14]); \
        acc[15] = fmaf(w_, fmaf((u3).w, R[aa][3], sc3 * y3.w), acc[15]); \
    } }

// One fused layer. 3 blocks/CU (LDS ~51KB).
__global__ __launch_bounds__(256, 3) void k_layer(
    const float* __restrict__ x, const float* __restrict__ h,
    const float* __restrict__ h0in, const float* __restrict__ vpre,
    const float* __restrict__ wqk,
    const float* __restrict__ w1, const float* __restrict__ b1,
    const float* __restrict__ rW, const float* __restrict__ sW,
    const float* __restrict__ Wskip, const float* __restrict__ Wo,
    const float* __restrict__ gw, const float* __restrict__ gb,
    const float* __restrict__ Wv_n, const float* __restrict__ Wq_n, const float* __restrict__ Wk_n,
    const float* __restrict__ WvO, const float* __restrict__ WqO, const float* __restrict__ WkO,
    float* __restrict__ hnew, float* __restrict__ h0out,
    float* __restrict__ vpre_n, float* __restrict__ wqk_n,
    float* __restrict__ wq2, float* __restrict__ U,
    int layer, int last)
{
    // rwswP: [wR2 2048 u32][wS2 2048 u32] fp16 j-pairs; later float-bits Wo / Wv_n / WvO-hi
    __shared__ uint32_t rwswP[4096];
    // rhs: first 2048 u32 = rh fp16 j-pairs (stride 16 u32/row); later P[8][528] f32; later Wskip / WvO-lo
    __shared__ __align__(16) float rhs[128 * 36];
    __shared__ __align__(16) float yss[128 * 20]; // Ys (stride 20, 16B-aligned); later hs[512]
    __shared__ __align__(16) float ub[1056];      // phase A: xs[384]|w1s[512]; post: hnS[528]|aggL[528]
    __shared__ float b1s[32];
    __shared__ float wqks[32];
    __shared__ float alphas[128];
    __shared__ float red[256];
    __shared__ float scale[128];
    __shared__ float sh_inv;

    int nblk = blockIdx.x, t = threadIdx.x;
    int g = nblk >> 7, b = nblk & 127;
    int gbase = g << 7;

    float* xs = ub;           // [384]
    float* w1s = ub + 384;    // [512]
    uint32_t* rh16 = reinterpret_cast<uint32_t*>(rhs);  // [128][16] fp16 j-pairs

    for (int o = t; o < 384; o += 256) xs[o] = x[gbase * 3 + o];
    for (int o = t; o < 512; o += 256) w1s[o] = w1[layer * 512 + o];
    if (t < 32) { b1s[t] = b1[layer * 32 + t]; wqks[t] = wqk[nblk * 32 + t]; }
    // stage rW/sW as fp16 j-pairs: wR2[(l*16+j2)*32+d] = (rW[l][2j2][d], rW[l][2j2+1][d])
    for (int idx = t; idx < 2048; idx += 256) {
        int d2 = idx & 31, j2 = (idx >> 5) & 15, l = idx >> 9;
        int src = layer * 4096 + l * 1024 + (2 * j2) * 32 + d2;
        rwswP[idx]        = f2h2(rW[src], rW[src + 32]);
        rwswP[2048 + idx] = f2h2(sW[src], sW[src + 32]);
    }
    __syncthreads();

    // ---- phase A: geometry, rh (fp32 for logit, fp16 j-pairs for GEMM), partial logit ----
    {
        int a = t & 127, dh = t >> 7;
        float rx = xs[b * 3 + 0] - xs[a * 3 + 0];
        float ry = xs[b * 3 + 1] - xs[a * 3 + 1];
        float rz = xs[b * 3 + 2] - xs[a * 3 + 2];
        float dd = sqrtf(rx * rx + ry * ry + rz * rz + 1e-12f);
        float inv = 1.f / dd;
        float ys[16];
        sph16(rx * inv, ry * inv, rz * inv, ys);
        if (dh == 0) {
#pragma unroll
            for (int m = 0; m < 16; m++) yss[a * 20 + m] = ys[m];
        }
        float rbf[16];
#pragma unroll
        for (int j = 0; j < 16; j++) {
            float dc = dd - (4.f / 15.f) * j;
            rbf[j] = __expf(-2.f * dc * dc);
        }
        float lpart = 0.f;
        int d0 = dh * 16;
        float sprev = 0.f;
        for (int d2 = 0; d2 < 16; d2++) {
            int d = d0 + d2;
            float s = b1s[d];
#pragma unroll
            for (int j = 0; j < 16; j++) s = fmaf(rbf[j], w1s[j * 32 + d], s);
            s = fmaxf(s, 0.f);
            lpart = fmaf(s, wqks[d], lpart);
            if (d2 & 1) rh16[a * 16 + dh * 8 + (d2 >> 1)] = f2h2(sprev, s);
            sprev = s;
        }
        red[t] = lpart;
    }
    __syncthreads();
    if (t < 128) alphas[t] = (red[t] + red[t + 128]) * 0.17677669529663687f; // 1/sqrt(32)
    __syncthreads();

    // ---- segment softmax over 127 valid edges (wave shuffle reductions) ----
    if (t < 128) {
        float m = (t != b) ? alphas[t] : -1e30f;
#pragma unroll
        for (int off = 32; off > 0; off >>= 1) m = fmaxf(m, __shfl_xor(m, off));
        if ((t & 63) == 0) red[t >> 6] = m;
    }
    __syncthreads();
    {
        float mx = fmaxf(red[0], red[1]);
        if (t < 128) {
            float e = (t != b) ? __expf(alphas[t] - mx) : 0.f;
            alphas[t] = e;
            float s = e;
#pragma unroll
            for (int off = 32; off > 0; off >>= 1) s += __shfl_xor(s, off);
            if ((t & 63) == 0) red[2 + (t >> 6)] = s;
        }
    }
    __syncthreads();
    if (t == 0) sh_inv = 1.f / (red[2] + red[3]);

    // ---- pass 2: dot2-based R/S GEMM + weighted aggregate ----
    int grp = t >> 5, d = t & 31;
    float acc[16];
#pragma unroll
    for (int m = 0; m < 16; m++) acc[m] = 0.f;

    for (int chunk = 0; chunk < 2; chunk++) {
        int a0 = grp * 16 + chunk * 8;
        float R[8][4], S[8][4];
#pragma unroll
        for (int aa = 0; aa < 8; aa++)
#pragma unroll
            for (int l = 0; l < 4; l++) { R[aa][l] = 0.f; S[aa][l] = 0.f; }

#pragma unroll 2
        for (int j8 = 0; j8 < 4; j8++) {           // 4 j-pair quads (8 j's each)
            uint4 rq[8];
#pragma unroll
            for (int aa = 0; aa < 8; aa++)
                rq[aa] = *reinterpret_cast<const uint4*>(&rh16[(a0 + aa) * 16 + j8 * 4]);
#pragma unroll
            for (int l = 0; l < 4; l++) {
#pragma unroll
                for (int jp = 0; jp < 4; jp++) {
                    uint32_t wr = rwswP[(l * 16 + j8 * 4 + jp) * 32 + d];
                    uint32_t ws = rwswP[2048 + (l * 16 + j8 * 4 + jp) * 32 + d];
#pragma unroll
                    for (int aa = 0; aa < 8; aa++) {
                        uint32_t rv = u4get(rq[aa], jp);
                        R[aa][l] = fdot2u(rv, wr, R[aa][l]);
                        S[aa][l] = fdot2u(rv, ws, S[aa][l]);
                    }
                }
            }
        }

        // epilogue: 2-deep double-buffered global loads (vpre rows + dense h0 sidecar)
        float4 A0, A1, A2, A3, B0, B1, B2, B3; float Ah, Bh;
        {
            const float4* p4 = reinterpret_cast<const float4*>(vpre + (gbase + a0) * 512 + d * 16);
            A0 = p4[0]; A1 = p4[1]; A2 = p4[2]; A3 = p4[3];
            Ah = h0in[(gbase + a0) * 32 + d];
            const float4* q4 = reinterpret_cast<const float4*>(vpre + (gbase + a0 + 1) * 512 + d * 16);
            B0 = q4[0]; B1 = q4[1]; B2 = q4[2]; B3 = q4[3];
            Bh = h0in[(gbase + a0 + 1) * 32 + d];
        }
#pragma unroll
        for (int ap = 0; ap < 4; ap++) {
            int aa = ap * 2;
            {
                float4 u0 = A0, u1 = A1, u2 = A2, u3 = A3; float h0v = Ah;
                if (ap < 3) {
                    const float4* p4 = reinterpret_cast<const float4*>(vpre + (gbase + a0 + aa + 2) * 512 + d * 16);
                    A0 = p4[0]; A1 = p4[1]; A2 = p4[2]; A3 = p4[3];
                    Ah = h0in[(gbase + a0 + aa + 2) * 32 + d];
                }
                PROC_SRC(aa, u0, u1, u2, u3, h0v)
            }
            {
                float4 u0 = B0, u1 = B1, u2 = B2, u3 = B3; float h0v = Bh;
                if (ap < 3) {
                    const float4* p4 = reinterpret_cast<const float4*>(vpre + (gbase + a0 + aa + 3) * 512 + d * 16);
                    B0 = p4[0]; B1 = p4[1]; B2 = p4[2]; B3 = p4[3];
                    Bh = h0in[(gbase + a0 + aa + 3) * 32 + d];
                }
                PROC_SRC(aa + 1, u0, u1, u2, u3, h0v)
            }
        }
    }
    __syncthreads();   // all pass-2 LDS reads (rh16/rwswP/yss) done

    // S1: partials into P (overlay rhs); stage h[n] (overlay yss); stage Wo (float bits in rwswP)
    float* P = rhs;
#pragma unroll
    for (int m = 0; m < 16; m++) P[grp * 528 + m * 33 + d] = acc[m];
    float* hs = yss;
    for (int o = t; o < 512; o += 256) hs[o] = h[nblk * 512 + o];
    for (int o = t; o < 4096; o += 256) rwswP[o] = __float_as_uint(Wo[layer * 4096 + o]);
    __syncthreads();

    // S2: reduce partials -> aggL[m*33+c]
    float* hnS = ub;          // [528]
    float* aggL = ub + 528;   // [528]
    float invs = sh_inv;
    for (int o = t; o < 512; o += 256) {
        int m = o >> 5, c = o & 31;
        float s = 0.f;
#pragma unroll
        for (int gg = 0; gg < 8; gg++) s += P[gg * 528 + m * 33 + c];
        aggL[m * 33 + c] = s * invs;
    }
    __syncthreads();

    // S3: stage Wskip into rhs (fp32), P dead
    for (int o = t; o < 4096; o += 256) rhs[o] = Wskip[layer * 4096 + o];
    __syncthreads();

    // S4: post GEMM: hn = h@Wskip + agg@Wo
    for (int o = t; o < 512; o += 256) {
        int m = o >> 5, dd = o & 31, l = lmap(m);
        float s = 0.f;
        const float* wa = &rhs[l * 1024 + dd];
        const uint32_t* wb = &rwswP[l * 1024 + dd];
        const float* hrow = &hs[m];
        const float* arow = &aggL[m * 33];
#pragma unroll
        for (int c = 0; c < 32; c++) {
            s = fmaf(hrow[c * 16], wa[c * 32], s);
            s = fmaf(arow[c], __uint_as_float(wb[c * 32]), s);
        }
        hnS[m * 33 + dd] = s;
    }
    __syncthreads();

    // S5: norm gate compute + stage next-stage value weights
    if (t < 128) {
        int dd = t >> 2, l = t & 3;
        int m0 = l * l, cnt = 2 * l + 1;
        float s = 1e-12f;
        for (int m = m0; m < m0 + cnt; m++) { float v = hnS[m * 33 + dd]; s = fmaf(v, v, s); }
        float nr = sqrtf(s);
        float phi = fmaxf(nr * gw[(layer * 4 + l) * 32 + dd] + gb[(layer * 4 + l) * 32 + dd], 0.f);
        scale[dd * 4 + l] = phi / (nr + 1e-6f);
    }
    if (!last) {
        for (int o = t; o < 4096; o += 256) rwswP[o] = __float_as_uint(Wv_n[o]);
    } else {
        for (int o = t; o < 4096; o += 256) {
            rhs[o] = WvO[o];                                   // l = 0,1
            rwswP[o] = __float_as_uint(WvO[4096 + o]);         // l = 2,3
        }
    }
    __syncthreads();

    // S6: apply gate, write hnew
    for (int o = t; o < 512; o += 256) {
        int dd = o >> 4, m = o & 15;
        float v = hnS[m * 33 + dd] * scale[dd * 4 + lmap(m)];
        hnew[nblk * 512 + o] = v;
        hnS[m * 33 + dd] = v;
    }
    __syncthreads();

    // dense h0 sidecar: one coalesced wave-store of the gated m=0 column
    if (t < 32) h0out[nblk * 32 + t] = hnS[t];

    if (!last) {
        for (int o = t; o < 512; o += 256) {
            int dd = o >> 4, m = o & 15, l = lmap(m);
            float s = 0.f;
            const uint32_t* wv = &rwswP[l * 1024 + dd];
            const float* hrow = &hnS[m * 33];
#pragma unroll
            for (int c = 0; c < 32; c++) s = fmaf(hrow[c], __uint_as_float(wv[c * 32]), s);
            vpre_n[nblk * 512 + o] = s;
        }
        if (t < 32) {
            float s = 0.f;
#pragma unroll
            for (int c = 0; c < 32; c++) s = fmaf(hnS[c * 33], Wq_n[c * 32 + t], s);
            red[t] = s;
        }
        __syncthreads();
        if (t < 32) {
            float s = 0.f;
#pragma unroll
            for (int j = 0; j < 32; j++) s = fmaf(Wk_n[t * 32 + j], red[j], s);
            wqk_n[nblk * 32 + t] = s;
        }
    } else {
        for (int o = t; o < 1024; o += 256) {
            int j = o >> 4, m = o & 15, l = lmap(m);
            float s = 0.f;
            const float* hrow = &hnS[m * 33];
            if (l < 2) {
                const float* wv = &rhs[l * 2048 + j];
#pragma unroll
                for (int c = 0; c < 32; c++) s = fmaf(hrow[c], wv[c * 64], s);
            } else {
                const uint32_t* wv = &rwswP[(l - 2) * 2048 + j];
#pragma unroll
                for (int c = 0; c < 32; c++) s = fmaf(hrow[c], __uint_as_float(wv[c * 64]), s);
            }
            U[nblk * 1024 + o] = s;
        }
        if (t < 64) {
            float s = 0.f;
#pragma unroll
            for (int c = 0; c < 32; c++) s = fmaf(hnS[c * 33], WqO[c * 64 + t], s);
            red[t] = s;
        }
        __syncthreads();
        if (t < 32) {
            float s = 0.f;
#pragma unroll
            for (int j = 0; j < 64; j++) s = fmaf(WkO[t * 64 + j], red[j], s);
            wq2[nblk * 32 + t] = s;
        }
    }
}

// Output-stage edge kernel + fused out_post (hout). 3 blocks/CU.
__global__ __launch_bounds__(256, 3) void k_out_edge(
    const float* __restrict__ x, const float* __restrict__ h0f,
    const float* __restrict__ w1o, const float* __restrict__ b1o,
    const float* __restrict__ wq2, const float* __restrict__ roW,
    const float* __restrict__ U, const float* __restrict__ WoO,
    const float* __restrict__ WskipO, float* __restrict__ hout)
{
    __shared__ uint32_t rosP[4096];               // fp16 pairs of roW c-neighbors
    __shared__ __align__(16) float rhs[128 * 36];
    __shared__ __align__(16) float yss[128 * 20];
    __shared__ float xs[384];
    __shared__ float w1s[512];
    __shared__ float b1s[32];
    __shared__ float wq2s[32];
    __shared__ float alphas[128];
    __shared__ float red[256];
    __shared__ float agg64s[64];
    __shared__ float sh_inv;

    int n = blockIdx.x, t = threadIdx.x;
    int g = n >> 7, b = n & 127;
    int gbase = g << 7;

    for (int o = t; o < 384; o += 256) xs[o] = x[gbase * 3 + o];
    for (int o = t; o < 512; o += 256) w1s[o] = w1o[o];
    if (t < 32) { b1s[t] = b1o[t]; wq2s[t] = wq2[n * 32 + t]; }
    for (int o = t; o < 4096; o += 256) {
        int j = o & 63, lc = o >> 6, cp = lc & 15, l = lc >> 4;
        rosP[o] = f2h2(roW[(l * 32 + 2 * cp) * 64 + j], roW[(l * 32 + 2 * cp + 1) * 64 + j]);
    }
    __syncthreads();

    // phase A split across 256 threads
    {
        int a = t & 127, dh = t >> 7;
        float rx = xs[b * 3 + 0] - xs[a * 3 + 0];
        float ry = xs[b * 3 + 1] - xs[a * 3 + 1];
        float rz = xs[b * 3 + 2] - xs[a * 3 + 2];
        float dd = sqrtf(rx * rx + ry * ry + rz * rz + 1e-12f);
        float inv = 1.f / dd;
        float ys[16];
        sph16(rx * inv, ry * inv, rz * inv, ys);
        if (dh == 0) {
#pragma unroll
            for (int m = 0; m < 16; m++) yss[a * 20 + m] = ys[m];
        }
        float rbf[16];
#pragma unroll
        for (int j = 0; j < 16; j++) {
            float dc = dd - (4.f / 15.f) * j;
            rbf[j] = __expf(-2.f * dc * dc);
        }
        float lpart = 0.f;
        int d0 = dh * 16;
        for (int d2 = 0; d2 < 16; d2++) {
            int d = d0 + d2;
            float s = b1s[d];
#pragma unroll
            for (int j = 0; j < 16; j++) s = fmaf(rbf[j], w1s[j * 32 + d], s);
            s = fmaxf(s, 0.f);
            rhs[a * 36 + d] = s;
            lpart = fmaf(s, wq2s[d], lpart);
        }
        red[t] = lpart;
    }
    __syncthreads();
    if (t < 128) alphas[t] = (red[t] + red[t + 128]) * 0.125f; // 1/sqrt(64)
    __syncthreads();

    if (t < 128) {
        float m = (t != b) ? alphas[t] : -1e30f;
#pragma unroll
        for (int off = 32; off > 0; off >>= 1) m = fmaxf(m, __shfl_xor(m, off));
        if ((t & 63) == 0) red[t >> 6] = m;
    }
    __syncthreads();
    {
        float mx = fmaxf(red[0], red[1]);
        if (t < 128) {
            float e = (t != b) ? __expf(alphas[t] - mx) : 0.f;
            alphas[t] = e;
            float s = e;
#pragma unroll
            for (int off = 32; off > 0; off >>= 1) s += __shfl_xor(s, off);
            if ((t & 63) == 0) red[2 + (t >> 6)] = s;
        }
    }
    __syncthreads();
    if (t == 0) sh_inv = 1.f / (red[2] + red[3]);
    __syncthreads();

    int grp = t >> 6, j = t & 63;
    float accO = 0.f;
    for (int chunk = 0; chunk < 4; chunk++) {
        int a0 = grp * 32 + chunk * 8;
        float RO[8][4];
#pragma unroll
        for (int aa = 0; aa < 8; aa++)
#pragma unroll
            for (int l = 0; l < 4; l++) RO[aa][l] = 0.f;

#pragma unroll 2
        for (int cq = 0; cq < 8; cq++) {
            float4 rh4[8];
#pragma unroll
            for (int aa = 0; aa < 8; aa++)
                rh4[aa] = *reinterpret_cast<const float4*>(&rhs[(a0 + aa) * 36 + cq * 4]);
#pragma unroll
            for (int l = 0; l < 4; l++) {
#pragma unroll
                for (int ch = 0; ch < 2; ch++) {
                    float2 w2 = h2f2(rosP[(l * 16 + cq * 2 + ch) * 64 + j]);
#pragma unroll
                    for (int aa = 0; aa < 8; aa++) {
                        RO[aa][l] = fmaf(f4get(rh4[aa], 2 * ch), w2.x, RO[aa][l]);
                        RO[aa][l] = fmaf(f4get(rh4[aa], 2 * ch + 1), w2.y, RO[aa][l]);
                    }
                }
            }
        }

        float4 A0, A1, A2, A3, B0, B1, B2, B3;
        {
            const float4* p4 = reinterpret_cast<const float4*>(U + (gbase + a0) * 1024 + j * 16);
            A0 = p4[0]; A1 = p4[1]; A2 = p4[2]; A3 = p4[3];
            const float4* q4 = reinterpret_cast<const float4*>(U + (gbase + a0 + 1) * 1024 + j * 16);
            B0 = q4[0]; B1 = q4[1]; B2 = q4[2]; B3 = q4[3];
        }
#define PROC_O(aa, u0, u1, u2, u3) { \
        int a_ = a0 + (aa); \
        float w_ = alphas[a_]; \
        if (w_ != 0.f) { \
            const float4* yp = reinterpret_cast<const float4*>(&yss[a_ * 20]); \
            float4 y0 = yp[0], y1 = yp[1], y2 = yp[2], y3 = yp[3]; \
            float cv0 = y0.x * (u0).x; \
            float cv1 = fmaf(y0.y, (u0).y, fmaf(y0.z, (u0).z, y0.w * (u0).w)); \
            float cv2 = fmaf(y1.x, (u1).x, fmaf(y1.y, (u1).y, fmaf(y1.z, (u1).z, fmaf(y1.w, (u1).w, y2.x * (u2).x)))); \
            float cv3 = fmaf(y2.y, (u2).y, fmaf(y2.z, (u2).z, fmaf(y2.w, (u2).w, \
                        fmaf(y3.x, (u3).x, fmaf(y3.y, (u3).y, fmaf(y3.z, (u3).z, y3.w * (u3).w)))))); \
            float s_ = fmaf(cv0, RO[aa][0], fmaf(cv1, RO[aa][1], fmaf(cv2, RO[aa][2], cv3 * RO[aa][3]))); \
            accO = fmaf(w_, s_, accO); \
        } }
#pragma unroll
        for (int ap = 0; ap < 4; ap++) {
            int aa = ap * 2;
            {
                float4 u0 = A0, u1 = A1, u2 = A2, u3 = A3;
                if (ap < 3) {
                    const float4* p4 = reinterpret_cast<const float4*>(U + (gbase + a0 + aa + 2) * 1024 + j * 16);
                    A0 = p4[0]; A1 = p4[1]; A2 = p4[2]; A3 = p4[3];
                }
                PROC_O(aa, u0, u1, u2, u3)
            }
            {
                float4 u0 = B0, u1 = B1, u2 = B2, u3 = B3;
                if (ap < 3) {
                    const float4* p4 = reinterpret_cast<const float4*>(U + (gbase + a0 + aa + 3) * 1024 + j * 16);
                    B0 = p4[0]; B1 = p4[1]; B2 = p4[2]; B3 = p4[3];
                }
                PROC_O(aa + 1, u0, u1, u2, u3)
            }
        }
#undef PROC_O
    }
    red[t] = accO;
    __syncthreads();
    if (t < 64) agg64s[t] = (red[t] + red[64 + t] + red[128 + t] + red[192 + t]) * sh_inv;
    __syncthreads();

    if (t < 64) {
        float s = 0.f;
#pragma unroll
        for (int c = 0; c < 64; c++) s = fmaf(agg64s[c], WoO[c * 64 + t], s);
        const float* hr = &h0f[n * 32];
#pragma unroll
        for (int c = 0; c < 32; c++) s = fmaf(hr[c], WskipO[c * 64 + t], s);
        hout[n * 64 + t] = s;
    }
}

__global__ __launch_bounds__(64) void k_final(
    const float* __restrict__ hout, const float* __restrict__ Whid,
    const float* __restrict__ bhid, const float* __restrict__ Wout,
    const float* __restrict__ bout, float* __restrict__ out)
{
    __shared__ float pooled[64], hid[64];
    int g = blockIdx.x, t = threadIdx.x;
    float s = 0.f;
    for (int p = 0; p < 128; p++) s += hout[(g * 128 + p) * 64 + t];
    pooled[t] = s * (1.f / 128.f);
    __syncthreads();
    float hv = bhid[t];
#pragma unroll
    for (int c = 0; c < 64; c++) hv = fmaf(pooled[c], Whid[c * 64 + t], hv);
    hid[t] = fmaxf(hv, 0.f);
    __syncthreads();
    if (t < 15) {
        float o = bout[t];
#pragma unroll
        for (int c = 0; c < 64; c++) o = fmaf(hid[c], Wout[c * 15 + t], o);
        out[g * 15 + t] = o;
    }
}

extern "C" void kernel_launch(void* const* d_in, const int* in_sizes, int n_in,
                              void* d_out, int out_size, void* d_ws, size_t ws_size,
                              hipStream_t stream) {
    const float* x      = (const float*)d_in[0];
    const float* w1     = (const float*)d_in[1];
    const float* b1     = (const float*)d_in[2];
    const float* rW     = (const float*)d_in[3];
    const float* sW     = (const float*)d_in[4];
    const float* Wv     = (const float*)d_in[5];
    const float* Wq     = (const float*)d_in[6];
    const float* Wk     = (const float*)d_in[7];
    const float* Wo     = (const float*)d_in[8];
    const float* Wskip  = (const float*)d_in[9];
    const float* gw     = (const float*)d_in[10];
    const float* gb     = (const float*)d_in[11];
    const float* w1o    = (const float*)d_in[12];
    const float* b1o    = (const float*)d_in[13];
    const float* roW    = (const float*)d_in[14];
    const float* WvO    = (const float*)d_in[15];
    const float* WqO    = (const float*)d_in[16];
    const float* WkO    = (const float*)d_in[17];
    const float* WoO    = (const float*)d_in[18];
    const float* WskipO = (const float*)d_in[19];
    const float* Whid   = (const float*)d_in[20];
    const float* bhid   = (const float*)d_in[21];
    const float* Wout   = (const float*)d_in[22];
    const float* bout   = (const float*)d_in[23];
    float* out = (float*)d_out;

    float* ws = (float*)d_ws;
    float* h0    = ws;
    float* h1    = h0 + NNODE * 512;
    float* vA    = h1 + NNODE * 512;
    float* wqkA  = vA + NNODE * 512;
    float* vB    = wqkA + NNODE * 32;
    float* wqkB  = vB + NNODE * 512;
    float* wq2   = wqkB + NNODE * 32;
    float* U     = wq2 + NNODE * 32;
    float* hout  = U + NNODE * 1024;
    float* s0A   = hout + NNODE * 64;
    float* s0B   = s0A + NNODE * 32;

    hipMemsetAsync(h0, 0, NNODE * 512 * sizeof(float), stream);
    hipMemsetAsync(vA, 0, (NNODE * 512 + NNODE * 32) * sizeof(float), stream);
    hipMemsetAsync(s0A, 0, NNODE * 32 * sizeof(float), stream);

    for (int i = 0; i < 4; i++) {
        const float* hc  = (i & 1) ? h1 : h0;
        float*       hn  = (i & 1) ? h0 : h1;
        const float* vin  = (i & 1) ? vB : vA;
        const float* qin  = (i & 1) ? wqkB : wqkA;
        float*       vout = (i & 1) ? vA : vB;
        float*       qout = (i & 1) ? wqkA : wqkB;
        const float* s0in = (i & 1) ? s0B : s0A;
        float*       s0out= (i & 1) ? s0A : s0B;
        int last = (i == 3);
        k_layer<<<NNODE, 256, 0, stream>>>(
            x, hc, s0in, vin, qin, w1, b1, rW, sW, Wskip, Wo, gw, gb,
            Wv + (last ? 0 : (i + 1) * 4096),
            Wq + (last ? 0 : (i + 1) * 1024),
            Wk + (last ? 0 : (i + 1) * 1024),
            WvO, WqO, WkO,
            hn, s0out, vout, qout, wq2, U, i, last);
    }
    // final h0 sidecar: i=3 wrote s0A
    k_out_edge<<<NNODE, 256, 0, stream>>>(x, s0A, w1o, b1o, wq2, roW, U, WoO, WskipO, hout);
    k_final<<<NGRAPH, 64, 0, stream>>>(hout, Whid, bhid, Wout, bout, out);
}

// Round 14
// 511.563 us; speedup vs baseline: 2.1730x; 1.0284x over previous
//
#include <hip/hip_runtime.h>
#include <hip/hip_bf16.h>
#include <hip/hip_fp16.h>

#define NNODE 2048
#define NGRAPH 16

typedef _Float16 h2v __attribute__((ext_vector_type(2)));

__device__ __forceinline__ int lmap(int m) { return m == 0 ? 0 : (m < 4 ? 1 : (m < 9 ? 2 : 3)); }

__device__ __forceinline__ float f4get(const float4& v, int j) {
    return j == 0 ? v.x : (j == 1 ? v.y : (j == 2 ? v.z : v.w));
}
__device__ __forceinline__ uint32_t u4get(const uint4& v, int j) {
    return j == 0 ? v.x : (j == 1 ? v.y : (j == 2 ? v.z : v.w));
}

// pack two floats as fp16 pair in a u32 (lo = a, hi = b)
__device__ __forceinline__ uint32_t f2h2(float a, float b) {
    __half2 h2 = __floats2half2_rn(a, b);
    return *reinterpret_cast<uint32_t*>(&h2);
}
__device__ __forceinline__ float2 h2f2(uint32_t u) {
    __half2 h2 = *reinterpret_cast<__half2*>(&u);
    return __half22float2(h2);
}

// 2-way f16 dot with fp32 accumulate (V_DOT2_F32_F16); safe fallback
__device__ __forceinline__ float fdot2u(uint32_t a, uint32_t b, float c) {
#if defined(__has_builtin)
#if __has_builtin(__builtin_amdgcn_fdot2)
    return __builtin_amdgcn_fdot2(__builtin_bit_cast(h2v, a), __builtin_bit_cast(h2v, b), c, false);
#else
    float2 af = h2f2(a), bf = h2f2(b);
    return fmaf(af.x, bf.x, fmaf(af.y, bf.y, c));
#endif
#else
    float2 af = h2f2(a), bf = h2f2(b);
    return fmaf(af.x, bf.x, fmaf(af.y, bf.y, c));
#endif
}

__device__ __forceinline__ void sph16(float x, float y, float z, float* Y) {
    Y[0] = 0.28209479177f;
    Y[1] = 0.4886025119f * y; Y[2] = 0.4886025119f * z; Y[3] = 0.4886025119f * x;
    Y[4] = 1.09254843059f * x * y;
    Y[5] = 1.09254843059f * y * z;
    Y[6] = 0.31539156525f * (3.f * z * z - 1.f);
    Y[7] = 1.09254843059f * x * z;
    Y[8] = 0.54627421529f * (x * x - y * y);
    Y[9]  = 0.59004358992f * y * (3.f * x * x - y * y);
    Y[10] = 2.89061144264f * x * y * z;
    Y[11] = 0.45704579946f * y * (5.f * z * z - 1.f);
    Y[12] = 0.37317633259f * z * (5.f * z * z - 3.f);
    Y[13] = 0.45704579946f * x * (5.f * z * z - 1.f);
    Y[14] = 1.44530572132f * z * (x * x - y * y);
    Y[15] = 0.59004358992f * x * (x * x - 3.f * y * y);
}

#define PROC_SRC(aa, u0, u1, u2, u3, h0v) { \
    int a_ = a0 + (aa); \
    float w_ = alphas[a_]; \
    if (w_ != 0.f) { \
        const float4* yp = reinterpret_cast<const float4*>(&yss[a_ * 20]); \
        float4 y0 = yp[0], y1 = yp[1], y2 = yp[2], y3 = yp[3]; \
        float hb1 = (h0v) + 1.f; \
        float sc0 = S[aa][0] * hb1, sc1 = S[aa][1] * hb1; \
        float sc2 = S[aa][2] * hb1, sc3 = S[aa][3] * hb1; \
        acc[0]  = fmaf(w_, fmaf((u0).x, R[aa][0], sc0 * y0.x), acc[0]); \
        acc[1]  = fmaf(w_, fmaf((u0).y, R[aa][1], sc1 * y0.y), acc[1]); \
        acc[2]  = fmaf(w_, fmaf((u0).z, R[aa][1], sc1 * y0.z), acc[2]); \
        acc[3]  = fmaf(w_, fmaf((u0).w, R[aa][1], sc1 * y0.w), acc[3]); \
        acc[4]  = fmaf(w_, fmaf((u1).x, R[aa][2], sc2 * y1.x), acc[4]); \
        acc[5]  = fmaf(w_, fmaf((u1).y, R[aa][2], sc2 * y1.y), acc[5]); \
        acc[6]  = fmaf(w_, fmaf((u1).z, R[aa][2], sc2 * y1.z), acc[6]); \
        acc[7]  = fmaf(w_, fmaf((u1).w, R[aa][2], sc2 * y1.w), acc[7]); \
        acc[8]  = fmaf(w_, fmaf((u2).x, R[aa][2], sc2 * y2.x), acc[8]); \
        acc[9]  = fmaf(w_, fmaf((u2).y, R[aa][3], sc3 * y2.y), acc[9]); \
        acc[10] = fmaf(w_, fmaf((u2).z, R[aa][3], sc3 * y2.z), acc[10]); \
        acc[11] = fmaf(w_, fmaf((u2).w, R[aa][3], sc3 * y2.w), acc[11]); \
        acc[12] = fmaf(w_, fmaf((u3).x, R[aa][3], sc3 * y3.x), acc[12]); \
        acc[13] = fmaf(w_, fmaf((u3).y, R[aa][3], sc3 * y3.y), acc[13]); \
        acc[14] = fmaf(w_, fmaf((u3).z, R[aa][3], sc3 * y3.z), acc[14]); \
        acc[15] = fmaf(w_, fmaf((u3).w, R[aa][3], sc3 * y3.w), acc[15]); \
    } }

// One fused layer. 3 blocks/CU (LDS ~51KB).
__global__ __launch_bounds__(256, 3) void k_layer(
    const float* __restrict__ x, const float* __restrict__ h,
    const float* __restrict__ h0in, const float* __restrict__ vpre,
    const float* __restrict__ wqk,
    const float* __restrict__ w1, const float* __restrict__ b1,
    const float* __restrict__ rW, const float* __restrict__ sW,
    const float* __restrict__ Wskip, const float* __restrict__ Wo,
    const float* __restrict__ gw, const float* __restrict__ gb,
    const float* __restrict__ Wv_n, const float* __restrict__ Wq_n, const float* __restrict__ Wk_n,
    const float* __restrict__ WvO, const float* __restrict__ WqO, const float* __restrict__ WkO,
    float* __restrict__ hnew, float* __restrict__ h0out,
    float* __restrict__ vpre_n, float* __restrict__ wqk_n,
    float* __restrict__ wq2, float* __restrict__ U,
    int layer, int last)
{
    // rwswP: interleaved fp16 j-pairs [(l*16+j2)*64 + 2d] = wR2, +1 = wS2;
    //        later float-bits Wo / Wv_n / WvO-hi
    __shared__ __align__(16) uint32_t rwswP[4096];
    // rhs: first 2048 u32 = rh fp16 j-pairs (stride 16 u32/row); later P[8][528] f32; later Wskip / WvO-lo
    __shared__ __align__(16) float rhs[128 * 36];
    __shared__ __align__(16) float yss[128 * 20]; // Ys (stride 20, 16B-aligned); later hs[512]
    __shared__ __align__(16) float ub[1056];      // phase A: xs[384]|w1s[512]; post: hnS[528]|aggL[528]
    __shared__ float b1s[32];
    __shared__ float wqks[32];
    __shared__ float alphas[128];
    __shared__ float red[256];
    __shared__ float scale[128];
    __shared__ float sh_inv;

    int nblk = blockIdx.x, t = threadIdx.x;
    int g = nblk >> 7, b = nblk & 127;
    int gbase = g << 7;

    float* xs = ub;           // [384]
    float* w1s = ub + 384;    // [512]
    uint32_t* rh16 = reinterpret_cast<uint32_t*>(rhs);  // [128][16] fp16 j-pairs

    for (int o = t; o < 384; o += 256) xs[o] = x[gbase * 3 + o];
    for (int o = t; o < 512; o += 256) w1s[o] = w1[layer * 512 + o];
    if (t < 32) { b1s[t] = b1[layer * 32 + t]; wqks[t] = wqk[nblk * 32 + t]; }
    // stage rW/sW as interleaved fp16 j-pairs
    for (int idx = t; idx < 2048; idx += 256) {
        int d2 = idx & 31, j2 = (idx >> 5) & 15, l = idx >> 9;
        int src = layer * 4096 + l * 1024 + (2 * j2) * 32 + d2;
        int base = ((l * 16 + j2) << 6) + (d2 << 1);
        rwswP[base]     = f2h2(rW[src], rW[src + 32]);
        rwswP[base + 1] = f2h2(sW[src], sW[src + 32]);
    }
    __syncthreads();

    // ---- phase A: geometry, rh (fp16 j-pairs), partial logit ----
    {
        int a = t & 127, dh = t >> 7;
        float rx = xs[b * 3 + 0] - xs[a * 3 + 0];
        float ry = xs[b * 3 + 1] - xs[a * 3 + 1];
        float rz = xs[b * 3 + 2] - xs[a * 3 + 2];
        float dd = sqrtf(rx * rx + ry * ry + rz * rz + 1e-12f);
        float inv = 1.f / dd;
        float ys[16];
        sph16(rx * inv, ry * inv, rz * inv, ys);
        if (dh == 0) {
#pragma unroll
            for (int m = 0; m < 16; m++) yss[a * 20 + m] = ys[m];
        }
        float rbf[16];
#pragma unroll
        for (int j = 0; j < 16; j++) {
            float dc = dd - (4.f / 15.f) * j;
            rbf[j] = __expf(-2.f * dc * dc);
        }
        float lpart = 0.f;
        int d0 = dh * 16;
        float sprev = 0.f;
        for (int d2 = 0; d2 < 16; d2++) {
            int d = d0 + d2;
            float s = b1s[d];
#pragma unroll
            for (int j = 0; j < 16; j++) s = fmaf(rbf[j], w1s[j * 32 + d], s);
            s = fmaxf(s, 0.f);
            lpart = fmaf(s, wqks[d], lpart);
            if (d2 & 1) rh16[a * 16 + dh * 8 + (d2 >> 1)] = f2h2(sprev, s);
            sprev = s;
        }
        red[t] = lpart;
    }
    __syncthreads();
    if (t < 128) alphas[t] = (red[t] + red[t + 128]) * 0.17677669529663687f; // 1/sqrt(32)
    __syncthreads();

    // ---- segment softmax over 127 valid edges (wave shuffle reductions) ----
    if (t < 128) {
        float m = (t != b) ? alphas[t] : -1e30f;
#pragma unroll
        for (int off = 32; off > 0; off >>= 1) m = fmaxf(m, __shfl_xor(m, off));
        if ((t & 63) == 0) red[t >> 6] = m;
    }
    __syncthreads();
    {
        float mx = fmaxf(red[0], red[1]);
        if (t < 128) {
            float e = (t != b) ? __expf(alphas[t] - mx) : 0.f;
            alphas[t] = e;
            float s = e;
#pragma unroll
            for (int off = 32; off > 0; off >>= 1) s += __shfl_xor(s, off);
            if ((t & 63) == 0) red[2 + (t >> 6)] = s;
        }
    }
    __syncthreads();
    if (t == 0) sh_inv = 1.f / (red[2] + red[3]);

    // ---- pass 2: dot2-based R/S GEMM + weighted aggregate ----
    int grp = t >> 5, d = t & 31;
    float acc[16];
#pragma unroll
    for (int m = 0; m < 16; m++) acc[m] = 0.f;

    for (int chunk = 0; chunk < 2; chunk++) {
        int a0 = grp * 16 + chunk * 8;
        float R[8][4], S[8][4];
#pragma unroll
        for (int aa = 0; aa < 8; aa++)
#pragma unroll
            for (int l = 0; l < 4; l++) { R[aa][l] = 0.f; S[aa][l] = 0.f; }

#pragma unroll 2
        for (int j8 = 0; j8 < 4; j8++) {           // 4 j-pair quads (8 j's each)
            uint4 rq[8];
#pragma unroll
            for (int aa = 0; aa < 8; aa++)
                rq[aa] = *reinterpret_cast<const uint4*>(&rh16[(a0 + aa) * 16 + j8 * 4]);
#pragma unroll
            for (int l = 0; l < 4; l++) {
#pragma unroll
                for (int jp = 0; jp < 4; jp++) {
                    uint2 wp = *reinterpret_cast<const uint2*>(
                        &rwswP[((l * 16 + j8 * 4 + jp) << 6) + (d << 1)]);
#pragma unroll
                    for (int aa = 0; aa < 8; aa++) {
                        uint32_t rv = u4get(rq[aa], jp);
                        R[aa][l] = fdot2u(rv, wp.x, R[aa][l]);
                        S[aa][l] = fdot2u(rv, wp.y, S[aa][l]);
                    }
                }
            }
        }

        // epilogue: 2-deep double-buffered global loads (vpre rows + dense h0 sidecar)
        float4 A0, A1, A2, A3, B0, B1, B2, B3; float Ah, Bh;
        {
            const float4* p4 = reinterpret_cast<const float4*>(vpre + (gbase + a0) * 512 + d * 16);
            A0 = p4[0]; A1 = p4[1]; A2 = p4[2]; A3 = p4[3];
            Ah = h0in[(gbase + a0) * 32 + d];
            const float4* q4 = reinterpret_cast<const float4*>(vpre + (gbase + a0 + 1) * 512 + d * 16);
            B0 = q4[0]; B1 = q4[1]; B2 = q4[2]; B3 = q4[3];
            Bh = h0in[(gbase + a0 + 1) * 32 + d];
        }
#pragma unroll
        for (int ap = 0; ap < 4; ap++) {
            int aa = ap * 2;
            {
                float4 u0 = A0, u1 = A1, u2 = A2, u3 = A3; float h0v = Ah;
                if (ap < 3) {
                    const float4* p4 = reinterpret_cast<const float4*>(vpre + (gbase + a0 + aa + 2) * 512 + d * 16);
                    A0 = p4[0]; A1 = p4[1]; A2 = p4[2]; A3 = p4[3];
                    Ah = h0in[(gbase + a0 + aa + 2) * 32 + d];
                }
                PROC_SRC(aa, u0, u1, u2, u3, h0v)
            }
            {
                float4 u0 = B0, u1 = B1, u2 = B2, u3 = B3; float h0v = Bh;
                if (ap < 3) {
                    const float4* p4 = reinterpret_cast<const float4*>(vpre + (gbase + a0 + aa + 3) * 512 + d * 16);
                    B0 = p4[0]; B1 = p4[1]; B2 = p4[2]; B3 = p4[3];
                    Bh = h0in[(gbase + a0 + aa + 3) * 32 + d];
                }
                PROC_SRC(aa + 1, u0, u1, u2, u3, h0v)
            }
        }
    }
    __syncthreads();   // all pass-2 LDS reads (rh16/rwswP/yss) done

    // S1: partials into P (overlay rhs); stage h[n] (overlay yss); stage Wo (float bits in rwswP)
    float* P = rhs;
#pragma unroll
    for (int m = 0; m < 16; m++) P[grp * 528 + m * 33 + d] = acc[m];
    float* hs = yss;
    for (int o = t; o < 512; o += 256) hs[o] = h[nblk * 512 + o];
    for (int o = t; o < 4096; o += 256) rwswP[o] = __float_as_uint(Wo[layer * 4096 + o]);
    __syncthreads();

    // S2: reduce partials -> aggL[m*33+c]
    float* hnS = ub;          // [528]
    float* aggL = ub + 528;   // [528]
    float invs = sh_inv;
    for (int o = t; o < 512; o += 256) {
        int m = o >> 5, c = o & 31;
        float s = 0.f;
#pragma unroll
        for (int gg = 0; gg < 8; gg++) s += P[gg * 528 + m * 33 + c];
        aggL[m * 33 + c] = s * invs;
    }
    __syncthreads();

    // S3: stage Wskip into rhs (fp32), P dead
    for (int o = t; o < 4096; o += 256) rhs[o] = Wskip[layer * 4096 + o];
    __syncthreads();

    // S4: post GEMM: hn = h@Wskip + agg@Wo
    for (int o = t; o < 512; o += 256) {
        int m = o >> 5, dd = o & 31, l = lmap(m);
        float s = 0.f;
        const float* wa = &rhs[l * 1024 + dd];
        const uint32_t* wb = &rwswP[l * 1024 + dd];
        const float* hrow = &hs[m];
        const float* arow = &aggL[m * 33];
#pragma unroll
        for (int c = 0; c < 32; c++) {
            s = fmaf(hrow[c * 16], wa[c * 32], s);
            s = fmaf(arow[c], __uint_as_float(wb[c * 32]), s);
        }
        hnS[m * 33 + dd] = s;
    }
    __syncthreads();

    // S5: norm gate compute + stage next-stage value weights
    if (t < 128) {
        int dd = t >> 2, l = t & 3;
        int m0 = l * l, cnt = 2 * l + 1;
        float s = 1e-12f;
        for (int m = m0; m < m0 + cnt; m++) { float v = hnS[m * 33 + dd]; s = fmaf(v, v, s); }
        float nr = sqrtf(s);
        float phi = fmaxf(nr * gw[(layer * 4 + l) * 32 + dd] + gb[(layer * 4 + l) * 32 + dd], 0.f);
        scale[dd * 4 + l] = phi / (nr + 1e-6f);
    }
    if (!last) {
        for (int o = t; o < 4096; o += 256) rwswP[o] = __float_as_uint(Wv_n[o]);
    } else {
        for (int o = t; o < 4096; o += 256) {
            rhs[o] = WvO[o];                                   // l = 0,1
            rwswP[o] = __float_as_uint(WvO[4096 + o]);         // l = 2,3
        }
    }
    __syncthreads();

    // S6: apply gate, write hnew
    for (int o = t; o < 512; o += 256) {
        int dd = o >> 4, m = o & 15;
        float v = hnS[m * 33 + dd] * scale[dd * 4 + lmap(m)];
        hnew[nblk * 512 + o] = v;
        hnS[m * 33 + dd] = v;
    }
    __syncthreads();

    // dense h0 sidecar: one coalesced wave-store of the gated m=0 column
    if (t < 32) h0out[nblk * 32 + t] = hnS[t];

    if (!last) {
        for (int o = t; o < 512; o += 256) {
            int dd = o >> 4, m = o & 15, l = lmap(m);
            float s = 0.f;
            const uint32_t* wv = &rwswP[l * 1024 + dd];
            const float* hrow = &hnS[m * 33];
#pragma unroll
            for (int c = 0; c < 32; c++) s = fmaf(hrow[c], __uint_as_float(wv[c * 32]), s);
            vpre_n[nblk * 512 + o] = s;
        }
        if (t < 32) {
            float s = 0.f;
#pragma unroll
            for (int c = 0; c < 32; c++) s = fmaf(hnS[c * 33], Wq_n[c * 32 + t], s);
            red[t] = s;
        }
        __syncthreads();
        if (t < 32) {
            float s = 0.f;
#pragma unroll
            for (int j = 0; j < 32; j++) s = fmaf(Wk_n[t * 32 + j], red[j], s);
            wqk_n[nblk * 32 + t] = s;
        }
    } else {
        for (int o = t; o < 1024; o += 256) {
            int j = o >> 4, m = o & 15, l = lmap(m);
            float s = 0.f;
            const float* hrow = &hnS[m * 33];
            if (l < 2) {
                const float* wv = &rhs[l * 2048 + j];
#pragma unroll
                for (int c = 0; c < 32; c++) s = fmaf(hrow[c], wv[c * 64], s);
            } else {
                const uint32_t* wv = &rwswP[(l - 2) * 2048 + j];
#pragma unroll
                for (int c = 0; c < 32; c++) s = fmaf(hrow[c], __uint_as_float(wv[c * 64]), s);
            }
            U[nblk * 1024 + o] = s;
        }
        if (t < 64) {
            float s = 0.f;
#pragma unroll
            for (int c = 0; c < 32; c++) s = fmaf(hnS[c * 33], WqO[c * 64 + t], s);
            red[t] = s;
        }
        __syncthreads();
        if (t < 32) {
            float s = 0.f;
#pragma unroll
            for (int j = 0; j < 64; j++) s = fmaf(WkO[t * 64 + j], red[j], s);
            wq2[nblk * 32 + t] = s;
        }
    }
}

// Output-stage edge kernel + fused out_post (hout). 3 blocks/CU.
__global__ __launch_bounds__(256, 3) void k_out_edge(
    const float* __restrict__ x, const float* __restrict__ h0f,
    const float* __restrict__ w1o, const float* __restrict__ b1o,
    const float* __restrict__ wq2, const float* __restrict__ roW,
    const float* __restrict__ U, const float* __restrict__ WoO,
    const float* __restrict__ WskipO, float* __restrict__ hout)
{
    __shared__ uint32_t rosP[4096];               // fp16 c-pairs of roW
    __shared__ __align__(16) uint32_t rh16o[128 * 16]; // rh fp16 c-pairs
    __shared__ __align__(16) float yss[128 * 20];
    __shared__ float xs[384];
    __shared__ float w1s[512];
    __shared__ float b1s[32];
    __shared__ float wq2s[32];
    __shared__ float alphas[128];
    __shared__ float red[256];
    __shared__ float agg64s[64];
    __shared__ float sh_inv;

    int n = blockIdx.x, t = threadIdx.x;
    int g = n >> 7, b = n & 127;
    int gbase = g << 7;

    for (int o = t; o < 384; o += 256) xs[o] = x[gbase * 3 + o];
    for (int o = t; o < 512; o += 256) w1s[o] = w1o[o];
    if (t < 32) { b1s[t] = b1o[t]; wq2s[t] = wq2[n * 32 + t]; }
    for (int o = t; o < 4096; o += 256) {
        int j = o & 63, lc = o >> 6, cp = lc & 15, l = lc >> 4;
        rosP[o] = f2h2(roW[(l * 32 + 2 * cp) * 64 + j], roW[(l * 32 + 2 * cp + 1) * 64 + j]);
    }
    __syncthreads();

    // phase A split across 256 threads; rh stored as fp16 c-pairs
    {
        int a = t & 127, dh = t >> 7;
        float rx = xs[b * 3 + 0] - xs[a * 3 + 0];
        float ry = xs[b * 3 + 1] - xs[a * 3 + 1];
        float rz = xs[b * 3 + 2] - xs[a * 3 + 2];
        float dd = sqrtf(rx * rx + ry * ry + rz * rz + 1e-12f);
        float inv = 1.f / dd;
        float ys[16];
        sph16(rx * inv, ry * inv, rz * inv, ys);
        if (dh == 0) {
#pragma unroll
            for (int m = 0; m < 16; m++) yss[a * 20 + m] = ys[m];
        }
        float rbf[16];
#pragma unroll
        for (int j = 0; j < 16; j++) {
            float dc = dd - (4.f / 15.f) * j;
            rbf[j] = __expf(-2.f * dc * dc);
        }
        float lpart = 0.f;
        int d0 = dh * 16;
        float sprev = 0.f;
        for (int d2 = 0; d2 < 16; d2++) {
            int d = d0 + d2;
            float s = b1s[d];
#pragma unroll
            for (int j = 0; j < 16; j++) s = fmaf(rbf[j], w1s[j * 32 + d], s);
            s = fmaxf(s, 0.f);
            lpart = fmaf(s, wq2s[d], lpart);
            if (d2 & 1) rh16o[a * 16 + dh * 8 + (d2 >> 1)] = f2h2(sprev, s);
            sprev = s;
        }
        red[t] = lpart;
    }
    __syncthreads();
    if (t < 128) alphas[t] = (red[t] + red[t + 128]) * 0.125f; // 1/sqrt(64)
    __syncthreads();

    if (t < 128) {
        float m = (t != b) ? alphas[t] : -1e30f;
#pragma unroll
        for (int off = 32; off > 0; off >>= 1) m = fmaxf(m, __shfl_xor(m, off));
        if ((t & 63) == 0) red[t >> 6] = m;
    }
    __syncthreads();
    {
        float mx = fmaxf(red[0], red[1]);
        if (t < 128) {
            float e = (t != b) ? __expf(alphas[t] - mx) : 0.f;
            alphas[t] = e;
            float s = e;
#pragma unroll
            for (int off = 32; off > 0; off >>= 1) s += __shfl_xor(s, off);
            if ((t & 63) == 0) red[2 + (t >> 6)] = s;
        }
    }
    __syncthreads();
    if (t == 0) sh_inv = 1.f / (red[2] + red[3]);
    __syncthreads();

    int grp = t >> 6, j = t & 63;
    float accO = 0.f;
    for (int chunk = 0; chunk < 4; chunk++) {
        int a0 = grp * 32 + chunk * 8;
        float RO[8][4];
#pragma unroll
        for (int aa = 0; aa < 8; aa++)
#pragma unroll
            for (int l = 0; l < 4; l++) RO[aa][l] = 0.f;

#pragma unroll 2
        for (int q = 0; q < 4; q++) {              // 4 c-pair quads
            uint4 rq[8];
#pragma unroll
            for (int aa = 0; aa < 8; aa++)
                rq[aa] = *reinterpret_cast<const uint4*>(&rh16o[(a0 + aa) * 16 + q * 4]);
#pragma unroll
            for (int l = 0; l < 4; l++) {
#pragma unroll
                for (int cp = 0; cp < 4; cp++) {
                    uint32_t wv = rosP[(l * 16 + q * 4 + cp) * 64 + j];
#pragma unroll
                    for (int aa = 0; aa < 8; aa++)
                        RO[aa][l] = fdot2u(u4get(rq[aa], cp), wv, RO[aa][l]);
                }
            }
        }

        float4 A0, A1, A2, A3, B0, B1, B2, B3;
        {
            const float4* p4 = reinterpret_cast<const float4*>(U + (gbase + a0) * 1024 + j * 16);
            A0 = p4[0]; A1 = p4[1]; A2 = p4[2]; A3 = p4[3];
            const float4* q4 = reinterpret_cast<const float4*>(U + (gbase + a0 + 1) * 1024 + j * 16);
            B0 = q4[0]; B1 = q4[1]; B2 = q4[2]; B3 = q4[3];
        }
#define PROC_O(aa, u0, u1, u2, u3) { \
        int a_ = a0 + (aa); \
        float w_ = alphas[a_]; \
        if (w_ != 0.f) { \
            const float4* yp = reinterpret_cast<const float4*>(&yss[a_ * 20]); \
            float4 y0 = yp[0], y1 = yp[1], y2 = yp[2], y3 = yp[3]; \
            float cv0 = y0.x * (u0).x; \
            float cv1 = fmaf(y0.y, (u0).y, fmaf(y0.z, (u0).z, y0.w * (u0).w)); \
            float cv2 = fmaf(y1.x, (u1).x, fmaf(y1.y, (u1).y, fmaf(y1.z, (u1).z, fmaf(y1.w, (u1).w, y2.x * (u2).x)))); \
            float cv3 = fmaf(y2.y, (u2).y, fmaf(y2.z, (u2).z, fmaf(y2.w, (u2).w, \
                        fmaf(y3.x, (u3).x, fmaf(y3.y, (u3).y, fmaf(y3.z, (u3).z, y3.w * (u3).w)))))); \
            float s_ = fmaf(cv0, RO[aa][0], fmaf(cv1, RO[aa][1], fmaf(cv2, RO[aa][2], cv3 * RO[aa][3]))); \
            accO = fmaf(w_, s_, accO); \
        } }
#pragma unroll
        for (int ap = 0; ap < 4; ap++) {
            int aa = ap * 2;
            {
                float4 u0 = A0, u1 = A1, u2 = A2, u3 = A3;
                if (ap < 3) {
                    const float4* p4 = reinterpret_cast<const float4*>(U + (gbase + a0 + aa + 2) * 1024 + j * 16);
                    A0 = p4[0]; A1 = p4[1]; A2 = p4[2]; A3 = p4[3];
                }
                PROC_O(aa, u0, u1, u2, u3)
            }
            {
                float4 u0 = B0, u1 = B1, u2 = B2, u3 = B3;
                if (ap < 3) {
                    const float4* p4 = reinterpret_cast<const float4*>(U + (gbase + a0 + aa + 3) * 1024 + j * 16);
                    B0 = p4[0]; B1 = p4[1]; B2 = p4[2]; B3 = p4[3];
                }
                PROC_O(aa + 1, u0, u1, u2, u3)
            }
        }
#undef PROC_O
    }
    red[t] = accO;
    __syncthreads();
    if (t < 64) agg64s[t] = (red[t] + red[64 + t] + red[128 + t] + red[192 + t]) * sh_inv;
    __syncthreads();

    if (t < 64) {
        float s = 0.f;
#pragma unroll
        for (int c = 0; c < 64; c++) s = fmaf(agg64s[c], WoO[c * 64 + t], s);
        const float* hr = &h0f[n * 32];
#pragma unroll
        for (int c = 0; c < 32; c++) s = fmaf(hr[c], WskipO[c * 64 + t], s);
        hout[n * 64 + t] = s;
    }
}

__global__ __launch_bounds__(64) void k_final(
    const float* __restrict__ hout, const float* __restrict__ Whid,
    const float* __restrict__ bhid, const float* __restrict__ Wout,
    const float* __restrict__ bout, float* __restrict__ out)
{
    __shared__ float pooled[64], hid[64];
    int g = blockIdx.x, t = threadIdx.x;
    float s = 0.f;
    for (int p = 0; p < 128; p++) s += hout[(g * 128 + p) * 64 + t];
    pooled[t] = s * (1.f / 128.f);
    __syncthreads();
    float hv = bhid[t];
#pragma unroll
    for (int c = 0; c < 64; c++) hv = fmaf(pooled[c], Whid[c * 64 + t], hv);
    hid[t] = fmaxf(hv, 0.f);
    __syncthreads();
    if (t < 15) {
        float o = bout[t];
#pragma unroll
        for (int c = 0; c < 64; c++) o = fmaf(hid[c], Wout[c * 15 + t], o);
        out[g * 15 + t] = o;
    }
}

extern "C" void kernel_launch(void* const* d_in, const int* in_sizes, int n_in,
                              void* d_out, int out_size, void* d_ws, size_t ws_size,
                              hipStream_t stream) {
    const float* x      = (const float*)d_in[0];
    const float* w1     = (const float*)d_in[1];
    const float* b1     = (const float*)d_in[2];
    const float* rW     = (const float*)d_in[3];
    const float* sW     = (const float*)d_in[4];
    const float* Wv     = (const float*)d_in[5];
    const float* Wq     = (const float*)d_in[6];
    const float* Wk     = (const float*)d_in[7];
    const float* Wo     = (const float*)d_in[8];
    const float* Wskip  = (const float*)d_in[9];
    const float* gw     = (const float*)d_in[10];
    const float* gb     = (const float*)d_in[11];
    const float* w1o    = (const float*)d_in[12];
    const float* b1o    = (const float*)d_in[13];
    const float* roW    = (const float*)d_in[14];
    const float* WvO    = (const float*)d_in[15];
    const float* WqO    = (const float*)d_in[16];
    const float* WkO    = (const float*)d_in[17];
    const float* WoO    = (const float*)d_in[18];
    const float* WskipO = (const float*)d_in[19];
    const float* Whid   = (const float*)d_in[20];
    const float* bhid   = (const float*)d_in[21];
    const float* Wout   = (const float*)d_in[22];
    const float* bout   = (const float*)d_in[23];
    float* out = (float*)d_out;

    float* ws = (float*)d_ws;
    float* h0    = ws;
    float* h1    = h0 + NNODE * 512;
    float* vA    = h1 + NNODE * 512;
    float* wqkA  = vA + NNODE * 512;
    float* vB    = wqkA + NNODE * 32;
    float* wqkB  = vB + NNODE * 512;
    float* wq2   = wqkB + NNODE * 32;
    float* U     = wq2 + NNODE * 32;
    float* hout  = U + NNODE * 1024;
    float* s0A   = hout + NNODE * 64;
    float* s0B   = s0A + NNODE * 32;

    hipMemsetAsync(h0, 0, NNODE * 512 * sizeof(float), stream);
    hipMemsetAsync(vA, 0, (NNODE * 512 + NNODE * 32) * sizeof(float), stream);
    hipMemsetAsync(s0A, 0, NNODE * 32 * sizeof(float), stream);

    for (int i = 0; i < 4; i++) {
        const float* hc  = (i & 1) ? h1 : h0;
        float*       hn  = (i & 1) ? h0 : h1;
        const float* vin  = (i & 1) ? vB : vA;
        const float* qin  = (i & 1) ? wqkB : wqkA;
        float*       vout = (i & 1) ? vA : vB;
        float*       qout = (i & 1) ? wqkA : wqkB;
        const float* s0in = (i & 1) ? s0B : s0A;
        float*       s0out= (i & 1) ? s0A : s0B;
        int last = (i == 3);
        k_layer<<<NNODE, 256, 0, stream>>>(
            x, hc, s0in, vin, qin, w1, b1, rW, sW, Wskip, Wo, gw, gb,
            Wv + (last ? 0 : (i + 1) * 4096),
            Wq + (last ? 0 : (i + 1) * 1024),
            Wk + (last ? 0 : (i + 1) * 1024),
            WvO, WqO, WkO,
            hn, s0out, vout, qout, wq2, U, i, last);
    }
    // final h0 sidecar: i=3 wrote s0A
    k_out_edge<<<NNODE, 256, 0, stream>>>(x, s0A, w1o, b1o, wq2, roW, U, WoO, WskipO, hout);
    k_final<<<NGRAPH, 64, 0, stream>>>(hout, Whid, bhid, Wout, bout, out);
}